// Round 1
// 4616.382 us; speedup vs baseline: 1.0229x; 1.0229x over previous
//
#include <hip/hip_runtime.h>
#include <math.h>

// ---------------------------------------------------------------------------
// Faster-RCNN head, fp64 through the rois-determining path. Round 6:
//  - conv3x3_fused: T14 async-stage split — next ky row is prefetched into
//    registers BEFORE the MFMA phase, so the global-load latency hides under
//    the 576-MFMA shadow instead of sitting exposed between the two barriers.
//    __launch_bounds__(256,4) pins VGPR<=128 so LDS-capped occupancy
//    (4 blocks/CU) is preserved. Arithmetic order unchanged (bit-identical).
//  - nms_reduce_d: supp row i+1 prefetched while processing row i — removes
//    the ~300cy L2 latency from the 1000-iteration serial dependence chain.
//  - everything else unchanged from R5.
//
// Workspace (BYTES):
//   o64  (double, 11,173,888 el)   [0          .. 89,391,104)
//   p64  (double, 11,173,888 el)   [89,391,104 .. 178,782,208)
//   c6   (float)                   [178,782,208 .. 179,830,784)
//   scores (double)                [179,830,784 .. 182,973,440)
//   boxes  (double)                [182,973,440 .. 195,544,064)
//   ss/sb/rois64/supp tail         [195,544,064 .. 195,944,064)
//   featsH/L (bf16) overlap p64+   [89,391,104 .. 189,743,104)   (after rpn)
//   fc region overlaps o64 (dead after roi_align):
//     fc1b f32  [0 .. 8,192,000)      fc2b f32 [8,192,000 .. 16,384,000)
//     wT1H [16,384,000 .. 42,074,112) wT1L [42,074,112 .. 67,764,224)
//     wT2H [67,764,224 .. 69,861,376) wT2L [69,861,376 .. 71,958,528)
//     fc1H [71,958,528 .. 76,054,528) fc1L [76,054,528 .. 80,150,528)
// ---------------------------------------------------------------------------

#define NUM_ANCH 196416

typedef double d4 __attribute__((ext_vector_type(4)));
typedef __attribute__((ext_vector_type(8))) short bf8_t;
typedef __attribute__((ext_vector_type(4))) float f4_t;

__device__ inline unsigned short f2bf(float x) {
  unsigned u = __float_as_uint(x);
  unsigned r = (u + 0x7fffu + ((u >> 16) & 1u)) >> 16;   // RNE
  return (unsigned short)r;
}
__device__ inline float bf2f(unsigned short h) {
  return __uint_as_float(((unsigned)h) << 16);
}

// ---------------- maxpool2 c5 (2,16,16,2048) -> c6 (2,8,8,2048), f32 --------
__global__ void maxpool_kernel(const float* __restrict__ in, float* __restrict__ out) {
  int idx = blockIdx.x * 256 + threadIdx.x;     // 262144 total
  int c = idx & 2047;
  int x = (idx >> 11) & 7;
  int y = (idx >> 14) & 7;
  int b = idx >> 17;
  const float* p = in + (((size_t)b * 16 + 2 * y) * 16 + 2 * x) * 2048 + c;
  float m = fmaxf(fmaxf(p[0], p[2048]), fmaxf(p[16 * 2048], p[16 * 2048 + 2048]));
  out[idx] = m;
}

// ---------------- 1x1 lateral conv + bias, f32 in -> f64 out ----------------
template <int CIN>
__global__ __launch_bounds__(256) void lateral_d(
    const float* __restrict__ in, const float* __restrict__ w,
    const float* __restrict__ bias, double* __restrict__ out) {
  const int t = threadIdx.x;
  const size_t pix0 = (size_t)blockIdx.x * 4;
  double b = (double)bias[t];
  double a0 = b, a1 = b, a2 = b, a3 = b;
  const float* i0 = in + pix0 * CIN;
  for (int ci = 0; ci < CIN; ++ci) {
    double wv = (double)w[ci * 256 + t];
    a0 += (double)i0[ci] * wv;
    a1 += (double)i0[CIN + ci] * wv;
    a2 += (double)i0[2 * CIN + ci] * wv;
    a3 += (double)i0[3 * CIN + ci] * wv;
  }
  out[(pix0 + 0) * 256 + t] = a0;
  out[(pix0 + 1) * 256 + t] = a1;
  out[(pix0 + 2) * 256 + t] = a2;
  out[(pix0 + 3) * 256 + t] = a3;
}

// ---------------- fine += upsample2(coarse), C=256, f64 ---------------------
__global__ void upadd_d(double* __restrict__ fine, const double* __restrict__ coarse,
                        int Hf, int Wf) {
  int idx = blockIdx.x * 256 + threadIdx.x;
  int c = idx & 255;
  int rem = idx >> 8;
  int x = rem % Wf; rem /= Wf;
  int y = rem % Hf;
  int b = rem / Hf;
  fine[idx] += coarse[(((size_t)b * (Hf >> 1) + (y >> 1)) * (Wf >> 1) + (x >> 1)) * 256 + c];
}

// ---------------- fused 5-level 3x3 conv, f64 MFMA --------------------------
// One dispatch covers all FPN levels; blockIdx.x -> (level, x-tile, y, batch)
// via the offset table. Per-level math identical to R5 (bitwise identical);
// R6 adds register prefetch of the next ky row (async-stage split).
struct Conv5Args {
  const double* in[5];
  double* out[5];
  const float* w[5];
  const float* b[5];
  int H[5];
  int nbx[5];
  int off[6];
};

template <bool RELU>
__global__ __launch_bounds__(256, 4) void conv3x3_fused(Conv5Args A) {
  __shared__ double sh[18 * 257];   // 36.99 KB
  const int bx = blockIdx.x;
  int l = 0;
#pragma unroll
  for (int i = 1; i < 5; ++i)
    if (bx >= A.off[i]) l = i;
  const int rel = bx - A.off[l];
  const int H = A.H[l];
  const int nbx = A.nbx[l];
  const int x0 = (rel % nbx) * 16;
  const int y = (rel / nbx) % H;
  const int b = rel / (nbx * H);
  const double* __restrict__ in = A.in[l];
  double* __restrict__ out = A.out[l];
  const float* __restrict__ w = A.w[l];
  const float* __restrict__ bias = A.b[l];
  const int W = H;

  const int t = threadIdx.x;
  const int lane = t & 63;
  const int wave = t >> 6;
  const int m = lane & 15;      // A row (pixel) / B col (cout) owner index
  const int kq = lane >> 4;     // k slot within mfma K=4

  // probe the D/C register layout (robust to any permutation)
  d4 z = {0.0, 0.0, 0.0, 0.0};
  double pa = (kq == 0) ? (double)m : 0.0;
  double pb = (kq == 0) ? 1.0 : 0.0;
  d4 p1 = __builtin_amdgcn_mfma_f64_16x16x4f64(pa, pb, z, 0, 0, 0);
  d4 p2 = __builtin_amdgcn_mfma_f64_16x16x4f64(pb, pa, z, 0, 0, 0);
  int drow[4], dcol[4];
#pragma unroll
  for (int r = 0; r < 4; ++r) {
    int rr = (int)(p1[r] + 0.5);
    int cc = (int)(p2[r] + 0.5);
    drow[r] = rr < 0 ? 0 : (rr > 15 ? 15 : rr);
    dcol[r] = cc < 0 ? 0 : (cc > 15 ? 15 : cc);
  }

  const int n_base = wave * 64;
  d4 acc[4];
#pragma unroll
  for (int nt = 0; nt < 4; ++nt)
#pragma unroll
    for (int r = 0; r < 4; ++r)
      acc[nt][r] = (double)bias[n_base + nt * 16 + dcol[r]];

  // ---- register prefetch of input rows (async-stage split) ----
  double rin[18];
  {
    const int gy = y - 1;                       // row for ky=0
    const bool gok = (gy >= 0);
    const double* rp = in + (((size_t)b * H + (gok ? gy : 0)) * W) * 256 + t;
#pragma unroll
    for (int j = 0; j < 18; ++j) {
      int gx = x0 + j - 1;
      rin[j] = (gok && gx >= 0 && gx < W) ? rp[(size_t)gx * 256] : 0.0;
    }
  }

  for (int ky = 0; ky < 3; ++ky) {
    __syncthreads();                            // LDS free (WAR vs prev compute)
#pragma unroll
    for (int j = 0; j < 18; ++j) sh[j * 257 + t] = rin[j];
    __syncthreads();                            // LDS ready (RAW)
    if (ky < 2) {
      // issue next row's loads NOW; latency hides under the MFMA phase below
      const int gy = y + ky;                    // row for ky+1: y+(ky+1)-1
      const bool gok = (gy < H);                // gy >= 0 always here
      const double* rp = in + (((size_t)b * H + (gok ? gy : 0)) * W) * 256 + t;
#pragma unroll
      for (int j = 0; j < 18; ++j) {
        int gx = x0 + j - 1;
        rin[j] = (gok && gx >= 0 && gx < W) ? rp[(size_t)gx * 256] : 0.0;
      }
    }
#pragma unroll
    for (int kx = 0; kx < 3; ++kx) {
      const double* arow = sh + (m + kx) * 257 + kq;
      const float* wp = w + (size_t)((ky * 3 + kx) * 256 + kq) * 256 + n_base + m;
      for (int s = 0; s < 64; ++s) {
        double a = arow[s * 4];
        const float* wrow = wp + (size_t)(s * 4) * 256;
#pragma unroll
        for (int nt = 0; nt < 4; ++nt) {
          double bv = (double)wrow[nt * 16];
          acc[nt] = __builtin_amdgcn_mfma_f64_16x16x4f64(a, bv, acc[nt], 0, 0, 0);
        }
      }
    }
  }
#pragma unroll
  for (int nt = 0; nt < 4; ++nt) {
#pragma unroll
    for (int r = 0; r < 4; ++r) {
      int gx = x0 + drow[r];
      if (gx < W) {
        double v = acc[nt][r];
        if (RELU) v = fmax(v, 0.0);
        out[(((size_t)b * H + y) * W + gx) * 256 + n_base + nt * 16 + dcol[r]] = v;
      }
    }
  }
}

// ---------------- RPN head (obj + delta 1x1) + anchor decode, f64 -----------
struct AnchorHW { double hh[9]; double ww[9]; };

__global__ __launch_bounds__(64) void rpn_head_d(
    const double* __restrict__ tmap,
    const float* __restrict__ w_obj, const float* __restrict__ b_obj,
    const float* __restrict__ w_dlt, const float* __restrict__ b_dlt,
    double* __restrict__ scores, double* __restrict__ boxes,
    int H, int W, int a_off, double stride, AnchorHW anc) {
  __shared__ double tv[256];
  __shared__ double dlt[36];
  const int t = threadIdx.x;
  const int x = blockIdx.x, y = blockIdx.y, b = blockIdx.z;
  const double* px = tmap + (((size_t)b * H + y) * W + x) * 256;
  tv[t] = px[t]; tv[t + 64] = px[t + 64]; tv[t + 128] = px[t + 128]; tv[t + 192] = px[t + 192];
  __syncthreads();
  double sacc = 0.0;
  if (t < 9) {
    sacc = (double)b_obj[t];
    for (int ci = 0; ci < 256; ++ci) sacc += tv[ci] * (double)w_obj[ci * 9 + t];
  } else if (t < 45) {
    int j = t - 9;
    double a = (double)b_dlt[j];
    for (int ci = 0; ci < 256; ++ci) a += tv[ci] * (double)w_dlt[ci * 36 + j];
    dlt[j] = a;
  }
  __syncthreads();
  if (t < 9) {
    int ai = a_off + (y * W + x) * 9 + t;
    scores[(size_t)b * NUM_ANCH + ai] = sacc;
    double cy = (y + 0.5) * stride, cx = (x + 0.5) * stride;
    double hh = anc.hh[t], ww = anc.ww[t];
    float ay1 = (float)fmin(fmax(cy - hh * 0.5, 0.0), 512.0);
    float ax1 = (float)fmin(fmax(cx - ww * 0.5, 0.0), 512.0);
    float ay2 = (float)fmin(fmax(cy + hh * 0.5, 0.0), 512.0);
    float ax2 = (float)fmin(fmax(cx + ww * 0.5, 0.0), 512.0);
    float ahf = ay2 - ay1, awf = ax2 - ax1;
    float actyf = ay1 + ahf * 0.5f, actxf = ax1 + awf * 0.5f;
    double dy = dlt[t * 4 + 0], dx = dlt[t * 4 + 1];
    double dh = dlt[t * 4 + 2], dw = dlt[t * 4 + 3];
    double ncy = dy * (double)ahf + (double)actyf;
    double ncx = dx * (double)awf + (double)actxf;
    double nh = exp(dh) * (double)ahf;
    double nw = exp(dw) * (double)awf;
    double* bo = boxes + ((size_t)b * NUM_ANCH + ai) * 4;
    bo[0] = ncy - nh * 0.5;
    bo[1] = ncx - nw * 0.5;
    bo[2] = ncy + nh * 0.5;
    bo[3] = ncx + nw * 0.5;
  }
}

// ---------------- exact top-1000 per batch (f64 radix-select + bitonic) -----
__device__ inline unsigned long long dkey(double f) {
  unsigned long long u = (unsigned long long)__double_as_longlong(f);
  return u ^ ((unsigned long long)((long long)u >> 63) | 0x8000000000000000ull);
}

__global__ __launch_bounds__(1024) void topk_d(
    const double* __restrict__ scores, const double* __restrict__ boxes,
    double* __restrict__ ss, double* __restrict__ sb) {
  const int A = NUM_ANCH;
  __shared__ unsigned hist[256];
  __shared__ unsigned long long kk[2048];
  __shared__ unsigned id[2048];
  __shared__ unsigned long long s_prefix;
  __shared__ unsigned s_need, s_cnt;
  const int b = blockIdx.x, t = threadIdx.x;
  const double* sc = scores + (size_t)b * A;
  if (t == 0) { s_prefix = 0ull; s_need = 1000; s_cnt = 0; }
  __syncthreads();
  for (int r = 0; r < 8; ++r) {
    if (t < 256) hist[t] = 0;
    __syncthreads();
    const int shift = 56 - 8 * r;
    const unsigned long long prefix = s_prefix;
    unsigned long long maskHigh = 0ull;
    if (r != 0) maskHigh = (~0ull) << (shift + 8);
    for (int i = t; i < A; i += 1024) {
      unsigned long long k = dkey(sc[i]);
      if ((k & maskHigh) == prefix) atomicAdd(&hist[(unsigned)(k >> shift) & 255u], 1u);
    }
    __syncthreads();
    if (t == 0) {
      unsigned need = s_need, cum = 0;
      for (int bin = 255; bin >= 0; --bin) {
        cum += hist[bin];
        if (cum >= need) {
          s_prefix = prefix | ((unsigned long long)bin << shift);
          s_need = need - (cum - hist[bin]);
          break;
        }
      }
    }
    __syncthreads();
  }
  const unsigned long long K = s_prefix;
  for (int i = t; i < A; i += 1024) {
    unsigned long long k = dkey(sc[i]);
    if (k >= K) {
      unsigned pos = atomicAdd(&s_cnt, 1u);
      if (pos < 2048) { kk[pos] = k; id[pos] = (unsigned)i; }
    }
  }
  __syncthreads();
  unsigned cnt = s_cnt;
  for (int i = t; i < 2048; i += 1024)
    if (i >= cnt) { kk[i] = 0ull; id[i] = 0xFFFFFFFFu; }
  __syncthreads();
  for (int k = 2; k <= 2048; k <<= 1) {
    for (int j = k >> 1; j > 0; j >>= 1) {
#pragma unroll
      for (int u = 0; u < 2; ++u) {
        int i = t + u * 1024;
        int ixj = i ^ j;
        if (ixj > i) {
          unsigned long long ka = kk[i], kc = kk[ixj];
          unsigned ia = id[i], ic = id[ixj];
          bool cPrec = (kc > ka) || (kc == ka && ic < ia);
          bool up = (i & k) != 0;
          if (cPrec != up) { kk[i] = kc; kk[ixj] = ka; id[i] = ic; id[ixj] = ia; }
        }
      }
      __syncthreads();
    }
  }
  if (t < 1000) {
    unsigned idx = id[t];
    ss[b * 1000 + t] = sc[idx];
    const double* bp = boxes + ((size_t)b * A + idx) * 4;
    double* op = sb + (b * 1000 + t) * 4;
    op[0] = bp[0]; op[1] = bp[1]; op[2] = bp[2]; op[3] = bp[3];
  }
}

// ---------------- suppression bit-matrix (iou>0.7 & j>i), f64 ---------------
__global__ void suppmat_d(const double* __restrict__ sb,
                          unsigned long long* __restrict__ supp) {
  int g = blockIdx.x * 256 + threadIdx.x;   // 32000 = 2*1000*16
  int w = g & 15;
  int i = (g >> 4) % 1000;
  int b = g / 16000;
  const double* bx = sb + b * 4000;
  double y1 = bx[i * 4 + 0], x1 = bx[i * 4 + 1], y2 = bx[i * 4 + 2], x2 = bx[i * 4 + 3];
  double ai = (y2 - y1) * (x2 - x1);
  unsigned long long m = 0;
  for (int q = 0; q < 64; ++q) {
    int j = w * 64 + q;
    if (j > i && j < 1000) {
      double by1 = bx[j * 4 + 0], bx1 = bx[j * 4 + 1], by2 = bx[j * 4 + 2], bx2 = bx[j * 4 + 3];
      double aj = (by2 - by1) * (bx2 - bx1);
      double iy1 = fmax(y1, by1), ix1 = fmax(x1, bx1);
      double iy2 = fmin(y2, by2), ix2 = fmin(x2, bx2);
      double inter = fmax(iy2 - iy1, 0.0) * fmax(ix2 - ix1, 0.0);
      double iou = inter / (ai + aj - inter + 1e-8);
      if (iou > 0.7) m |= (1ull << q);
    }
  }
  supp[g] = m;
}

// ---------------- greedy NMS reduce + slot scatter --------------------------
// R6: supp row i+1 is prefetched while row i is being applied, so the serial
// 1000-iteration chain is shfl+ANDN (VALU) instead of shfl+L2-load latency.
__global__ __launch_bounds__(64) void nms_reduce_d(
    const double* __restrict__ ss, const double* __restrict__ sb,
    const unsigned long long* __restrict__ supp,
    float* __restrict__ rois, double* __restrict__ rois64) {
  __shared__ unsigned long long aliveS[16];
  __shared__ int pref[16];
  const int b = blockIdx.x, lane = threadIdx.x;
  unsigned long long myword = 0;
  if (lane < 16) {
    for (int q = 0; q < 64; ++q) {
      int j = lane * 64 + q;
      if (j < 1000 && ss[b * 1000 + j] > 0.0) myword |= (1ull << q);
    }
  }
  const unsigned long long* sp = supp + (size_t)b * 16000;
  unsigned long long cur = (lane < 16) ? sp[lane] : 0ull;
  for (int i = 0; i < 1000; ++i) {
    unsigned long long nxt = (lane < 16 && i < 999) ? sp[(i + 1) * 16 + lane] : 0ull;
    unsigned long long wv = __shfl(myword, i >> 6);
    if ((wv >> (i & 63)) & 1ull) {
      if (lane < 16) myword &= ~cur;
    }
    cur = nxt;
  }
  if (lane < 16) aliveS[lane] = myword;
  __syncthreads();
  if (lane == 0) {
    int s = 0;
    for (int w = 0; w < 16; ++w) { pref[w] = s; s += __popcll(aliveS[w]); }
  }
  float* ro = rois + b * 4000;
  double* rd = rois64 + b * 4000;
  for (int k = lane; k < 4000; k += 64) { ro[k] = 0.0f; rd[k] = 0.0; }
  __syncthreads();
  for (int j = lane; j < 1000; j += 64) {
    int w = j >> 6;
    unsigned long long word = aliveS[w];
    if ((word >> (j & 63)) & 1ull) {
      unsigned long long below = (j & 63) ? (word & ((1ull << (j & 63)) - 1ull)) : 0ull;
      int slot = pref[w] + __popcll(below);
      const double* bp = sb + (b * 1000 + j) * 4;
      ro[slot * 4 + 0] = (float)bp[0]; ro[slot * 4 + 1] = (float)bp[1];
      ro[slot * 4 + 2] = (float)bp[2]; ro[slot * 4 + 3] = (float)bp[3];
      rd[slot * 4 + 0] = bp[0]; rd[slot * 4 + 1] = bp[1];
      rd[slot * 4 + 2] = bp[2]; rd[slot * 4 + 3] = bp[3];
    }
  }
}

// ---------------- ROI align: f64 sampling -> hi/lo bf16 feats ---------------
__global__ __launch_bounds__(256) void roi_align_d(
    const double* __restrict__ o2, const double* __restrict__ o3,
    const double* __restrict__ o4, const double* __restrict__ o5,
    const double* __restrict__ o6, const double* __restrict__ rois64,
    unsigned short* __restrict__ featsH, unsigned short* __restrict__ featsL) {
  __shared__ double s_wy[14], s_wx[14];
  __shared__ int s_y0[14], s_y1[14], s_x0[14], s_x1[14];
  const int t = threadIdx.x;
  const int b = blockIdx.x / 1000, r = blockIdx.x % 1000;
  const double* box = rois64 + (b * 1000 + r) * 4;
  double b0 = box[0], b1 = box[1], b2 = box[2], b3 = box[3];
  double h = b2 - b0, w = b3 - b1;
  double size = sqrt(fmax(h * w, 1e-8));
  double lf = floor(log2(size / 224.0) + 4.0);
  lf = fmin(fmax(lf, 2.0), 6.0);
  int lvl = (int)lf;
  int stride_i = 1 << lvl;
  double stride = (double)stride_i;
  int fs_i = 512 >> lvl;
  double fs = (double)fs_i;
  if (t < 14) {
    double v = b0 / stride + ((t + 0.5) * (h / stride)) / 14.0 - 0.5;
    v = fmin(fmax(v, 0.0), fs - 1.0);
    int i0 = (int)floor(v);
    s_y0[t] = i0; s_y1[t] = min(i0 + 1, fs_i - 1); s_wy[t] = v - (double)i0;
  } else if (t >= 64 && t < 78) {
    int u = t - 64;
    double v = b1 / stride + ((u + 0.5) * (w / stride)) / 14.0 - 0.5;
    v = fmin(fmax(v, 0.0), fs - 1.0);
    int i0 = (int)floor(v);
    s_x0[u] = i0; s_x1[u] = min(i0 + 1, fs_i - 1); s_wx[u] = v - (double)i0;
  }
  __syncthreads();
  const double* omaps[5] = {o2, o3, o4, o5, o6};
  const double* fm = omaps[lvl - 2] + (size_t)b * fs_i * fs_i * 256 + t;
  size_t obase = ((size_t)(b * 1000 + r) * 49) * 256 + t;
  for (int oy = 0; oy < 7; ++oy) {
    double acc[7] = {0, 0, 0, 0, 0, 0, 0};
#pragma unroll
    for (int sy = 0; sy < 2; ++sy) {
      int yy = oy * 2 + sy;
      int y0 = s_y0[yy], y1 = s_y1[yy];
      double wy = s_wy[yy];
      const double* r0 = fm + (size_t)y0 * fs_i * 256;
      const double* r1 = fm + (size_t)y1 * fs_i * 256;
      for (int ox = 0; ox < 7; ++ox) {
#pragma unroll
        for (int sx = 0; sx < 2; ++sx) {
          int xx = ox * 2 + sx;
          int x0 = s_x0[xx], x1 = s_x1[xx];
          double wx = s_wx[xx];
          double v00 = r0[x0 * 256], v01 = r0[x1 * 256];
          double v10 = r1[x0 * 256], v11 = r1[x1 * 256];
          double val = (1.0 - wy) * ((1.0 - wx) * v00 + wx * v01) +
                       wy * ((1.0 - wx) * v10 + wx * v11);
          acc[ox] += val;
        }
      }
    }
    for (int ox = 0; ox < 7; ++ox) {
      float v = (float)(acc[ox] * 0.25);
      unsigned short hh = f2bf(v);
      size_t idx = obase + (size_t)(oy * 7 + ox) * 256;
      featsH[idx] = hh;
      featsL[idx] = f2bf(v - bf2f(hh));
    }
  }
}

// ---------------- split f32 [K][N] -> bf16 hi/lo transposed [N][K] ----------
__global__ __launch_bounds__(256) void split_transpose(
    const float* __restrict__ W, unsigned short* __restrict__ TH,
    unsigned short* __restrict__ TL, int K, int N) {
  __shared__ unsigned short shh[32 * 33], shl[32 * 33];
  const int kt = blockIdx.y * 32, nt = blockIdx.x * 32;
  const int tx = threadIdx.x & 31, ty = threadIdx.x >> 5;   // 32x8
  for (int yy = ty; yy < 32; yy += 8) {
    float v = W[(size_t)(kt + yy) * N + nt + tx];
    unsigned short h = f2bf(v);
    shh[yy * 33 + tx] = h;
    shl[yy * 33 + tx] = f2bf(v - bf2f(h));
  }
  __syncthreads();
  for (int yy = ty; yy < 32; yy += 8) {
    TH[(size_t)(nt + yy) * K + kt + tx] = shh[tx * 33 + yy];
    TL[(size_t)(nt + yy) * K + kt + tx] = shl[tx * 33 + yy];
  }
}

// ---------------- split f32 rows -> bf16 hi/lo (no transpose) ---------------
__global__ void split_rows(const float* __restrict__ X, unsigned short* __restrict__ H,
                           unsigned short* __restrict__ L, int n) {
  int i = blockIdx.x * 256 + threadIdx.x;
  if (i < n) {
    float v = X[i];
    unsigned short h = f2bf(v);
    H[i] = h;
    L[i] = f2bf(v - bf2f(h));
  }
}

// ---------------- split-bf16 MFMA GEMM 128x128: C = relu?(A@B + bias) -------
// A (hi/lo) [M][K] bf16, BT (hi/lo) [N][K] bf16. Tile 128x128, BK=32.
// 4 waves: wave w -> n-half (w&1, 64 cols), m-half (w>>1, 64 rows); per wave
// 4x4 tiles of 16x16, 3 mfma each (aL*bH + aH*bL + aH*bH) — same per-output
// accumulation sequence as R4 (bitwise identical).
template <bool RELU>
__global__ __launch_bounds__(256) void gemm_mfma_split(
    const unsigned short* __restrict__ AH, const unsigned short* __restrict__ AL,
    const unsigned short* __restrict__ BTH, const unsigned short* __restrict__ BTL,
    const float* __restrict__ bias, float* __restrict__ C, int M, int N, int K) {
  __shared__ __align__(16) unsigned short AsH[128 * 40], AsL[128 * 40];
  __shared__ __align__(16) unsigned short BsH[128 * 40], BsL[128 * 40];
  const int t = threadIdx.x;
  const int lane = t & 63;
  const int wave = t >> 6;
  const int lm = lane & 15, lq = lane >> 4;
  const int wn = wave & 1, wm = wave >> 1;
  const int m0 = blockIdx.y * 128, n0 = blockIdx.x * 128;
  const int sr = t >> 1;            // 0..127
  const int sk = (t & 1) * 16;      // 0,16

  f4_t acc[4][4];
#pragma unroll
  for (int mt = 0; mt < 4; ++mt)
#pragma unroll
    for (int nt = 0; nt < 4; ++nt) acc[mt][nt] = (f4_t){0.f, 0.f, 0.f, 0.f};

  const uint4 zz = {0u, 0u, 0u, 0u};
  for (int k0 = 0; k0 < K; k0 += 32) {
    __syncthreads();
    // stage A 128x32 (hi/lo): thread -> row sr, k-halves sk..sk+15
    {
      uint4 vh0 = zz, vh1 = zz, vl0 = zz, vl1 = zz;
      if (m0 + sr < M) {
        size_t off = (size_t)(m0 + sr) * K + k0 + sk;
        vh0 = *(const uint4*)&AH[off];
        vh1 = *(const uint4*)&AH[off + 8];
        vl0 = *(const uint4*)&AL[off];
        vl1 = *(const uint4*)&AL[off + 8];
      }
      *(uint4*)&AsH[sr * 40 + sk] = vh0;
      *(uint4*)&AsH[sr * 40 + sk + 8] = vh1;
      *(uint4*)&AsL[sr * 40 + sk] = vl0;
      *(uint4*)&AsL[sr * 40 + sk + 8] = vl1;
    }
    // stage B 128x32 (hi/lo), rows n0..n0+127 of BT
    {
      size_t off = (size_t)(n0 + sr) * K + k0 + sk;
      *(uint4*)&BsH[sr * 40 + sk] = *(const uint4*)&BTH[off];
      *(uint4*)&BsH[sr * 40 + sk + 8] = *(const uint4*)&BTH[off + 8];
      *(uint4*)&BsL[sr * 40 + sk] = *(const uint4*)&BTL[off];
      *(uint4*)&BsL[sr * 40 + sk + 8] = *(const uint4*)&BTL[off + 8];
    }
    __syncthreads();

    bf8_t aH[4], aL[4], bH[4], bL[4];
#pragma unroll
    for (int mt = 0; mt < 4; ++mt) {
      int idx = (wm * 64 + mt * 16 + lm) * 40 + lq * 8;
      aH[mt] = *(const bf8_t*)&AsH[idx];
      aL[mt] = *(const bf8_t*)&AsL[idx];
    }
#pragma unroll
    for (int nt = 0; nt < 4; ++nt) {
      int idx = (wn * 64 + nt * 16 + lm) * 40 + lq * 8;
      bH[nt] = *(const bf8_t*)&BsH[idx];
      bL[nt] = *(const bf8_t*)&BsL[idx];
    }
#pragma unroll
    for (int mt = 0; mt < 4; ++mt)
#pragma unroll
      for (int nt = 0; nt < 4; ++nt) {
        f4_t a0 = acc[mt][nt];
        a0 = __builtin_amdgcn_mfma_f32_16x16x32_bf16(aL[mt], bH[nt], a0, 0, 0, 0);
        a0 = __builtin_amdgcn_mfma_f32_16x16x32_bf16(aH[mt], bL[nt], a0, 0, 0, 0);
        a0 = __builtin_amdgcn_mfma_f32_16x16x32_bf16(aH[mt], bH[nt], a0, 0, 0, 0);
        acc[mt][nt] = a0;
      }
  }
  // D layout (verified 16x16): col = lane&15, row = (lane>>4)*4 + reg
#pragma unroll
  for (int mt = 0; mt < 4; ++mt) {
#pragma unroll
    for (int nt = 0; nt < 4; ++nt) {
      int ncol = n0 + wn * 64 + nt * 16 + lm;
      float bb = bias[ncol];
#pragma unroll
      for (int r = 0; r < 4; ++r) {
        int m = m0 + wm * 64 + mt * 16 + lq * 4 + r;
        if (m < M) {
          float v = acc[mt][nt][r] + bb;
          if (RELU) v = fmaxf(v, 0.0f);
          C[(size_t)m * N + ncol] = v;
        }
      }
    }
  }
}

// ---------------- final box(4) + cls(81) heads, f32 -------------------------
__global__ __launch_bounds__(128) void boxcls_kernel(
    const float* __restrict__ x, const float* __restrict__ w_box,
    const float* __restrict__ b_box, const float* __restrict__ w_cls,
    const float* __restrict__ b_cls, float* __restrict__ out) {
  __shared__ float xv[1024];
  const int t = threadIdx.x;
  const int row = blockIdx.x;
  const float* xp = x + (size_t)row * 1024;
#pragma unroll
  for (int k = 0; k < 8; ++k) xv[k * 128 + t] = xp[k * 128 + t];
  __syncthreads();
  if (t < 4) {
    float acc = b_box[t];
    for (int k = 0; k < 1024; ++k) acc += xv[k] * w_box[k * 4 + t];
    out[8000 + row * 4 + t] = acc;
  } else if (t < 85) {
    int j = t - 4;
    float acc = b_cls[j];
    for (int k = 0; k < 1024; ++k) acc += xv[k] * w_cls[k * 81 + j];
    out[16000 + row * 81 + j] = acc;
  }
}

// ---------------------------------------------------------------------------
extern "C" void kernel_launch(void* const* d_in, const int* in_sizes, int n_in,
                              void* d_out, int out_size, void* d_ws, size_t ws_size,
                              hipStream_t stream) {
  (void)in_sizes; (void)n_in; (void)out_size; (void)ws_size;

  const float* c_in[4] = {(const float*)d_in[0], (const float*)d_in[1],
                          (const float*)d_in[2], (const float*)d_in[3]};
  const float *w_l[5], *b_l[5], *w_o[5], *b_o[5];
  for (int l = 0; l < 5; ++l) {
    w_l[l] = (const float*)d_in[4 + l * 4 + 0];
    b_l[l] = (const float*)d_in[4 + l * 4 + 1];
    w_o[l] = (const float*)d_in[4 + l * 4 + 2];
    b_o[l] = (const float*)d_in[4 + l * 4 + 3];
  }
  const float* w_rpn = (const float*)d_in[24];
  const float* b_rpn = (const float*)d_in[25];
  const float* w_obj = (const float*)d_in[26];
  const float* b_obj = (const float*)d_in[27];
  const float* w_dlt = (const float*)d_in[28];
  const float* b_dlt = (const float*)d_in[29];
  const float* w_fc1 = (const float*)d_in[30];
  const float* b_fc1 = (const float*)d_in[31];
  const float* w_fc2 = (const float*)d_in[32];
  const float* b_fc2 = (const float*)d_in[33];
  const float* w_box = (const float*)d_in[34];
  const float* b_box = (const float*)d_in[35];
  const float* w_cls = (const float*)d_in[36];
  const float* b_cls = (const float*)d_in[37];

  char* W8 = (char*)d_ws;
  double* o64 = (double*)(W8 + 0);
  double* p64 = (double*)(W8 + 89391104);
  float* c6buf = (float*)(W8 + 178782208);
  double* scores = (double*)(W8 + 179830784);
  double* boxes = (double*)(W8 + 182973440);
  double* ssb = (double*)(W8 + 195544064);
  double* sbb = (double*)(W8 + 195560064);
  double* rois64 = (double*)(W8 + 195624064);
  unsigned long long* suppb = (unsigned long long*)(W8 + 195688064);
  unsigned short* featsH = (unsigned short*)(W8 + 89391104);
  unsigned short* featsL = (unsigned short*)(W8 + 139567104);
  float* fc1b = (float*)(W8 + 0);
  float* fc2b = (float*)(W8 + 8192000);
  unsigned short* wT1H = (unsigned short*)(W8 + 16384000);
  unsigned short* wT1L = (unsigned short*)(W8 + 42074112);
  unsigned short* wT2H = (unsigned short*)(W8 + 67764224);
  unsigned short* wT2L = (unsigned short*)(W8 + 69861376);
  unsigned short* fc1H = (unsigned short*)(W8 + 71958528);
  unsigned short* fc1L = (unsigned short*)(W8 + 76054528);
  float* outf = (float*)d_out;

  const size_t OFF[5] = {0, 8388608, 10485760, 11010048, 11141120};
  double* o[5]; double* p[5];
  for (int l = 0; l < 5; ++l) { o[l] = o64 + OFF[l]; p[l] = p64 + OFF[l]; }

  const int HS[5] = {128, 64, 32, 16, 8};
  const int a_off[5] = {0, 147456, 184320, 193536, 195840};
  const double strides[5] = {4.0, 8.0, 16.0, 32.0, 64.0};
  const double SZ[5] = {16.0, 32.0, 64.0, 128.0, 256.0};
  AnchorHW anc[5];
  for (int l = 0; l < 5; ++l) {
    const double ars[3] = {0.5, 1.0, 2.0};
    for (int s = 0; s < 3; ++s) {
      double sc = pow(2.0, s / 3.0);
      for (int a = 0; a < 3; ++a) {
        double sq = sqrt(ars[a]);
        anc[l].hh[s * 3 + a] = SZ[l] * sc / sq;
        anc[l].ww[s * 3 + a] = SZ[l] * sc * sq;
      }
    }
  }

  // ---- FPN (f64) ----
  maxpool_kernel<<<1024, 256, 0, stream>>>(c_in[3], c6buf);
  lateral_d<2048><<<32, 256, 0, stream>>>(c6buf, w_l[4], b_l[4], p[4]);      // p6
  lateral_d<2048><<<128, 256, 0, stream>>>(c_in[3], w_l[3], b_l[3], p[3]);   // p5
  upadd_d<<<512, 256, 0, stream>>>(p[3], p[4], 16, 16);
  lateral_d<1024><<<512, 256, 0, stream>>>(c_in[2], w_l[2], b_l[2], p[2]);   // p4
  upadd_d<<<2048, 256, 0, stream>>>(p[2], p[3], 32, 32);
  lateral_d<512><<<2048, 256, 0, stream>>>(c_in[1], w_l[1], b_l[1], p[1]);   // p3
  upadd_d<<<8192, 256, 0, stream>>>(p[1], p[2], 64, 64);
  lateral_d<256><<<8192, 256, 0, stream>>>(c_in[0], w_l[0], b_l[0], p[0]);   // p2
  upadd_d<<<32768, 256, 0, stream>>>(p[0], p[1], 128, 128);

  // ---- fused 5-level conv passes ----
  Conv5Args co, ct;
  int total = 0;
  for (int l = 0; l < 5; ++l) {
    int nbx = (HS[l] + 15) / 16;
    co.in[l] = p[l]; co.out[l] = o[l]; co.w[l] = w_o[l]; co.b[l] = b_o[l];
    ct.in[l] = o[l]; ct.out[l] = p[l]; ct.w[l] = w_rpn;  ct.b[l] = b_rpn;
    co.H[l] = ct.H[l] = HS[l];
    co.nbx[l] = ct.nbx[l] = nbx;
    co.off[l] = ct.off[l] = total;
    total += nbx * HS[l] * 2;
  }
  co.off[5] = ct.off[5] = total;   // 2736
  conv3x3_fused<false><<<total, 256, 0, stream>>>(co);
  conv3x3_fused<true><<<total, 256, 0, stream>>>(ct);

  for (int l = 0; l < 5; ++l) {
    dim3 g(HS[l], HS[l], 2);
    rpn_head_d<<<g, 64, 0, stream>>>(p[l], w_obj, b_obj, w_dlt, b_dlt, scores, boxes,
                                     HS[l], HS[l], a_off[l], strides[l], anc[l]);
  }
  // ---- top-1000 + NMS (f64) ----
  topk_d<<<2, 1024, 0, stream>>>(scores, boxes, ssb, sbb);
  suppmat_d<<<125, 256, 0, stream>>>(sbb, suppb);
  nms_reduce_d<<<2, 64, 0, stream>>>(ssb, sbb, suppb, outf, rois64);
  // ---- ROI align (emits hi/lo bf16 feats) ----
  roi_align_d<<<2000, 256, 0, stream>>>(o[0], o[1], o[2], o[3], o[4], rois64,
                                        featsH, featsL);
  // ---- FC head: split weights (o64 now dead), then MFMA GEMMs ----
  split_transpose<<<dim3(32, 392), 256, 0, stream>>>(w_fc1, wT1H, wT1L, 12544, 1024);
  split_transpose<<<dim3(32, 32), 256, 0, stream>>>(w_fc2, wT2H, wT2L, 1024, 1024);
  gemm_mfma_split<true><<<dim3(8, 16), 256, 0, stream>>>(
      featsH, featsL, wT1H, wT1L, b_fc1, fc1b, 2000, 1024, 12544);
  split_rows<<<8000, 256, 0, stream>>>(fc1b, fc1H, fc1L, 2048000);
  gemm_mfma_split<true><<<dim3(8, 16), 256, 0, stream>>>(
      fc1H, fc1L, wT2H, wT2L, b_fc2, fc2b, 2000, 1024, 1024);
  boxcls_kernel<<<2000, 128, 0, stream>>>(fc2b, w_box, b_box, w_cls, b_cls, outf);
}

// Round 2
// 3668.972 us; speedup vs baseline: 1.2870x; 1.2582x over previous
//
#include <hip/hip_runtime.h>
#include <math.h>

// ---------------------------------------------------------------------------
// Faster-RCNN head. Round 7:
//  - conv3x3 passes moved OFF the f64 MFMA pipe (75% util = structural floor,
//    ~970us each) onto the f16 MFMA pipe via double-f16 split arithmetic:
//      x = xH + xL*2^-12 (lo plane pre-scaled by 2^12 to avoid f16 subnormals)
//      w = wH + wL*2^-12
//      product terms: xH*wH -> accA ; xH*wL' + xL'*wH -> accB (scale 2^12)
//      per-ky fold: dacc(f64) += accA + accB * 2^-12
//    Per-product error ~2^-23, total conv error ~5e-7 relative — below the
//    JAX-f32 reference's own rounding noise, so topk/NMS decisions preserved.
//  - Weights pre-split into f16 hi/lo planes laid out in MFMA B-frag order
//    (1 KB contiguous per (k-tile, cout-tile)), stored in the boxes/scores
//    scratch (dead until rpn_head runs after the convs).
//  - 32-pixel x-tiles (M=32), 256 cout, 4 waves (wave = cout quarter),
//    XOR-swizzled LDS (T2) for conflict-free ds_read_b128 of A-fragments.
//  - Everything else (laterals/rpn/topk/NMS/roi_align/fc GEMMs) unchanged.
//
// Workspace (BYTES):
//   o64  (double, 11,173,888 el)   [0          .. 89,391,104)
//   p64  (double, 11,173,888 el)   [89,391,104 .. 178,782,208)
//   c6   (float)                   [178,782,208 .. 179,830,784)
//   scores (double)                [179,830,784 .. 182,973,440)
//     (w_rpn f16 hi/lo planes live here until rpn_head writes scores)
//   boxes  (double)                [182,973,440 .. 195,544,064)
//     (w_o[0..4] f16 hi/lo planes live here until rpn_head writes boxes)
//   ss/sb/rois64/supp tail         [195,544,064 .. 195,944,064)
//   featsH/L (bf16) overlap p64+   [89,391,104 .. 189,743,104)   (after rpn)
//   fc region overlaps o64 (dead after roi_align)
// ---------------------------------------------------------------------------

#define NUM_ANCH 196416

typedef double d4 __attribute__((ext_vector_type(4)));
typedef __attribute__((ext_vector_type(8))) short bf8_t;
typedef __attribute__((ext_vector_type(4))) float f4_t;
typedef _Float16 h8_t __attribute__((ext_vector_type(8)));

__device__ inline unsigned short f2bf(float x) {
  unsigned u = __float_as_uint(x);
  unsigned r = (u + 0x7fffu + ((u >> 16) & 1u)) >> 16;   // RNE
  return (unsigned short)r;
}
__device__ inline float bf2f(unsigned short h) {
  return __uint_as_float(((unsigned)h) << 16);
}

// ---------------- maxpool2 c5 (2,16,16,2048) -> c6 (2,8,8,2048), f32 --------
__global__ void maxpool_kernel(const float* __restrict__ in, float* __restrict__ out) {
  int idx = blockIdx.x * 256 + threadIdx.x;     // 262144 total
  int c = idx & 2047;
  int x = (idx >> 11) & 7;
  int y = (idx >> 14) & 7;
  int b = idx >> 17;
  const float* p = in + (((size_t)b * 16 + 2 * y) * 16 + 2 * x) * 2048 + c;
  float m = fmaxf(fmaxf(p[0], p[2048]), fmaxf(p[16 * 2048], p[16 * 2048 + 2048]));
  out[idx] = m;
}

// ---------------- 1x1 lateral conv + bias, f32 in -> f64 out ----------------
template <int CIN>
__global__ __launch_bounds__(256) void lateral_d(
    const float* __restrict__ in, const float* __restrict__ w,
    const float* __restrict__ bias, double* __restrict__ out) {
  const int t = threadIdx.x;
  const size_t pix0 = (size_t)blockIdx.x * 4;
  double b = (double)bias[t];
  double a0 = b, a1 = b, a2 = b, a3 = b;
  const float* i0 = in + pix0 * CIN;
  for (int ci = 0; ci < CIN; ++ci) {
    double wv = (double)w[ci * 256 + t];
    a0 += (double)i0[ci] * wv;
    a1 += (double)i0[CIN + ci] * wv;
    a2 += (double)i0[2 * CIN + ci] * wv;
    a3 += (double)i0[3 * CIN + ci] * wv;
  }
  out[(pix0 + 0) * 256 + t] = a0;
  out[(pix0 + 1) * 256 + t] = a1;
  out[(pix0 + 2) * 256 + t] = a2;
  out[(pix0 + 3) * 256 + t] = a3;
}

// ---------------- fine += upsample2(coarse), C=256, f64 ---------------------
__global__ void upadd_d(double* __restrict__ fine, const double* __restrict__ coarse,
                        int Hf, int Wf) {
  int idx = blockIdx.x * 256 + threadIdx.x;
  int c = idx & 255;
  int rem = idx >> 8;
  int x = rem % Wf; rem /= Wf;
  int y = rem % Hf;
  int b = rem / Hf;
  fine[idx] += coarse[(((size_t)b * (Hf >> 1) + (y >> 1)) * (Wf >> 1) + (x >> 1)) * 256 + c];
}

// ---------------- weight split: f32 HWIO -> f16 hi/lo, B-frag layout --------
// in:  W[p9=ky*3+kx][ci][co] f32  (589,824 elements)
// out: plane[q][lm][ciw] with q=(p9*8+kt)*16+coT, kt=ci>>5, coT=co>>4,
//      lm=co&15, ciw=ci&31 — so a wave's B-frag (16 couts x 32 ci) is one
//      contiguous 1 KB block.
__global__ __launch_bounds__(256) void wsplit_f16(
    const float* __restrict__ W, unsigned short* __restrict__ PH,
    unsigned short* __restrict__ PL) {
  int id = blockIdx.x * 256 + threadIdx.x;      // 589824 total
  int co = id & 255, ci = (id >> 8) & 255, p9 = id >> 16;
  float w = W[id];
  _Float16 wh = (_Float16)w;
  float rw = (w - (float)wh) * 4096.0f;         // exact (Sterbenz) then *2^12
  _Float16 wl = (_Float16)rw;
  int q = (p9 * 8 + (ci >> 5)) * 16 + (co >> 4);
  int idx = q * 512 + (co & 15) * 32 + (ci & 31);
  PH[idx] = __builtin_bit_cast(unsigned short, wh);
  PL[idx] = __builtin_bit_cast(unsigned short, wl);
}

// ---------------- fused 5-level 3x3 conv, double-f16 MFMA -------------------
// Block = one y row x 32-pixel x-tile x 256 cout. 4 waves = cout quarters.
// Per wave: 2 M-tiles x 4 N-tiles; K=2304 (9 taps x 256 ch) as 72 k-tiles
// of 32; 3 mfma per (M,N,k-tile). f64 master accumulators folded per ky.
struct ConvArgsH {
  const double* in[5];
  double* out[5];
  const unsigned short* wH[5];
  const unsigned short* wL[5];
  const float* bias[5];
  int H[5];
  int nbx[5];
  int off[6];
};

template <bool RELU>
__global__ __launch_bounds__(256) void conv3x3_h2(ConvArgsH A) {
  // LDS: H plane [0,17408), L plane [17408,34816); 34 pixels x 256 ch f16,
  // XOR-swizzled (byte ^= (pix&7)<<4) for conflict-free ds_read_b128.
  __shared__ uint4 smemq[34816 / 16];
  char* sh = (char*)smemq;
  const int bx = blockIdx.x;
  int l = 0;
#pragma unroll
  for (int i = 1; i < 5; ++i)
    if (bx >= A.off[i]) l = i;
  const int rel = bx - A.off[l];
  const int H = A.H[l];
  const int W = H;
  const int nbx = A.nbx[l];
  const int x0 = (rel % nbx) * 32;
  const int y = (rel / nbx) % H;
  const int b = rel / (nbx * H);
  const double* __restrict__ in = A.in[l];
  double* __restrict__ out = A.out[l];
  const unsigned short* __restrict__ wHp = A.wH[l];
  const unsigned short* __restrict__ wLp = A.wL[l];
  const float* __restrict__ bias = A.bias[l];

  const int t = threadIdx.x;
  const int lane = t & 63;
  const int wq = t >> 6;        // cout quarter
  const int lm = lane & 15;     // A row (pixel) / B col (cout)
  const int lq = lane >> 4;     // k-subgroup of 8

  // f64 master accumulators, init with bias (all 4 regs share cout = col)
  d4 dacc[2][4];
#pragma unroll
  for (int mt = 0; mt < 2; ++mt)
#pragma unroll
    for (int nt = 0; nt < 4; ++nt) {
      double bv = (double)bias[wq * 64 + nt * 16 + lm];
      dacc[mt][nt] = (d4){bv, bv, bv, bv};
    }

  const int cst = (t & 127) * 2;   // staging channel pair
  const int prow = t >> 7;         // staging pixel parity

  for (int ky = 0; ky < 3; ++ky) {
    const int gy = y + ky - 1;
    __syncthreads();
    // stage 34 halo pixels (x0-1 .. x0+32) as f16 hi/lo pairs
    for (int pp = prow; pp < 34; pp += 2) {
      int gx = x0 + pp - 1;
      double xv0 = 0.0, xv1 = 0.0;
      if (gy >= 0 && gy < H && gx >= 0 && gx < W) {
        const double* ptr = in + (((size_t)b * H + gy) * W + gx) * 256 + cst;
        xv0 = ptr[0];
        xv1 = ptr[1];
      }
      _Float16 h0 = (_Float16)((float)xv0);
      _Float16 h1 = (_Float16)((float)xv1);
      float r0 = (float)(xv0 - (double)(float)h0) * 4096.0f;
      float r1 = (float)(xv1 - (double)(float)h1) * 4096.0f;
      _Float16 l0 = (_Float16)r0, l1 = (_Float16)r1;
      unsigned hp = (unsigned)__builtin_bit_cast(unsigned short, h0) |
                    ((unsigned)__builtin_bit_cast(unsigned short, h1) << 16);
      unsigned lp = (unsigned)__builtin_bit_cast(unsigned short, l0) |
                    ((unsigned)__builtin_bit_cast(unsigned short, l1) << 16);
      int bo = pp * 512 + ((cst * 2) ^ ((pp & 7) << 4));
      *(unsigned*)(sh + bo) = hp;
      *(unsigned*)(sh + 17408 + bo) = lp;
    }
    __syncthreads();

    f4_t accA[2][4], accB[2][4];
#pragma unroll
    for (int mt = 0; mt < 2; ++mt)
#pragma unroll
      for (int nt = 0; nt < 4; ++nt) {
        accA[mt][nt] = (f4_t){0.f, 0.f, 0.f, 0.f};
        accB[mt][nt] = (f4_t){0.f, 0.f, 0.f, 0.f};
      }

    for (int kx = 0; kx < 3; ++kx) {
      const int P0 = (ky * 3 + kx) * 8;
      for (int kt = 0; kt < 8; ++kt) {
        h8_t aH[2], aL[2];
#pragma unroll
        for (int mt = 0; mt < 2; ++mt) {
          int pix = mt * 16 + lm + kx;
          int bo = pix * 512 + ((kt * 64 + lq * 16) ^ ((pix & 7) << 4));
          aH[mt] = *(const h8_t*)(sh + bo);
          aL[mt] = *(const h8_t*)(sh + 17408 + bo);
        }
        h8_t bH[4], bL[4];
#pragma unroll
        for (int nt = 0; nt < 4; ++nt) {
          size_t eo = (size_t)((P0 + kt) * 16 + wq * 4 + nt) * 512 + lm * 32 + lq * 8;
          bH[nt] = *(const h8_t*)(wHp + eo);
          bL[nt] = *(const h8_t*)(wLp + eo);
        }
#pragma unroll
        for (int mt = 0; mt < 2; ++mt)
#pragma unroll
          for (int nt = 0; nt < 4; ++nt) {
            accB[mt][nt] = __builtin_amdgcn_mfma_f32_16x16x32_f16(aH[mt], bL[nt], accB[mt][nt], 0, 0, 0);
            accB[mt][nt] = __builtin_amdgcn_mfma_f32_16x16x32_f16(aL[mt], bH[nt], accB[mt][nt], 0, 0, 0);
            accA[mt][nt] = __builtin_amdgcn_mfma_f32_16x16x32_f16(aH[mt], bH[nt], accA[mt][nt], 0, 0, 0);
          }
      }
    }
    // fold into f64 (cross terms carry scale 2^12)
#pragma unroll
    for (int mt = 0; mt < 2; ++mt)
#pragma unroll
      for (int nt = 0; nt < 4; ++nt)
#pragma unroll
        for (int r = 0; r < 4; ++r)
          dacc[mt][nt][r] += (double)accA[mt][nt][r] +
                             (double)accB[mt][nt][r] * (1.0 / 4096.0);
  }

  // epilogue: D layout col=lane&15 (cout), row=(lane>>4)*4+r (pixel)
#pragma unroll
  for (int mt = 0; mt < 2; ++mt)
#pragma unroll
    for (int nt = 0; nt < 4; ++nt) {
      int cout = wq * 64 + nt * 16 + lm;
#pragma unroll
      for (int r = 0; r < 4; ++r) {
        int gx = x0 + mt * 16 + lq * 4 + r;
        if (gx < W) {
          double v = dacc[mt][nt][r];
          if (RELU) v = fmax(v, 0.0);
          out[(((size_t)b * H + y) * W + gx) * 256 + cout] = v;
        }
      }
    }
}

// ---------------- RPN head (obj + delta 1x1) + anchor decode, f64 -----------
struct AnchorHW { double hh[9]; double ww[9]; };

__global__ __launch_bounds__(64) void rpn_head_d(
    const double* __restrict__ tmap,
    const float* __restrict__ w_obj, const float* __restrict__ b_obj,
    const float* __restrict__ w_dlt, const float* __restrict__ b_dlt,
    double* __restrict__ scores, double* __restrict__ boxes,
    int H, int W, int a_off, double stride, AnchorHW anc) {
  __shared__ double tv[256];
  __shared__ double dlt[36];
  const int t = threadIdx.x;
  const int x = blockIdx.x, y = blockIdx.y, b = blockIdx.z;
  const double* px = tmap + (((size_t)b * H + y) * W + x) * 256;
  tv[t] = px[t]; tv[t + 64] = px[t + 64]; tv[t + 128] = px[t + 128]; tv[t + 192] = px[t + 192];
  __syncthreads();
  double sacc = 0.0;
  if (t < 9) {
    sacc = (double)b_obj[t];
    for (int ci = 0; ci < 256; ++ci) sacc += tv[ci] * (double)w_obj[ci * 9 + t];
  } else if (t < 45) {
    int j = t - 9;
    double a = (double)b_dlt[j];
    for (int ci = 0; ci < 256; ++ci) a += tv[ci] * (double)w_dlt[ci * 36 + j];
    dlt[j] = a;
  }
  __syncthreads();
  if (t < 9) {
    int ai = a_off + (y * W + x) * 9 + t;
    scores[(size_t)b * NUM_ANCH + ai] = sacc;
    double cy = (y + 0.5) * stride, cx = (x + 0.5) * stride;
    double hh = anc.hh[t], ww = anc.ww[t];
    float ay1 = (float)fmin(fmax(cy - hh * 0.5, 0.0), 512.0);
    float ax1 = (float)fmin(fmax(cx - ww * 0.5, 0.0), 512.0);
    float ay2 = (float)fmin(fmax(cy + hh * 0.5, 0.0), 512.0);
    float ax2 = (float)fmin(fmax(cx + ww * 0.5, 0.0), 512.0);
    float ahf = ay2 - ay1, awf = ax2 - ax1;
    float actyf = ay1 + ahf * 0.5f, actxf = ax1 + awf * 0.5f;
    double dy = dlt[t * 4 + 0], dx = dlt[t * 4 + 1];
    double dh = dlt[t * 4 + 2], dw = dlt[t * 4 + 3];
    double ncy = dy * (double)ahf + (double)actyf;
    double ncx = dx * (double)awf + (double)actxf;
    double nh = exp(dh) * (double)ahf;
    double nw = exp(dw) * (double)awf;
    double* bo = boxes + ((size_t)b * NUM_ANCH + ai) * 4;
    bo[0] = ncy - nh * 0.5;
    bo[1] = ncx - nw * 0.5;
    bo[2] = ncy + nh * 0.5;
    bo[3] = ncx + nw * 0.5;
  }
}

// ---------------- exact top-1000 per batch (f64 radix-select + bitonic) -----
__device__ inline unsigned long long dkey(double f) {
  unsigned long long u = (unsigned long long)__double_as_longlong(f);
  return u ^ ((unsigned long long)((long long)u >> 63) | 0x8000000000000000ull);
}

__global__ __launch_bounds__(1024) void topk_d(
    const double* __restrict__ scores, const double* __restrict__ boxes,
    double* __restrict__ ss, double* __restrict__ sb) {
  const int A = NUM_ANCH;
  __shared__ unsigned hist[256];
  __shared__ unsigned long long kk[2048];
  __shared__ unsigned id[2048];
  __shared__ unsigned long long s_prefix;
  __shared__ unsigned s_need, s_cnt;
  const int b = blockIdx.x, t = threadIdx.x;
  const double* sc = scores + (size_t)b * A;
  if (t == 0) { s_prefix = 0ull; s_need = 1000; s_cnt = 0; }
  __syncthreads();
  for (int r = 0; r < 8; ++r) {
    if (t < 256) hist[t] = 0;
    __syncthreads();
    const int shift = 56 - 8 * r;
    const unsigned long long prefix = s_prefix;
    unsigned long long maskHigh = 0ull;
    if (r != 0) maskHigh = (~0ull) << (shift + 8);
    for (int i = t; i < A; i += 1024) {
      unsigned long long k = dkey(sc[i]);
      if ((k & maskHigh) == prefix) atomicAdd(&hist[(unsigned)(k >> shift) & 255u], 1u);
    }
    __syncthreads();
    if (t == 0) {
      unsigned need = s_need, cum = 0;
      for (int bin = 255; bin >= 0; --bin) {
        cum += hist[bin];
        if (cum >= need) {
          s_prefix = prefix | ((unsigned long long)bin << shift);
          s_need = need - (cum - hist[bin]);
          break;
        }
      }
    }
    __syncthreads();
  }
  const unsigned long long K = s_prefix;
  for (int i = t; i < A; i += 1024) {
    unsigned long long k = dkey(sc[i]);
    if (k >= K) {
      unsigned pos = atomicAdd(&s_cnt, 1u);
      if (pos < 2048) { kk[pos] = k; id[pos] = (unsigned)i; }
    }
  }
  __syncthreads();
  unsigned cnt = s_cnt;
  for (int i = t; i < 2048; i += 1024)
    if (i >= cnt) { kk[i] = 0ull; id[i] = 0xFFFFFFFFu; }
  __syncthreads();
  for (int k = 2; k <= 2048; k <<= 1) {
    for (int j = k >> 1; j > 0; j >>= 1) {
#pragma unroll
      for (int u = 0; u < 2; ++u) {
        int i = t + u * 1024;
        int ixj = i ^ j;
        if (ixj > i) {
          unsigned long long ka = kk[i], kc = kk[ixj];
          unsigned ia = id[i], ic = id[ixj];
          bool cPrec = (kc > ka) || (kc == ka && ic < ia);
          bool up = (i & k) != 0;
          if (cPrec != up) { kk[i] = kc; kk[ixj] = ka; id[i] = ic; id[ixj] = ia; }
        }
      }
      __syncthreads();
    }
  }
  if (t < 1000) {
    unsigned idx = id[t];
    ss[b * 1000 + t] = sc[idx];
    const double* bp = boxes + ((size_t)b * A + idx) * 4;
    double* op = sb + (b * 1000 + t) * 4;
    op[0] = bp[0]; op[1] = bp[1]; op[2] = bp[2]; op[3] = bp[3];
  }
}

// ---------------- suppression bit-matrix (iou>0.7 & j>i), f64 ---------------
__global__ void suppmat_d(const double* __restrict__ sb,
                          unsigned long long* __restrict__ supp) {
  int g = blockIdx.x * 256 + threadIdx.x;   // 32000 = 2*1000*16
  int w = g & 15;
  int i = (g >> 4) % 1000;
  int b = g / 16000;
  const double* bx = sb + b * 4000;
  double y1 = bx[i * 4 + 0], x1 = bx[i * 4 + 1], y2 = bx[i * 4 + 2], x2 = bx[i * 4 + 3];
  double ai = (y2 - y1) * (x2 - x1);
  unsigned long long m = 0;
  for (int q = 0; q < 64; ++q) {
    int j = w * 64 + q;
    if (j > i && j < 1000) {
      double by1 = bx[j * 4 + 0], bx1 = bx[j * 4 + 1], by2 = bx[j * 4 + 2], bx2 = bx[j * 4 + 3];
      double aj = (by2 - by1) * (bx2 - bx1);
      double iy1 = fmax(y1, by1), ix1 = fmax(x1, bx1);
      double iy2 = fmin(y2, by2), ix2 = fmin(x2, bx2);
      double inter = fmax(iy2 - iy1, 0.0) * fmax(ix2 - ix1, 0.0);
      double iou = inter / (ai + aj - inter + 1e-8);
      if (iou > 0.7) m |= (1ull << q);
    }
  }
  supp[g] = m;
}

// ---------------- greedy NMS reduce + slot scatter --------------------------
__global__ __launch_bounds__(64) void nms_reduce_d(
    const double* __restrict__ ss, const double* __restrict__ sb,
    const unsigned long long* __restrict__ supp,
    float* __restrict__ rois, double* __restrict__ rois64) {
  __shared__ unsigned long long aliveS[16];
  __shared__ int pref[16];
  const int b = blockIdx.x, lane = threadIdx.x;
  unsigned long long myword = 0;
  if (lane < 16) {
    for (int q = 0; q < 64; ++q) {
      int j = lane * 64 + q;
      if (j < 1000 && ss[b * 1000 + j] > 0.0) myword |= (1ull << q);
    }
  }
  const unsigned long long* sp = supp + (size_t)b * 16000;
  unsigned long long cur = (lane < 16) ? sp[lane] : 0ull;
  for (int i = 0; i < 1000; ++i) {
    unsigned long long nxt = (lane < 16 && i < 999) ? sp[(i + 1) * 16 + lane] : 0ull;
    unsigned long long wv = __shfl(myword, i >> 6);
    if ((wv >> (i & 63)) & 1ull) {
      if (lane < 16) myword &= ~cur;
    }
    cur = nxt;
  }
  if (lane < 16) aliveS[lane] = myword;
  __syncthreads();
  if (lane == 0) {
    int s = 0;
    for (int w = 0; w < 16; ++w) { pref[w] = s; s += __popcll(aliveS[w]); }
  }
  float* ro = rois + b * 4000;
  double* rd = rois64 + b * 4000;
  for (int k = lane; k < 4000; k += 64) { ro[k] = 0.0f; rd[k] = 0.0; }
  __syncthreads();
  for (int j = lane; j < 1000; j += 64) {
    int w = j >> 6;
    unsigned long long word = aliveS[w];
    if ((word >> (j & 63)) & 1ull) {
      unsigned long long below = (j & 63) ? (word & ((1ull << (j & 63)) - 1ull)) : 0ull;
      int slot = pref[w] + __popcll(below);
      const double* bp = sb + (b * 1000 + j) * 4;
      ro[slot * 4 + 0] = (float)bp[0]; ro[slot * 4 + 1] = (float)bp[1];
      ro[slot * 4 + 2] = (float)bp[2]; ro[slot * 4 + 3] = (float)bp[3];
      rd[slot * 4 + 0] = bp[0]; rd[slot * 4 + 1] = bp[1];
      rd[slot * 4 + 2] = bp[2]; rd[slot * 4 + 3] = bp[3];
    }
  }
}

// ---------------- ROI align: f64 sampling -> hi/lo bf16 feats ---------------
__global__ __launch_bounds__(256) void roi_align_d(
    const double* __restrict__ o2, const double* __restrict__ o3,
    const double* __restrict__ o4, const double* __restrict__ o5,
    const double* __restrict__ o6, const double* __restrict__ rois64,
    unsigned short* __restrict__ featsH, unsigned short* __restrict__ featsL) {
  __shared__ double s_wy[14], s_wx[14];
  __shared__ int s_y0[14], s_y1[14], s_x0[14], s_x1[14];
  const int t = threadIdx.x;
  const int b = blockIdx.x / 1000, r = blockIdx.x % 1000;
  const double* box = rois64 + (b * 1000 + r) * 4;
  double b0 = box[0], b1 = box[1], b2 = box[2], b3 = box[3];
  double h = b2 - b0, w = b3 - b1;
  double size = sqrt(fmax(h * w, 1e-8));
  double lf = floor(log2(size / 224.0) + 4.0);
  lf = fmin(fmax(lf, 2.0), 6.0);
  int lvl = (int)lf;
  int stride_i = 1 << lvl;
  double stride = (double)stride_i;
  int fs_i = 512 >> lvl;
  double fs = (double)fs_i;
  if (t < 14) {
    double v = b0 / stride + ((t + 0.5) * (h / stride)) / 14.0 - 0.5;
    v = fmin(fmax(v, 0.0), fs - 1.0);
    int i0 = (int)floor(v);
    s_y0[t] = i0; s_y1[t] = min(i0 + 1, fs_i - 1); s_wy[t] = v - (double)i0;
  } else if (t >= 64 && t < 78) {
    int u = t - 64;
    double v = b1 / stride + ((u + 0.5) * (w / stride)) / 14.0 - 0.5;
    v = fmin(fmax(v, 0.0), fs - 1.0);
    int i0 = (int)floor(v);
    s_x0[u] = i0; s_x1[u] = min(i0 + 1, fs_i - 1); s_wx[u] = v - (double)i0;
  }
  __syncthreads();
  const double* omaps[5] = {o2, o3, o4, o5, o6};
  const double* fm = omaps[lvl - 2] + (size_t)b * fs_i * fs_i * 256 + t;
  size_t obase = ((size_t)(b * 1000 + r) * 49) * 256 + t;
  for (int oy = 0; oy < 7; ++oy) {
    double acc[7] = {0, 0, 0, 0, 0, 0, 0};
#pragma unroll
    for (int sy = 0; sy < 2; ++sy) {
      int yy = oy * 2 + sy;
      int y0 = s_y0[yy], y1 = s_y1[yy];
      double wy = s_wy[yy];
      const double* r0 = fm + (size_t)y0 * fs_i * 256;
      const double* r1 = fm + (size_t)y1 * fs_i * 256;
      for (int ox = 0; ox < 7; ++ox) {
#pragma unroll
        for (int sx = 0; sx < 2; ++sx) {
          int xx = ox * 2 + sx;
          int x0 = s_x0[xx], x1 = s_x1[xx];
          double wx = s_wx[xx];
          double v00 = r0[x0 * 256], v01 = r0[x1 * 256];
          double v10 = r1[x0 * 256], v11 = r1[x1 * 256];
          double val = (1.0 - wy) * ((1.0 - wx) * v00 + wx * v01) +
                       wy * ((1.0 - wx) * v10 + wx * v11);
          acc[ox] += val;
        }
      }
    }
    for (int ox = 0; ox < 7; ++ox) {
      float v = (float)(acc[ox] * 0.25);
      unsigned short hh = f2bf(v);
      size_t idx = obase + (size_t)(oy * 7 + ox) * 256;
      featsH[idx] = hh;
      featsL[idx] = f2bf(v - bf2f(hh));
    }
  }
}

// ---------------- split f32 [K][N] -> bf16 hi/lo transposed [N][K] ----------
__global__ __launch_bounds__(256) void split_transpose(
    const float* __restrict__ W, unsigned short* __restrict__ TH,
    unsigned short* __restrict__ TL, int K, int N) {
  __shared__ unsigned short shh[32 * 33], shl[32 * 33];
  const int kt = blockIdx.y * 32, nt = blockIdx.x * 32;
  const int tx = threadIdx.x & 31, ty = threadIdx.x >> 5;   // 32x8
  for (int yy = ty; yy < 32; yy += 8) {
    float v = W[(size_t)(kt + yy) * N + nt + tx];
    unsigned short h = f2bf(v);
    shh[yy * 33 + tx] = h;
    shl[yy * 33 + tx] = f2bf(v - bf2f(h));
  }
  __syncthreads();
  for (int yy = ty; yy < 32; yy += 8) {
    TH[(size_t)(nt + yy) * K + kt + tx] = shh[tx * 33 + yy];
    TL[(size_t)(nt + yy) * K + kt + tx] = shl[tx * 33 + yy];
  }
}

// ---------------- split f32 rows -> bf16 hi/lo (no transpose) ---------------
__global__ void split_rows(const float* __restrict__ X, unsigned short* __restrict__ H,
                           unsigned short* __restrict__ L, int n) {
  int i = blockIdx.x * 256 + threadIdx.x;
  if (i < n) {
    float v = X[i];
    unsigned short h = f2bf(v);
    H[i] = h;
    L[i] = f2bf(v - bf2f(h));
  }
}

// ---------------- split-bf16 MFMA GEMM 128x128: C = relu?(A@B + bias) -------
template <bool RELU>
__global__ __launch_bounds__(256) void gemm_mfma_split(
    const unsigned short* __restrict__ AH, const unsigned short* __restrict__ AL,
    const unsigned short* __restrict__ BTH, const unsigned short* __restrict__ BTL,
    const float* __restrict__ bias, float* __restrict__ C, int M, int N, int K) {
  __shared__ __align__(16) unsigned short AsH[128 * 40], AsL[128 * 40];
  __shared__ __align__(16) unsigned short BsH[128 * 40], BsL[128 * 40];
  const int t = threadIdx.x;
  const int lane = t & 63;
  const int wave = t >> 6;
  const int lm = lane & 15, lq = lane >> 4;
  const int wn = wave & 1, wm = wave >> 1;
  const int m0 = blockIdx.y * 128, n0 = blockIdx.x * 128;
  const int sr = t >> 1;            // 0..127
  const int sk = (t & 1) * 16;      // 0,16

  f4_t acc[4][4];
#pragma unroll
  for (int mt = 0; mt < 4; ++mt)
#pragma unroll
    for (int nt = 0; nt < 4; ++nt) acc[mt][nt] = (f4_t){0.f, 0.f, 0.f, 0.f};

  const uint4 zz = {0u, 0u, 0u, 0u};
  for (int k0 = 0; k0 < K; k0 += 32) {
    __syncthreads();
    {
      uint4 vh0 = zz, vh1 = zz, vl0 = zz, vl1 = zz;
      if (m0 + sr < M) {
        size_t off = (size_t)(m0 + sr) * K + k0 + sk;
        vh0 = *(const uint4*)&AH[off];
        vh1 = *(const uint4*)&AH[off + 8];
        vl0 = *(const uint4*)&AL[off];
        vl1 = *(const uint4*)&AL[off + 8];
      }
      *(uint4*)&AsH[sr * 40 + sk] = vh0;
      *(uint4*)&AsH[sr * 40 + sk + 8] = vh1;
      *(uint4*)&AsL[sr * 40 + sk] = vl0;
      *(uint4*)&AsL[sr * 40 + sk + 8] = vl1;
    }
    {
      size_t off = (size_t)(n0 + sr) * K + k0 + sk;
      *(uint4*)&BsH[sr * 40 + sk] = *(const uint4*)&BTH[off];
      *(uint4*)&BsH[sr * 40 + sk + 8] = *(const uint4*)&BTH[off + 8];
      *(uint4*)&BsL[sr * 40 + sk] = *(const uint4*)&BTL[off];
      *(uint4*)&BsL[sr * 40 + sk + 8] = *(const uint4*)&BTL[off + 8];
    }
    __syncthreads();

    bf8_t aH[4], aL[4], bH[4], bL[4];
#pragma unroll
    for (int mt = 0; mt < 4; ++mt) {
      int idx = (wm * 64 + mt * 16 + lm) * 40 + lq * 8;
      aH[mt] = *(const bf8_t*)&AsH[idx];
      aL[mt] = *(const bf8_t*)&AsL[idx];
    }
#pragma unroll
    for (int nt = 0; nt < 4; ++nt) {
      int idx = (wn * 64 + nt * 16 + lm) * 40 + lq * 8;
      bH[nt] = *(const bf8_t*)&BsH[idx];
      bL[nt] = *(const bf8_t*)&BsL[idx];
    }
#pragma unroll
    for (int mt = 0; mt < 4; ++mt)
#pragma unroll
      for (int nt = 0; nt < 4; ++nt) {
        f4_t a0 = acc[mt][nt];
        a0 = __builtin_amdgcn_mfma_f32_16x16x32_bf16(aL[mt], bH[nt], a0, 0, 0, 0);
        a0 = __builtin_amdgcn_mfma_f32_16x16x32_bf16(aH[mt], bL[nt], a0, 0, 0, 0);
        a0 = __builtin_amdgcn_mfma_f32_16x16x32_bf16(aH[mt], bH[nt], a0, 0, 0, 0);
        acc[mt][nt] = a0;
      }
  }
#pragma unroll
  for (int mt = 0; mt < 4; ++mt) {
#pragma unroll
    for (int nt = 0; nt < 4; ++nt) {
      int ncol = n0 + wn * 64 + nt * 16 + lm;
      float bb = bias[ncol];
#pragma unroll
      for (int r = 0; r < 4; ++r) {
        int m = m0 + wm * 64 + mt * 16 + lq * 4 + r;
        if (m < M) {
          float v = acc[mt][nt][r] + bb;
          if (RELU) v = fmaxf(v, 0.0f);
          C[(size_t)m * N + ncol] = v;
        }
      }
    }
  }
}

// ---------------- final box(4) + cls(81) heads, f32 -------------------------
__global__ __launch_bounds__(128) void boxcls_kernel(
    const float* __restrict__ x, const float* __restrict__ w_box,
    const float* __restrict__ b_box, const float* __restrict__ w_cls,
    const float* __restrict__ b_cls, float* __restrict__ out) {
  __shared__ float xv[1024];
  const int t = threadIdx.x;
  const int row = blockIdx.x;
  const float* xp = x + (size_t)row * 1024;
#pragma unroll
  for (int k = 0; k < 8; ++k) xv[k * 128 + t] = xp[k * 128 + t];
  __syncthreads();
  if (t < 4) {
    float acc = b_box[t];
    for (int k = 0; k < 1024; ++k) acc += xv[k] * w_box[k * 4 + t];
    out[8000 + row * 4 + t] = acc;
  } else if (t < 85) {
    int j = t - 4;
    float acc = b_cls[j];
    for (int k = 0; k < 1024; ++k) acc += xv[k] * w_cls[k * 81 + j];
    out[16000 + row * 81 + j] = acc;
  }
}

// ---------------------------------------------------------------------------
extern "C" void kernel_launch(void* const* d_in, const int* in_sizes, int n_in,
                              void* d_out, int out_size, void* d_ws, size_t ws_size,
                              hipStream_t stream) {
  (void)in_sizes; (void)n_in; (void)out_size; (void)ws_size;

  const float* c_in[4] = {(const float*)d_in[0], (const float*)d_in[1],
                          (const float*)d_in[2], (const float*)d_in[3]};
  const float *w_l[5], *b_l[5], *w_o[5], *b_o[5];
  for (int l = 0; l < 5; ++l) {
    w_l[l] = (const float*)d_in[4 + l * 4 + 0];
    b_l[l] = (const float*)d_in[4 + l * 4 + 1];
    w_o[l] = (const float*)d_in[4 + l * 4 + 2];
    b_o[l] = (const float*)d_in[4 + l * 4 + 3];
  }
  const float* w_rpn = (const float*)d_in[24];
  const float* b_rpn = (const float*)d_in[25];
  const float* w_obj = (const float*)d_in[26];
  const float* b_obj = (const float*)d_in[27];
  const float* w_dlt = (const float*)d_in[28];
  const float* b_dlt = (const float*)d_in[29];
  const float* w_fc1 = (const float*)d_in[30];
  const float* b_fc1 = (const float*)d_in[31];
  const float* w_fc2 = (const float*)d_in[32];
  const float* b_fc2 = (const float*)d_in[33];
  const float* w_box = (const float*)d_in[34];
  const float* b_box = (const float*)d_in[35];
  const float* w_cls = (const float*)d_in[36];
  const float* b_cls = (const float*)d_in[37];

  char* W8 = (char*)d_ws;
  double* o64 = (double*)(W8 + 0);
  double* p64 = (double*)(W8 + 89391104);
  float* c6buf = (float*)(W8 + 178782208);
  double* scores = (double*)(W8 + 179830784);
  double* boxes = (double*)(W8 + 182973440);
  double* ssb = (double*)(W8 + 195544064);
  double* sbb = (double*)(W8 + 195560064);
  double* rois64 = (double*)(W8 + 195624064);
  unsigned long long* suppb = (unsigned long long*)(W8 + 195688064);
  unsigned short* featsH = (unsigned short*)(W8 + 89391104);
  unsigned short* featsL = (unsigned short*)(W8 + 139567104);
  float* fc1b = (float*)(W8 + 0);
  float* fc2b = (float*)(W8 + 8192000);
  unsigned short* wT1H = (unsigned short*)(W8 + 16384000);
  unsigned short* wT1L = (unsigned short*)(W8 + 42074112);
  unsigned short* wT2H = (unsigned short*)(W8 + 67764224);
  unsigned short* wT2L = (unsigned short*)(W8 + 69861376);
  unsigned short* fc1H = (unsigned short*)(W8 + 71958528);
  unsigned short* fc1L = (unsigned short*)(W8 + 76054528);
  float* outf = (float*)d_out;

  // conv f16 weight planes: w_o sets in boxes region, w_rpn in scores region
  // (both dead until rpn_head runs, which is after both conv passes)
  unsigned short* woH[5];
  unsigned short* woL[5];
  for (int l = 0; l < 5; ++l) {
    woH[l] = (unsigned short*)(W8 + 182973440 + (size_t)l * 2359296);
    woL[l] = (unsigned short*)(W8 + 182973440 + (size_t)l * 2359296 + 1179648);
  }
  unsigned short* wrH = (unsigned short*)(W8 + 179830784);
  unsigned short* wrL = (unsigned short*)(W8 + 179830784 + 1179648);

  const size_t OFF[5] = {0, 8388608, 10485760, 11010048, 11141120};
  double* o[5]; double* p[5];
  for (int l = 0; l < 5; ++l) { o[l] = o64 + OFF[l]; p[l] = p64 + OFF[l]; }

  const int HS[5] = {128, 64, 32, 16, 8};
  const int a_off[5] = {0, 147456, 184320, 193536, 195840};
  const double strides[5] = {4.0, 8.0, 16.0, 32.0, 64.0};
  const double SZ[5] = {16.0, 32.0, 64.0, 128.0, 256.0};
  AnchorHW anc[5];
  for (int l = 0; l < 5; ++l) {
    const double ars[3] = {0.5, 1.0, 2.0};
    for (int s = 0; s < 3; ++s) {
      double sc = pow(2.0, s / 3.0);
      for (int a = 0; a < 3; ++a) {
        double sq = sqrt(ars[a]);
        anc[l].hh[s * 3 + a] = SZ[l] * sc / sq;
        anc[l].ww[s * 3 + a] = SZ[l] * sc * sq;
      }
    }
  }

  // ---- weight split for conv passes (independent of FPN) ----
  for (int l = 0; l < 5; ++l)
    wsplit_f16<<<2304, 256, 0, stream>>>(w_o[l], woH[l], woL[l]);
  wsplit_f16<<<2304, 256, 0, stream>>>(w_rpn, wrH, wrL);

  // ---- FPN (f64) ----
  maxpool_kernel<<<1024, 256, 0, stream>>>(c_in[3], c6buf);
  lateral_d<2048><<<32, 256, 0, stream>>>(c6buf, w_l[4], b_l[4], p[4]);      // p6
  lateral_d<2048><<<128, 256, 0, stream>>>(c_in[3], w_l[3], b_l[3], p[3]);   // p5
  upadd_d<<<512, 256, 0, stream>>>(p[3], p[4], 16, 16);
  lateral_d<1024><<<512, 256, 0, stream>>>(c_in[2], w_l[2], b_l[2], p[2]);   // p4
  upadd_d<<<2048, 256, 0, stream>>>(p[2], p[3], 32, 32);
  lateral_d<512><<<2048, 256, 0, stream>>>(c_in[1], w_l[1], b_l[1], p[1]);   // p3
  upadd_d<<<8192, 256, 0, stream>>>(p[1], p[2], 64, 64);
  lateral_d<256><<<8192, 256, 0, stream>>>(c_in[0], w_l[0], b_l[0], p[0]);   // p2
  upadd_d<<<32768, 256, 0, stream>>>(p[0], p[1], 128, 128);

  // ---- fused 5-level conv passes (double-f16 MFMA) ----
  ConvArgsH co, ct;
  int total = 0;
  for (int l = 0; l < 5; ++l) {
    int nbx = (HS[l] + 31) / 32;
    co.in[l] = p[l]; co.out[l] = o[l];
    co.wH[l] = woH[l]; co.wL[l] = woL[l]; co.bias[l] = b_o[l];
    ct.in[l] = o[l]; ct.out[l] = p[l];
    ct.wH[l] = wrH;  ct.wL[l] = wrL;  ct.bias[l] = b_rpn;
    co.H[l] = ct.H[l] = HS[l];
    co.nbx[l] = ct.nbx[l] = nbx;
    co.off[l] = ct.off[l] = total;
    total += nbx * HS[l] * 2;
  }
  co.off[5] = ct.off[5] = total;   // 1392
  conv3x3_h2<false><<<total, 256, 0, stream>>>(co);
  conv3x3_h2<true><<<total, 256, 0, stream>>>(ct);

  for (int l = 0; l < 5; ++l) {
    dim3 g(HS[l], HS[l], 2);
    rpn_head_d<<<g, 64, 0, stream>>>(p[l], w_obj, b_obj, w_dlt, b_dlt, scores, boxes,
                                     HS[l], HS[l], a_off[l], strides[l], anc[l]);
  }
  // ---- top-1000 + NMS (f64) ----
  topk_d<<<2, 1024, 0, stream>>>(scores, boxes, ssb, sbb);
  suppmat_d<<<125, 256, 0, stream>>>(sbb, suppb);
  nms_reduce_d<<<2, 64, 0, stream>>>(ssb, sbb, suppb, outf, rois64);
  // ---- ROI align (emits hi/lo bf16 feats) ----
  roi_align_d<<<2000, 256, 0, stream>>>(o[0], o[1], o[2], o[3], o[4], rois64,
                                        featsH, featsL);
  // ---- FC head: split weights (o64 now dead), then MFMA GEMMs ----
  split_transpose<<<dim3(32, 392), 256, 0, stream>>>(w_fc1, wT1H, wT1L, 12544, 1024);
  split_transpose<<<dim3(32, 32), 256, 0, stream>>>(w_fc2, wT2H, wT2L, 1024, 1024);
  gemm_mfma_split<true><<<dim3(8, 16), 256, 0, stream>>>(
      featsH, featsL, wT1H, wT1L, b_fc1, fc1b, 2000, 1024, 12544);
  split_rows<<<8000, 256, 0, stream>>>(fc1b, fc1H, fc1L, 2048000);
  gemm_mfma_split<true><<<dim3(8, 16), 256, 0, stream>>>(
      fc1H, fc1L, wT2H, wT2L, b_fc2, fc2b, 2000, 1024, 1024);
  boxcls_kernel<<<2000, 128, 0, stream>>>(fc2b, w_box, b_box, w_cls, b_cls, outf);
}

// Round 3
// 3304.385 us; speedup vs baseline: 1.4290x; 1.1103x over previous
//
#include <hip/hip_runtime.h>
#include <math.h>

// ---------------------------------------------------------------------------
// Faster-RCNN head. Round 8:
//  - fc GEMMs (gemm_mfma_split) were occupancy-starved: 128 blocks on 256 CUs
//    (Occupancy 5.9%, MfmaUtil 12%, HBM 11%) — pure latency bound. Now
//    split-K x4: grid (8,16,4) = 512 blocks, each computing a K/4 chunk into
//    f32 partial buffers; a reduce pass applies bias+relu. For fc1 the reduce
//    fuses the bf16 hi/lo split (split_rows eliminated).
//  - Partial/output placement vs live ranges:
//      fc1 partials: kc0->fc1b[0), kc1->8,192,000, kc2->71,958,528,
//                    kc3->80,150,528   (all dead during fc1 GEMM)
//      fc1H/L moved to 89,391,104 / 93,487,104 (featsH region, dead at reduce)
//      fc2 partials: kc0->fc2b, kc1->0, kc2->16,384,000, kc3->24,576,000
//                    (fc1b + wT1 regions, dead after fc1 GEMM)
//  - conv3x3 double-f16 MFMA path (R7) unchanged; rois path still f64-exact.
// ---------------------------------------------------------------------------

#define NUM_ANCH 196416

typedef double d4 __attribute__((ext_vector_type(4)));
typedef __attribute__((ext_vector_type(8))) short bf8_t;
typedef __attribute__((ext_vector_type(4))) float f4_t;
typedef _Float16 h8_t __attribute__((ext_vector_type(8)));

__device__ inline unsigned short f2bf(float x) {
  unsigned u = __float_as_uint(x);
  unsigned r = (u + 0x7fffu + ((u >> 16) & 1u)) >> 16;   // RNE
  return (unsigned short)r;
}
__device__ inline float bf2f(unsigned short h) {
  return __uint_as_float(((unsigned)h) << 16);
}

// ---------------- maxpool2 c5 (2,16,16,2048) -> c6 (2,8,8,2048), f32 --------
__global__ void maxpool_kernel(const float* __restrict__ in, float* __restrict__ out) {
  int idx = blockIdx.x * 256 + threadIdx.x;     // 262144 total
  int c = idx & 2047;
  int x = (idx >> 11) & 7;
  int y = (idx >> 14) & 7;
  int b = idx >> 17;
  const float* p = in + (((size_t)b * 16 + 2 * y) * 16 + 2 * x) * 2048 + c;
  float m = fmaxf(fmaxf(p[0], p[2048]), fmaxf(p[16 * 2048], p[16 * 2048 + 2048]));
  out[idx] = m;
}

// ---------------- 1x1 lateral conv + bias, f32 in -> f64 out ----------------
template <int CIN>
__global__ __launch_bounds__(256) void lateral_d(
    const float* __restrict__ in, const float* __restrict__ w,
    const float* __restrict__ bias, double* __restrict__ out) {
  const int t = threadIdx.x;
  const size_t pix0 = (size_t)blockIdx.x * 4;
  double b = (double)bias[t];
  double a0 = b, a1 = b, a2 = b, a3 = b;
  const float* i0 = in + pix0 * CIN;
  for (int ci = 0; ci < CIN; ++ci) {
    double wv = (double)w[ci * 256 + t];
    a0 += (double)i0[ci] * wv;
    a1 += (double)i0[CIN + ci] * wv;
    a2 += (double)i0[2 * CIN + ci] * wv;
    a3 += (double)i0[3 * CIN + ci] * wv;
  }
  out[(pix0 + 0) * 256 + t] = a0;
  out[(pix0 + 1) * 256 + t] = a1;
  out[(pix0 + 2) * 256 + t] = a2;
  out[(pix0 + 3) * 256 + t] = a3;
}

// ---------------- fine += upsample2(coarse), C=256, f64 ---------------------
__global__ void upadd_d(double* __restrict__ fine, const double* __restrict__ coarse,
                        int Hf, int Wf) {
  int idx = blockIdx.x * 256 + threadIdx.x;
  int c = idx & 255;
  int rem = idx >> 8;
  int x = rem % Wf; rem /= Wf;
  int y = rem % Hf;
  int b = rem / Hf;
  fine[idx] += coarse[(((size_t)b * (Hf >> 1) + (y >> 1)) * (Wf >> 1) + (x >> 1)) * 256 + c];
}

// ---------------- weight split: f32 HWIO -> f16 hi/lo, B-frag layout --------
__global__ __launch_bounds__(256) void wsplit_f16(
    const float* __restrict__ W, unsigned short* __restrict__ PH,
    unsigned short* __restrict__ PL) {
  int id = blockIdx.x * 256 + threadIdx.x;      // 589824 total
  int co = id & 255, ci = (id >> 8) & 255, p9 = id >> 16;
  float w = W[id];
  _Float16 wh = (_Float16)w;
  float rw = (w - (float)wh) * 4096.0f;         // exact (Sterbenz) then *2^12
  _Float16 wl = (_Float16)rw;
  int q = (p9 * 8 + (ci >> 5)) * 16 + (co >> 4);
  int idx = q * 512 + (co & 15) * 32 + (ci & 31);
  PH[idx] = __builtin_bit_cast(unsigned short, wh);
  PL[idx] = __builtin_bit_cast(unsigned short, wl);
}

// ---------------- fused 5-level 3x3 conv, double-f16 MFMA -------------------
struct ConvArgsH {
  const double* in[5];
  double* out[5];
  const unsigned short* wH[5];
  const unsigned short* wL[5];
  const float* bias[5];
  int H[5];
  int nbx[5];
  int off[6];
};

template <bool RELU>
__global__ __launch_bounds__(256) void conv3x3_h2(ConvArgsH A) {
  __shared__ uint4 smemq[34816 / 16];
  char* sh = (char*)smemq;
  const int bx = blockIdx.x;
  int l = 0;
#pragma unroll
  for (int i = 1; i < 5; ++i)
    if (bx >= A.off[i]) l = i;
  const int rel = bx - A.off[l];
  const int H = A.H[l];
  const int W = H;
  const int nbx = A.nbx[l];
  const int x0 = (rel % nbx) * 32;
  const int y = (rel / nbx) % H;
  const int b = rel / (nbx * H);
  const double* __restrict__ in = A.in[l];
  double* __restrict__ out = A.out[l];
  const unsigned short* __restrict__ wHp = A.wH[l];
  const unsigned short* __restrict__ wLp = A.wL[l];
  const float* __restrict__ bias = A.bias[l];

  const int t = threadIdx.x;
  const int lane = t & 63;
  const int wq = t >> 6;        // cout quarter
  const int lm = lane & 15;     // A row (pixel) / B col (cout)
  const int lq = lane >> 4;     // k-subgroup of 8

  d4 dacc[2][4];
#pragma unroll
  for (int mt = 0; mt < 2; ++mt)
#pragma unroll
    for (int nt = 0; nt < 4; ++nt) {
      double bv = (double)bias[wq * 64 + nt * 16 + lm];
      dacc[mt][nt] = (d4){bv, bv, bv, bv};
    }

  const int cst = (t & 127) * 2;   // staging channel pair
  const int prow = t >> 7;         // staging pixel parity

  for (int ky = 0; ky < 3; ++ky) {
    const int gy = y + ky - 1;
    __syncthreads();
    for (int pp = prow; pp < 34; pp += 2) {
      int gx = x0 + pp - 1;
      double xv0 = 0.0, xv1 = 0.0;
      if (gy >= 0 && gy < H && gx >= 0 && gx < W) {
        const double* ptr = in + (((size_t)b * H + gy) * W + gx) * 256 + cst;
        xv0 = ptr[0];
        xv1 = ptr[1];
      }
      _Float16 h0 = (_Float16)((float)xv0);
      _Float16 h1 = (_Float16)((float)xv1);
      float r0 = (float)(xv0 - (double)(float)h0) * 4096.0f;
      float r1 = (float)(xv1 - (double)(float)h1) * 4096.0f;
      _Float16 l0 = (_Float16)r0, l1 = (_Float16)r1;
      unsigned hp = (unsigned)__builtin_bit_cast(unsigned short, h0) |
                    ((unsigned)__builtin_bit_cast(unsigned short, h1) << 16);
      unsigned lp = (unsigned)__builtin_bit_cast(unsigned short, l0) |
                    ((unsigned)__builtin_bit_cast(unsigned short, l1) << 16);
      int bo = pp * 512 + ((cst * 2) ^ ((pp & 7) << 4));
      *(unsigned*)(sh + bo) = hp;
      *(unsigned*)(sh + 17408 + bo) = lp;
    }
    __syncthreads();

    f4_t accA[2][4], accB[2][4];
#pragma unroll
    for (int mt = 0; mt < 2; ++mt)
#pragma unroll
      for (int nt = 0; nt < 4; ++nt) {
        accA[mt][nt] = (f4_t){0.f, 0.f, 0.f, 0.f};
        accB[mt][nt] = (f4_t){0.f, 0.f, 0.f, 0.f};
      }

    for (int kx = 0; kx < 3; ++kx) {
      const int P0 = (ky * 3 + kx) * 8;
      for (int kt = 0; kt < 8; ++kt) {
        h8_t aH[2], aL[2];
#pragma unroll
        for (int mt = 0; mt < 2; ++mt) {
          int pix = mt * 16 + lm + kx;
          int bo = pix * 512 + ((kt * 64 + lq * 16) ^ ((pix & 7) << 4));
          aH[mt] = *(const h8_t*)(sh + bo);
          aL[mt] = *(const h8_t*)(sh + 17408 + bo);
        }
        h8_t bH[4], bL[4];
#pragma unroll
        for (int nt = 0; nt < 4; ++nt) {
          size_t eo = (size_t)((P0 + kt) * 16 + wq * 4 + nt) * 512 + lm * 32 + lq * 8;
          bH[nt] = *(const h8_t*)(wHp + eo);
          bL[nt] = *(const h8_t*)(wLp + eo);
        }
#pragma unroll
        for (int mt = 0; mt < 2; ++mt)
#pragma unroll
          for (int nt = 0; nt < 4; ++nt) {
            accB[mt][nt] = __builtin_amdgcn_mfma_f32_16x16x32_f16(aH[mt], bL[nt], accB[mt][nt], 0, 0, 0);
            accB[mt][nt] = __builtin_amdgcn_mfma_f32_16x16x32_f16(aL[mt], bH[nt], accB[mt][nt], 0, 0, 0);
            accA[mt][nt] = __builtin_amdgcn_mfma_f32_16x16x32_f16(aH[mt], bH[nt], accA[mt][nt], 0, 0, 0);
          }
      }
    }
#pragma unroll
    for (int mt = 0; mt < 2; ++mt)
#pragma unroll
      for (int nt = 0; nt < 4; ++nt)
#pragma unroll
        for (int r = 0; r < 4; ++r)
          dacc[mt][nt][r] += (double)accA[mt][nt][r] +
                             (double)accB[mt][nt][r] * (1.0 / 4096.0);
  }

#pragma unroll
  for (int mt = 0; mt < 2; ++mt)
#pragma unroll
    for (int nt = 0; nt < 4; ++nt) {
      int cout = wq * 64 + nt * 16 + lm;
#pragma unroll
      for (int r = 0; r < 4; ++r) {
        int gx = x0 + mt * 16 + lq * 4 + r;
        if (gx < W) {
          double v = dacc[mt][nt][r];
          if (RELU) v = fmax(v, 0.0);
          out[(((size_t)b * H + y) * W + gx) * 256 + cout] = v;
        }
      }
    }
}

// ---------------- RPN head (obj + delta 1x1) + anchor decode, f64 -----------
struct AnchorHW { double hh[9]; double ww[9]; };

__global__ __launch_bounds__(64) void rpn_head_d(
    const double* __restrict__ tmap,
    const float* __restrict__ w_obj, const float* __restrict__ b_obj,
    const float* __restrict__ w_dlt, const float* __restrict__ b_dlt,
    double* __restrict__ scores, double* __restrict__ boxes,
    int H, int W, int a_off, double stride, AnchorHW anc) {
  __shared__ double tv[256];
  __shared__ double dlt[36];
  const int t = threadIdx.x;
  const int x = blockIdx.x, y = blockIdx.y, b = blockIdx.z;
  const double* px = tmap + (((size_t)b * H + y) * W + x) * 256;
  tv[t] = px[t]; tv[t + 64] = px[t + 64]; tv[t + 128] = px[t + 128]; tv[t + 192] = px[t + 192];
  __syncthreads();
  double sacc = 0.0;
  if (t < 9) {
    sacc = (double)b_obj[t];
    for (int ci = 0; ci < 256; ++ci) sacc += tv[ci] * (double)w_obj[ci * 9 + t];
  } else if (t < 45) {
    int j = t - 9;
    double a = (double)b_dlt[j];
    for (int ci = 0; ci < 256; ++ci) a += tv[ci] * (double)w_dlt[ci * 36 + j];
    dlt[j] = a;
  }
  __syncthreads();
  if (t < 9) {
    int ai = a_off + (y * W + x) * 9 + t;
    scores[(size_t)b * NUM_ANCH + ai] = sacc;
    double cy = (y + 0.5) * stride, cx = (x + 0.5) * stride;
    double hh = anc.hh[t], ww = anc.ww[t];
    float ay1 = (float)fmin(fmax(cy - hh * 0.5, 0.0), 512.0);
    float ax1 = (float)fmin(fmax(cx - ww * 0.5, 0.0), 512.0);
    float ay2 = (float)fmin(fmax(cy + hh * 0.5, 0.0), 512.0);
    float ax2 = (float)fmin(fmax(cx + ww * 0.5, 0.0), 512.0);
    float ahf = ay2 - ay1, awf = ax2 - ax1;
    float actyf = ay1 + ahf * 0.5f, actxf = ax1 + awf * 0.5f;
    double dy = dlt[t * 4 + 0], dx = dlt[t * 4 + 1];
    double dh = dlt[t * 4 + 2], dw = dlt[t * 4 + 3];
    double ncy = dy * (double)ahf + (double)actyf;
    double ncx = dx * (double)awf + (double)actxf;
    double nh = exp(dh) * (double)ahf;
    double nw = exp(dw) * (double)awf;
    double* bo = boxes + ((size_t)b * NUM_ANCH + ai) * 4;
    bo[0] = ncy - nh * 0.5;
    bo[1] = ncx - nw * 0.5;
    bo[2] = ncy + nh * 0.5;
    bo[3] = ncx + nw * 0.5;
  }
}

// ---------------- exact top-1000 per batch (f64 radix-select + bitonic) -----
__device__ inline unsigned long long dkey(double f) {
  unsigned long long u = (unsigned long long)__double_as_longlong(f);
  return u ^ ((unsigned long long)((long long)u >> 63) | 0x8000000000000000ull);
}

__global__ __launch_bounds__(1024) void topk_d(
    const double* __restrict__ scores, const double* __restrict__ boxes,
    double* __restrict__ ss, double* __restrict__ sb) {
  const int A = NUM_ANCH;
  __shared__ unsigned hist[256];
  __shared__ unsigned long long kk[2048];
  __shared__ unsigned id[2048];
  __shared__ unsigned long long s_prefix;
  __shared__ unsigned s_need, s_cnt;
  const int b = blockIdx.x, t = threadIdx.x;
  const double* sc = scores + (size_t)b * A;
  if (t == 0) { s_prefix = 0ull; s_need = 1000; s_cnt = 0; }
  __syncthreads();
  for (int r = 0; r < 8; ++r) {
    if (t < 256) hist[t] = 0;
    __syncthreads();
    const int shift = 56 - 8 * r;
    const unsigned long long prefix = s_prefix;
    unsigned long long maskHigh = 0ull;
    if (r != 0) maskHigh = (~0ull) << (shift + 8);
    for (int i = t; i < A; i += 1024) {
      unsigned long long k = dkey(sc[i]);
      if ((k & maskHigh) == prefix) atomicAdd(&hist[(unsigned)(k >> shift) & 255u], 1u);
    }
    __syncthreads();
    if (t == 0) {
      unsigned need = s_need, cum = 0;
      for (int bin = 255; bin >= 0; --bin) {
        cum += hist[bin];
        if (cum >= need) {
          s_prefix = prefix | ((unsigned long long)bin << shift);
          s_need = need - (cum - hist[bin]);
          break;
        }
      }
    }
    __syncthreads();
  }
  const unsigned long long K = s_prefix;
  for (int i = t; i < A; i += 1024) {
    unsigned long long k = dkey(sc[i]);
    if (k >= K) {
      unsigned pos = atomicAdd(&s_cnt, 1u);
      if (pos < 2048) { kk[pos] = k; id[pos] = (unsigned)i; }
    }
  }
  __syncthreads();
  unsigned cnt = s_cnt;
  for (int i = t; i < 2048; i += 1024)
    if (i >= cnt) { kk[i] = 0ull; id[i] = 0xFFFFFFFFu; }
  __syncthreads();
  for (int k = 2; k <= 2048; k <<= 1) {
    for (int j = k >> 1; j > 0; j >>= 1) {
#pragma unroll
      for (int u = 0; u < 2; ++u) {
        int i = t + u * 1024;
        int ixj = i ^ j;
        if (ixj > i) {
          unsigned long long ka = kk[i], kc = kk[ixj];
          unsigned ia = id[i], ic = id[ixj];
          bool cPrec = (kc > ka) || (kc == ka && ic < ia);
          bool up = (i & k) != 0;
          if (cPrec != up) { kk[i] = kc; kk[ixj] = ka; id[i] = ic; id[ixj] = ia; }
        }
      }
      __syncthreads();
    }
  }
  if (t < 1000) {
    unsigned idx = id[t];
    ss[b * 1000 + t] = sc[idx];
    const double* bp = boxes + ((size_t)b * A + idx) * 4;
    double* op = sb + (b * 1000 + t) * 4;
    op[0] = bp[0]; op[1] = bp[1]; op[2] = bp[2]; op[3] = bp[3];
  }
}

// ---------------- suppression bit-matrix (iou>0.7 & j>i), f64 ---------------
__global__ void suppmat_d(const double* __restrict__ sb,
                          unsigned long long* __restrict__ supp) {
  int g = blockIdx.x * 256 + threadIdx.x;   // 32000 = 2*1000*16
  int w = g & 15;
  int i = (g >> 4) % 1000;
  int b = g / 16000;
  const double* bx = sb + b * 4000;
  double y1 = bx[i * 4 + 0], x1 = bx[i * 4 + 1], y2 = bx[i * 4 + 2], x2 = bx[i * 4 + 3];
  double ai = (y2 - y1) * (x2 - x1);
  unsigned long long m = 0;
  for (int q = 0; q < 64; ++q) {
    int j = w * 64 + q;
    if (j > i && j < 1000) {
      double by1 = bx[j * 4 + 0], bx1 = bx[j * 4 + 1], by2 = bx[j * 4 + 2], bx2 = bx[j * 4 + 3];
      double aj = (by2 - by1) * (bx2 - bx1);
      double iy1 = fmax(y1, by1), ix1 = fmax(x1, bx1);
      double iy2 = fmin(y2, by2), ix2 = fmin(x2, bx2);
      double inter = fmax(iy2 - iy1, 0.0) * fmax(ix2 - ix1, 0.0);
      double iou = inter / (ai + aj - inter + 1e-8);
      if (iou > 0.7) m |= (1ull << q);
    }
  }
  supp[g] = m;
}

// ---------------- greedy NMS reduce + slot scatter --------------------------
__global__ __launch_bounds__(64) void nms_reduce_d(
    const double* __restrict__ ss, const double* __restrict__ sb,
    const unsigned long long* __restrict__ supp,
    float* __restrict__ rois, double* __restrict__ rois64) {
  __shared__ unsigned long long aliveS[16];
  __shared__ int pref[16];
  const int b = blockIdx.x, lane = threadIdx.x;
  unsigned long long myword = 0;
  if (lane < 16) {
    for (int q = 0; q < 64; ++q) {
      int j = lane * 64 + q;
      if (j < 1000 && ss[b * 1000 + j] > 0.0) myword |= (1ull << q);
    }
  }
  const unsigned long long* sp = supp + (size_t)b * 16000;
  unsigned long long cur = (lane < 16) ? sp[lane] : 0ull;
  for (int i = 0; i < 1000; ++i) {
    unsigned long long nxt = (lane < 16 && i < 999) ? sp[(i + 1) * 16 + lane] : 0ull;
    unsigned long long wv = __shfl(myword, i >> 6);
    if ((wv >> (i & 63)) & 1ull) {
      if (lane < 16) myword &= ~cur;
    }
    cur = nxt;
  }
  if (lane < 16) aliveS[lane] = myword;
  __syncthreads();
  if (lane == 0) {
    int s = 0;
    for (int w = 0; w < 16; ++w) { pref[w] = s; s += __popcll(aliveS[w]); }
  }
  float* ro = rois + b * 4000;
  double* rd = rois64 + b * 4000;
  for (int k = lane; k < 4000; k += 64) { ro[k] = 0.0f; rd[k] = 0.0; }
  __syncthreads();
  for (int j = lane; j < 1000; j += 64) {
    int w = j >> 6;
    unsigned long long word = aliveS[w];
    if ((word >> (j & 63)) & 1ull) {
      unsigned long long below = (j & 63) ? (word & ((1ull << (j & 63)) - 1ull)) : 0ull;
      int slot = pref[w] + __popcll(below);
      const double* bp = sb + (b * 1000 + j) * 4;
      ro[slot * 4 + 0] = (float)bp[0]; ro[slot * 4 + 1] = (float)bp[1];
      ro[slot * 4 + 2] = (float)bp[2]; ro[slot * 4 + 3] = (float)bp[3];
      rd[slot * 4 + 0] = bp[0]; rd[slot * 4 + 1] = bp[1];
      rd[slot * 4 + 2] = bp[2]; rd[slot * 4 + 3] = bp[3];
    }
  }
}

// ---------------- ROI align: f64 sampling -> hi/lo bf16 feats ---------------
__global__ __launch_bounds__(256) void roi_align_d(
    const double* __restrict__ o2, const double* __restrict__ o3,
    const double* __restrict__ o4, const double* __restrict__ o5,
    const double* __restrict__ o6, const double* __restrict__ rois64,
    unsigned short* __restrict__ featsH, unsigned short* __restrict__ featsL) {
  __shared__ double s_wy[14], s_wx[14];
  __shared__ int s_y0[14], s_y1[14], s_x0[14], s_x1[14];
  const int t = threadIdx.x;
  const int b = blockIdx.x / 1000, r = blockIdx.x % 1000;
  const double* box = rois64 + (b * 1000 + r) * 4;
  double b0 = box[0], b1 = box[1], b2 = box[2], b3 = box[3];
  double h = b2 - b0, w = b3 - b1;
  double size = sqrt(fmax(h * w, 1e-8));
  double lf = floor(log2(size / 224.0) + 4.0);
  lf = fmin(fmax(lf, 2.0), 6.0);
  int lvl = (int)lf;
  int stride_i = 1 << lvl;
  double stride = (double)stride_i;
  int fs_i = 512 >> lvl;
  double fs = (double)fs_i;
  if (t < 14) {
    double v = b0 / stride + ((t + 0.5) * (h / stride)) / 14.0 - 0.5;
    v = fmin(fmax(v, 0.0), fs - 1.0);
    int i0 = (int)floor(v);
    s_y0[t] = i0; s_y1[t] = min(i0 + 1, fs_i - 1); s_wy[t] = v - (double)i0;
  } else if (t >= 64 && t < 78) {
    int u = t - 64;
    double v = b1 / stride + ((u + 0.5) * (w / stride)) / 14.0 - 0.5;
    v = fmin(fmax(v, 0.0), fs - 1.0);
    int i0 = (int)floor(v);
    s_x0[u] = i0; s_x1[u] = min(i0 + 1, fs_i - 1); s_wx[u] = v - (double)i0;
  }
  __syncthreads();
  const double* omaps[5] = {o2, o3, o4, o5, o6};
  const double* fm = omaps[lvl - 2] + (size_t)b * fs_i * fs_i * 256 + t;
  size_t obase = ((size_t)(b * 1000 + r) * 49) * 256 + t;
  for (int oy = 0; oy < 7; ++oy) {
    double acc[7] = {0, 0, 0, 0, 0, 0, 0};
#pragma unroll
    for (int sy = 0; sy < 2; ++sy) {
      int yy = oy * 2 + sy;
      int y0 = s_y0[yy], y1 = s_y1[yy];
      double wy = s_wy[yy];
      const double* r0 = fm + (size_t)y0 * fs_i * 256;
      const double* r1 = fm + (size_t)y1 * fs_i * 256;
      for (int ox = 0; ox < 7; ++ox) {
#pragma unroll
        for (int sx = 0; sx < 2; ++sx) {
          int xx = ox * 2 + sx;
          int x0 = s_x0[xx], x1 = s_x1[xx];
          double wx = s_wx[xx];
          double v00 = r0[x0 * 256], v01 = r0[x1 * 256];
          double v10 = r1[x0 * 256], v11 = r1[x1 * 256];
          double val = (1.0 - wy) * ((1.0 - wx) * v00 + wx * v01) +
                       wy * ((1.0 - wx) * v10 + wx * v11);
          acc[ox] += val;
        }
      }
    }
    for (int ox = 0; ox < 7; ++ox) {
      float v = (float)(acc[ox] * 0.25);
      unsigned short hh = f2bf(v);
      size_t idx = obase + (size_t)(oy * 7 + ox) * 256;
      featsH[idx] = hh;
      featsL[idx] = f2bf(v - bf2f(hh));
    }
  }
}

// ---------------- split f32 [K][N] -> bf16 hi/lo transposed [N][K] ----------
__global__ __launch_bounds__(256) void split_transpose(
    const float* __restrict__ W, unsigned short* __restrict__ TH,
    unsigned short* __restrict__ TL, int K, int N) {
  __shared__ unsigned short shh[32 * 33], shl[32 * 33];
  const int kt = blockIdx.y * 32, nt = blockIdx.x * 32;
  const int tx = threadIdx.x & 31, ty = threadIdx.x >> 5;   // 32x8
  for (int yy = ty; yy < 32; yy += 8) {
    float v = W[(size_t)(kt + yy) * N + nt + tx];
    unsigned short h = f2bf(v);
    shh[yy * 33 + tx] = h;
    shl[yy * 33 + tx] = f2bf(v - bf2f(h));
  }
  __syncthreads();
  for (int yy = ty; yy < 32; yy += 8) {
    TH[(size_t)(nt + yy) * K + kt + tx] = shh[tx * 33 + yy];
    TL[(size_t)(nt + yy) * K + kt + tx] = shl[tx * 33 + yy];
  }
}

// ---------------- split-K partial bf16 MFMA GEMM 128x128 --------------------
// blockIdx.z = k-chunk kc; each chunk sums K/KSPLIT into P[kc] (f32, raw —
// bias/relu applied by the reduce pass). Per-chunk accumulation sequence
// matches the R7 kernel (3 mfma: aL*bH, aH*bL, aH*bH).
struct GemmPArgs {
  const unsigned short* AH;
  const unsigned short* AL;
  const unsigned short* BTH;
  const unsigned short* BTL;
  float* P[4];
  int M, N, K, KC;
};

__global__ __launch_bounds__(256) void gemm_mfma_partial(GemmPArgs G) {
  __shared__ __align__(16) unsigned short AsH[128 * 40], AsL[128 * 40];
  __shared__ __align__(16) unsigned short BsH[128 * 40], BsL[128 * 40];
  const int t = threadIdx.x;
  const int lane = t & 63;
  const int wave = t >> 6;
  const int lm = lane & 15, lq = lane >> 4;
  const int wn = wave & 1, wm = wave >> 1;
  const int m0 = blockIdx.y * 128, n0 = blockIdx.x * 128;
  const int kc = blockIdx.z;
  const int kbeg = kc * G.KC, kend = kbeg + G.KC;
  const int M = G.M, N = G.N, K = G.K;
  float* __restrict__ C = G.P[kc];
  const unsigned short* __restrict__ AH = G.AH;
  const unsigned short* __restrict__ AL = G.AL;
  const unsigned short* __restrict__ BTH = G.BTH;
  const unsigned short* __restrict__ BTL = G.BTL;
  const int sr = t >> 1;            // 0..127
  const int sk = (t & 1) * 16;      // 0,16

  f4_t acc[4][4];
#pragma unroll
  for (int mt = 0; mt < 4; ++mt)
#pragma unroll
    for (int nt = 0; nt < 4; ++nt) acc[mt][nt] = (f4_t){0.f, 0.f, 0.f, 0.f};

  const uint4 zz = {0u, 0u, 0u, 0u};
  for (int k0 = kbeg; k0 < kend; k0 += 32) {
    __syncthreads();
    {
      uint4 vh0 = zz, vh1 = zz, vl0 = zz, vl1 = zz;
      if (m0 + sr < M) {
        size_t off = (size_t)(m0 + sr) * K + k0 + sk;
        vh0 = *(const uint4*)&AH[off];
        vh1 = *(const uint4*)&AH[off + 8];
        vl0 = *(const uint4*)&AL[off];
        vl1 = *(const uint4*)&AL[off + 8];
      }
      *(uint4*)&AsH[sr * 40 + sk] = vh0;
      *(uint4*)&AsH[sr * 40 + sk + 8] = vh1;
      *(uint4*)&AsL[sr * 40 + sk] = vl0;
      *(uint4*)&AsL[sr * 40 + sk + 8] = vl1;
    }
    {
      size_t off = (size_t)(n0 + sr) * K + k0 + sk;
      *(uint4*)&BsH[sr * 40 + sk] = *(const uint4*)&BTH[off];
      *(uint4*)&BsH[sr * 40 + sk + 8] = *(const uint4*)&BTH[off + 8];
      *(uint4*)&BsL[sr * 40 + sk] = *(const uint4*)&BTL[off];
      *(uint4*)&BsL[sr * 40 + sk + 8] = *(const uint4*)&BTL[off + 8];
    }
    __syncthreads();

    bf8_t aH[4], aL[4], bH[4], bL[4];
#pragma unroll
    for (int mt = 0; mt < 4; ++mt) {
      int idx = (wm * 64 + mt * 16 + lm) * 40 + lq * 8;
      aH[mt] = *(const bf8_t*)&AsH[idx];
      aL[mt] = *(const bf8_t*)&AsL[idx];
    }
#pragma unroll
    for (int nt = 0; nt < 4; ++nt) {
      int idx = (wn * 64 + nt * 16 + lm) * 40 + lq * 8;
      bH[nt] = *(const bf8_t*)&BsH[idx];
      bL[nt] = *(const bf8_t*)&BsL[idx];
    }
#pragma unroll
    for (int mt = 0; mt < 4; ++mt)
#pragma unroll
      for (int nt = 0; nt < 4; ++nt) {
        f4_t a0 = acc[mt][nt];
        a0 = __builtin_amdgcn_mfma_f32_16x16x32_bf16(aL[mt], bH[nt], a0, 0, 0, 0);
        a0 = __builtin_amdgcn_mfma_f32_16x16x32_bf16(aH[mt], bL[nt], a0, 0, 0, 0);
        a0 = __builtin_amdgcn_mfma_f32_16x16x32_bf16(aH[mt], bH[nt], a0, 0, 0, 0);
        acc[mt][nt] = a0;
      }
  }
  // D layout (verified 16x16): col = lane&15, row = (lane>>4)*4 + reg
#pragma unroll
  for (int mt = 0; mt < 4; ++mt) {
#pragma unroll
    for (int nt = 0; nt < 4; ++nt) {
      int ncol = n0 + wn * 64 + nt * 16 + lm;
#pragma unroll
      for (int r = 0; r < 4; ++r) {
        int m = m0 + wm * 64 + mt * 16 + lq * 4 + r;
        if (m < M) C[(size_t)m * N + ncol] = acc[mt][nt][r];
      }
    }
  }
}

// ---------------- reduce 4 partials + bias + relu -> bf16 hi/lo -------------
__global__ void reduce4_split(const float* __restrict__ p0, const float* __restrict__ p1,
                              const float* __restrict__ p2, const float* __restrict__ p3,
                              const float* __restrict__ bias,
                              unsigned short* __restrict__ H, unsigned short* __restrict__ L,
                              int n) {
  int i = blockIdx.x * 256 + threadIdx.x;
  if (i < n) {
    float v = ((p0[i] + p1[i]) + p2[i]) + p3[i] + bias[i & 1023];
    v = fmaxf(v, 0.0f);
    unsigned short h = f2bf(v);
    H[i] = h;
    L[i] = f2bf(v - bf2f(h));
  }
}

// ---------------- reduce 4 partials + bias + relu -> f32 --------------------
__global__ void reduce4_f32(const float* __restrict__ p0, const float* __restrict__ p1,
                            const float* __restrict__ p2, const float* __restrict__ p3,
                            const float* __restrict__ bias, float* __restrict__ C, int n) {
  int i = blockIdx.x * 256 + threadIdx.x;
  if (i < n) {
    float v = ((p0[i] + p1[i]) + p2[i]) + p3[i] + bias[i & 1023];
    C[i] = fmaxf(v, 0.0f);
  }
}

// ---------------- final box(4) + cls(81) heads, f32 -------------------------
__global__ __launch_bounds__(128) void boxcls_kernel(
    const float* __restrict__ x, const float* __restrict__ w_box,
    const float* __restrict__ b_box, const float* __restrict__ w_cls,
    const float* __restrict__ b_cls, float* __restrict__ out) {
  __shared__ float xv[1024];
  const int t = threadIdx.x;
  const int row = blockIdx.x;
  const float* xp = x + (size_t)row * 1024;
#pragma unroll
  for (int k = 0; k < 8; ++k) xv[k * 128 + t] = xp[k * 128 + t];
  __syncthreads();
  if (t < 4) {
    float acc = b_box[t];
    for (int k = 0; k < 1024; ++k) acc += xv[k] * w_box[k * 4 + t];
    out[8000 + row * 4 + t] = acc;
  } else if (t < 85) {
    int j = t - 4;
    float acc = b_cls[j];
    for (int k = 0; k < 1024; ++k) acc += xv[k] * w_cls[k * 81 + j];
    out[16000 + row * 81 + j] = acc;
  }
}

// ---------------------------------------------------------------------------
extern "C" void kernel_launch(void* const* d_in, const int* in_sizes, int n_in,
                              void* d_out, int out_size, void* d_ws, size_t ws_size,
                              hipStream_t stream) {
  (void)in_sizes; (void)n_in; (void)out_size; (void)ws_size;

  const float* c_in[4] = {(const float*)d_in[0], (const float*)d_in[1],
                          (const float*)d_in[2], (const float*)d_in[3]};
  const float *w_l[5], *b_l[5], *w_o[5], *b_o[5];
  for (int l = 0; l < 5; ++l) {
    w_l[l] = (const float*)d_in[4 + l * 4 + 0];
    b_l[l] = (const float*)d_in[4 + l * 4 + 1];
    w_o[l] = (const float*)d_in[4 + l * 4 + 2];
    b_o[l] = (const float*)d_in[4 + l * 4 + 3];
  }
  const float* w_rpn = (const float*)d_in[24];
  const float* b_rpn = (const float*)d_in[25];
  const float* w_obj = (const float*)d_in[26];
  const float* b_obj = (const float*)d_in[27];
  const float* w_dlt = (const float*)d_in[28];
  const float* b_dlt = (const float*)d_in[29];
  const float* w_fc1 = (const float*)d_in[30];
  const float* b_fc1 = (const float*)d_in[31];
  const float* w_fc2 = (const float*)d_in[32];
  const float* b_fc2 = (const float*)d_in[33];
  const float* w_box = (const float*)d_in[34];
  const float* b_box = (const float*)d_in[35];
  const float* w_cls = (const float*)d_in[36];
  const float* b_cls = (const float*)d_in[37];

  char* W8 = (char*)d_ws;
  double* o64 = (double*)(W8 + 0);
  double* p64 = (double*)(W8 + 89391104);
  float* c6buf = (float*)(W8 + 178782208);
  double* scores = (double*)(W8 + 179830784);
  double* boxes = (double*)(W8 + 182973440);
  double* ssb = (double*)(W8 + 195544064);
  double* sbb = (double*)(W8 + 195560064);
  double* rois64 = (double*)(W8 + 195624064);
  unsigned long long* suppb = (unsigned long long*)(W8 + 195688064);
  unsigned short* featsH = (unsigned short*)(W8 + 89391104);
  unsigned short* featsL = (unsigned short*)(W8 + 139567104);
  float* fc1b = (float*)(W8 + 0);
  float* fc2b = (float*)(W8 + 8192000);
  unsigned short* wT1H = (unsigned short*)(W8 + 16384000);
  unsigned short* wT1L = (unsigned short*)(W8 + 42074112);
  unsigned short* wT2H = (unsigned short*)(W8 + 67764224);
  unsigned short* wT2L = (unsigned short*)(W8 + 69861376);
  // fc1 output bf16 planes relocated into dead feats region (dead at reduce)
  unsigned short* fc1H = (unsigned short*)(W8 + 89391104);
  unsigned short* fc1L = (unsigned short*)(W8 + 93487104);
  // fc1 split-K partials (dead regions during fc1 GEMM)
  float* fc1p1 = (float*)(W8 + 8192000);    // fc2b region
  float* fc1p2 = (float*)(W8 + 71958528);   // old fc1H/L region
  float* fc1p3 = (float*)(W8 + 80150528);   // o64 tail
  // fc2 split-K partials (fc1b + wT1 regions, dead after fc1 GEMM)
  float* fc2p1 = (float*)(W8 + 0);
  float* fc2p2 = (float*)(W8 + 16384000);
  float* fc2p3 = (float*)(W8 + 24576000);
  float* outf = (float*)d_out;

  // conv f16 weight planes: w_o sets in boxes region, w_rpn in scores region
  unsigned short* woH[5];
  unsigned short* woL[5];
  for (int l = 0; l < 5; ++l) {
    woH[l] = (unsigned short*)(W8 + 182973440 + (size_t)l * 2359296);
    woL[l] = (unsigned short*)(W8 + 182973440 + (size_t)l * 2359296 + 1179648);
  }
  unsigned short* wrH = (unsigned short*)(W8 + 179830784);
  unsigned short* wrL = (unsigned short*)(W8 + 179830784 + 1179648);

  const size_t OFF[5] = {0, 8388608, 10485760, 11010048, 11141120};
  double* o[5]; double* p[5];
  for (int l = 0; l < 5; ++l) { o[l] = o64 + OFF[l]; p[l] = p64 + OFF[l]; }

  const int HS[5] = {128, 64, 32, 16, 8};
  const int a_off[5] = {0, 147456, 184320, 193536, 195840};
  const double strides[5] = {4.0, 8.0, 16.0, 32.0, 64.0};
  const double SZ[5] = {16.0, 32.0, 64.0, 128.0, 256.0};
  AnchorHW anc[5];
  for (int l = 0; l < 5; ++l) {
    const double ars[3] = {0.5, 1.0, 2.0};
    for (int s = 0; s < 3; ++s) {
      double sc = pow(2.0, s / 3.0);
      for (int a = 0; a < 3; ++a) {
        double sq = sqrt(ars[a]);
        anc[l].hh[s * 3 + a] = SZ[l] * sc / sq;
        anc[l].ww[s * 3 + a] = SZ[l] * sc * sq;
      }
    }
  }

  // ---- weight split for conv passes (independent of FPN) ----
  for (int l = 0; l < 5; ++l)
    wsplit_f16<<<2304, 256, 0, stream>>>(w_o[l], woH[l], woL[l]);
  wsplit_f16<<<2304, 256, 0, stream>>>(w_rpn, wrH, wrL);

  // ---- FPN (f64) ----
  maxpool_kernel<<<1024, 256, 0, stream>>>(c_in[3], c6buf);
  lateral_d<2048><<<32, 256, 0, stream>>>(c6buf, w_l[4], b_l[4], p[4]);      // p6
  lateral_d<2048><<<128, 256, 0, stream>>>(c_in[3], w_l[3], b_l[3], p[3]);   // p5
  upadd_d<<<512, 256, 0, stream>>>(p[3], p[4], 16, 16);
  lateral_d<1024><<<512, 256, 0, stream>>>(c_in[2], w_l[2], b_l[2], p[2]);   // p4
  upadd_d<<<2048, 256, 0, stream>>>(p[2], p[3], 32, 32);
  lateral_d<512><<<2048, 256, 0, stream>>>(c_in[1], w_l[1], b_l[1], p[1]);   // p3
  upadd_d<<<8192, 256, 0, stream>>>(p[1], p[2], 64, 64);
  lateral_d<256><<<8192, 256, 0, stream>>>(c_in[0], w_l[0], b_l[0], p[0]);   // p2
  upadd_d<<<32768, 256, 0, stream>>>(p[0], p[1], 128, 128);

  // ---- fused 5-level conv passes (double-f16 MFMA) ----
  ConvArgsH co, ct;
  int total = 0;
  for (int l = 0; l < 5; ++l) {
    int nbx = (HS[l] + 31) / 32;
    co.in[l] = p[l]; co.out[l] = o[l];
    co.wH[l] = woH[l]; co.wL[l] = woL[l]; co.bias[l] = b_o[l];
    ct.in[l] = o[l]; ct.out[l] = p[l];
    ct.wH[l] = wrH;  ct.wL[l] = wrL;  ct.bias[l] = b_rpn;
    co.H[l] = ct.H[l] = HS[l];
    co.nbx[l] = ct.nbx[l] = nbx;
    co.off[l] = ct.off[l] = total;
    total += nbx * HS[l] * 2;
  }
  co.off[5] = ct.off[5] = total;   // 1392
  conv3x3_h2<false><<<total, 256, 0, stream>>>(co);
  conv3x3_h2<true><<<total, 256, 0, stream>>>(ct);

  for (int l = 0; l < 5; ++l) {
    dim3 g(HS[l], HS[l], 2);
    rpn_head_d<<<g, 64, 0, stream>>>(p[l], w_obj, b_obj, w_dlt, b_dlt, scores, boxes,
                                     HS[l], HS[l], a_off[l], strides[l], anc[l]);
  }
  // ---- top-1000 + NMS (f64) ----
  topk_d<<<2, 1024, 0, stream>>>(scores, boxes, ssb, sbb);
  suppmat_d<<<125, 256, 0, stream>>>(sbb, suppb);
  nms_reduce_d<<<2, 64, 0, stream>>>(ssb, sbb, suppb, outf, rois64);
  // ---- ROI align (emits hi/lo bf16 feats) ----
  roi_align_d<<<2000, 256, 0, stream>>>(o[0], o[1], o[2], o[3], o[4], rois64,
                                        featsH, featsL);
  // ---- FC head: split weights (o64 now dead), split-K MFMA GEMMs ----
  split_transpose<<<dim3(32, 392), 256, 0, stream>>>(w_fc1, wT1H, wT1L, 12544, 1024);
  split_transpose<<<dim3(32, 32), 256, 0, stream>>>(w_fc2, wT2H, wT2L, 1024, 1024);

  GemmPArgs g1;
  g1.AH = featsH; g1.AL = featsL; g1.BTH = wT1H; g1.BTL = wT1L;
  g1.P[0] = fc1b; g1.P[1] = fc1p1; g1.P[2] = fc1p2; g1.P[3] = fc1p3;
  g1.M = 2000; g1.N = 1024; g1.K = 12544; g1.KC = 3136;
  gemm_mfma_partial<<<dim3(8, 16, 4), 256, 0, stream>>>(g1);
  reduce4_split<<<8000, 256, 0, stream>>>(fc1b, fc1p1, fc1p2, fc1p3, b_fc1,
                                          fc1H, fc1L, 2048000);

  GemmPArgs g2;
  g2.AH = fc1H; g2.AL = fc1L; g2.BTH = wT2H; g2.BTL = wT2L;
  g2.P[0] = fc2b; g2.P[1] = fc2p1; g2.P[2] = fc2p2; g2.P[3] = fc2p3;
  g2.M = 2000; g2.N = 1024; g2.K = 1024; g2.KC = 256;
  gemm_mfma_partial<<<dim3(8, 16, 4), 256, 0, stream>>>(g2);
  reduce4_f32<<<8000, 256, 0, stream>>>(fc2b, fc2p1, fc2p2, fc2p3, b_fc2,
                                        fc2b, 2048000);

  boxcls_kernel<<<2000, 128, 0, stream>>>(fc2b, w_box, b_box, w_cls, b_cls, outf);
}

// Round 5
// 3095.930 us; speedup vs baseline: 1.5253x; 1.0673x over previous
//
#include <hip/hip_runtime.h>
#include <math.h>

// ---------------------------------------------------------------------------
// Faster-RCNN head. Round 10 (R9 failed: f32 tower flipped NMS decisions,
// absmax 159. R10 re-applies only the VALUE-PRESERVING parts of R9 on top of
// the R8-proven bit-exact decision path):
//  - conv kernels restructured to 8 waves / 512 threads (__launch_bounds__
//    (512,4)): per-output MFMA chains + per-ky f64 folds unchanged ->
//    bit-identical outputs; VGPR drops 156 -> ~115 (R8's occupancy limiter).
//  - conv1 epilogue emits oF32 (for roi_align) + oH/oL f16 hi/lo planes,
//    split from the SAME f64 register value with the SAME convert sequence
//    R8's conv2 staging used -> conv2 MFMA inputs bit-identical -> tower
//    (p64, f64) bit-identical -> scores/boxes/rois bit-identical to R8.
//  - conv2 staging is now pure uint4 copies (no f64 load + convert chain).
//  - conv1 staging keeps R8's f64-read + in-kernel f16 split (p64 must stay
//    f64 for the lateral/upadd chain; decision path untouched).
//  - roi_align reads f32 maps (f64 interpolation math) — affects only feats/
//    fc outputs (~1e-7, below the bf16 0.0039 floor), NOT rois.
//
// Workspace (BYTES):
//   o region [0 .. 89,391,104):
//     oF32 [0 .. 44,695,552)  oH [44,695,552 .. 67,043,328)
//     oL  [67,043,328 .. 89,391,104)
//   p64  (double, 11,173,888 el)  [89,391,104 .. 178,782,208)
//   c6   (float)                  [178,782,208 .. 179,830,784)
//   scores (double)               [179,830,784 .. 182,973,440)
//     (w_rpn f16 planes live here until rpn_head writes scores)
//   boxes  (double)               [182,973,440 .. 195,544,064)
//     (w_o f16 planes live here until rpn_head writes boxes)
//   ss/sb/rois64/supp tail        [195,544,064 .. 195,944,064)
//   featsH/L overlap p64 after rpn; fc region overlaps o region after
//   roi_align (same live-range audit as R8).
// ---------------------------------------------------------------------------

#define NUM_ANCH 196416

typedef double d4 __attribute__((ext_vector_type(4)));
typedef __attribute__((ext_vector_type(8))) short bf8_t;
typedef __attribute__((ext_vector_type(4))) float f4_t;
typedef _Float16 h8_t __attribute__((ext_vector_type(8)));

__device__ inline unsigned short f2bf(float x) {
  unsigned u = __float_as_uint(x);
  unsigned r = (u + 0x7fffu + ((u >> 16) & 1u)) >> 16;   // RNE
  return (unsigned short)r;
}
__device__ inline float bf2f(unsigned short h) {
  return __uint_as_float(((unsigned)h) << 16);
}

// ---------------- maxpool2 c5 (2,16,16,2048) -> c6 (2,8,8,2048), f32 --------
__global__ void maxpool_kernel(const float* __restrict__ in, float* __restrict__ out) {
  int idx = blockIdx.x * 256 + threadIdx.x;     // 262144 total
  int c = idx & 2047;
  int x = (idx >> 11) & 7;
  int y = (idx >> 14) & 7;
  int b = idx >> 17;
  const float* p = in + (((size_t)b * 16 + 2 * y) * 16 + 2 * x) * 2048 + c;
  float m = fmaxf(fmaxf(p[0], p[2048]), fmaxf(p[16 * 2048], p[16 * 2048 + 2048]));
  out[idx] = m;
}

// ---------------- 1x1 lateral conv + bias, f32 in -> f64 out ----------------
template <int CIN>
__global__ __launch_bounds__(256) void lateral_d(
    const float* __restrict__ in, const float* __restrict__ w,
    const float* __restrict__ bias, double* __restrict__ out) {
  const int t = threadIdx.x;
  const size_t pix0 = (size_t)blockIdx.x * 4;
  double b = (double)bias[t];
  double a0 = b, a1 = b, a2 = b, a3 = b;
  const float* i0 = in + pix0 * CIN;
  for (int ci = 0; ci < CIN; ++ci) {
    double wv = (double)w[ci * 256 + t];
    a0 += (double)i0[ci] * wv;
    a1 += (double)i0[CIN + ci] * wv;
    a2 += (double)i0[2 * CIN + ci] * wv;
    a3 += (double)i0[3 * CIN + ci] * wv;
  }
  out[(pix0 + 0) * 256 + t] = a0;
  out[(pix0 + 1) * 256 + t] = a1;
  out[(pix0 + 2) * 256 + t] = a2;
  out[(pix0 + 3) * 256 + t] = a3;
}

// ---------------- fine += upsample2(coarse), C=256, f64 ---------------------
__global__ void upadd_d(double* __restrict__ fine, const double* __restrict__ coarse,
                        int Hf, int Wf) {
  int idx = blockIdx.x * 256 + threadIdx.x;
  int c = idx & 255;
  int rem = idx >> 8;
  int x = rem % Wf; rem /= Wf;
  int y = rem % Hf;
  int b = rem / Hf;
  fine[idx] += coarse[(((size_t)b * (Hf >> 1) + (y >> 1)) * (Wf >> 1) + (x >> 1)) * 256 + c];
}

// ---------------- weight split: f32 HWIO -> f16 hi/lo, B-frag layout --------
__global__ __launch_bounds__(256) void wsplit_f16(
    const float* __restrict__ W, unsigned short* __restrict__ PH,
    unsigned short* __restrict__ PL) {
  int id = blockIdx.x * 256 + threadIdx.x;      // 589824 total
  int co = id & 255, ci = (id >> 8) & 255, p9 = id >> 16;
  float w = W[id];
  _Float16 wh = (_Float16)w;
  float rw = (w - (float)wh) * 4096.0f;         // exact (Sterbenz) then *2^12
  _Float16 wl = (_Float16)rw;
  int q = (p9 * 8 + (ci >> 5)) * 16 + (co >> 4);
  int idx = q * 512 + (co & 15) * 32 + (ci & 31);
  PH[idx] = __builtin_bit_cast(unsigned short, wh);
  PL[idx] = __builtin_bit_cast(unsigned short, wl);
}

// ---------------- fused 5-level 3x3 conv, double-f16 MFMA, 8-wave -----------
// PLANES=false: stage from f64 input, in-kernel f16 hi/lo split (R8 convert
//               sequence, bit-exact).
// PLANES=true:  stage from precomputed f16 hi/lo planes (pure uint4 copy).
// OSPLIT=true:  epilogue writes oF32 + oH/oL planes (split from the f64
//               register value, same sequence as R8's conv2 staging).
// OSPLIT=false: epilogue writes f64 (tower for rpn_head).
// Per-output arithmetic identical to R8's conv3x3_h2 (bit-identical).
struct ConvArgsU {
  const double* inD[5];
  const unsigned short* inH[5];
  const unsigned short* inL[5];
  float* outF[5];
  unsigned short* outH[5];
  unsigned short* outL[5];
  double* outD[5];
  const unsigned short* wH[5];
  const unsigned short* wL[5];
  const float* bias[5];
  int H[5];
  int nbx[5];
  int off[6];
};

template <bool PLANES, bool RELU, bool OSPLIT>
__global__ __launch_bounds__(512, 4) void conv3x3_u(ConvArgsU A) {
  // LDS: H plane [0,17408), L plane [17408,34816); 34 px x 256 ch f16,
  // XOR-swizzled (byte ^= (pix&7)<<4).
  __shared__ uint4 smemq[34816 / 16];
  char* sh = (char*)smemq;
  const int bx = blockIdx.x;
  int l = 0;
#pragma unroll
  for (int i = 1; i < 5; ++i)
    if (bx >= A.off[i]) l = i;
  const int rel = bx - A.off[l];
  const int H = A.H[l];
  const int W = H;
  const int nbx = A.nbx[l];
  const int x0 = (rel % nbx) * 32;
  const int y = (rel / nbx) % H;
  const int b = rel / (nbx * H);
  const unsigned short* __restrict__ wHp = A.wH[l];
  const unsigned short* __restrict__ wLp = A.wL[l];
  const float* __restrict__ bias = A.bias[l];

  const int t = threadIdx.x;
  const int lane = t & 63;
  const int wq = t >> 6;        // cout eighth (32 couts)
  const int lm = lane & 15;     // A row (pixel) / B col (cout)
  const int lq = lane >> 4;     // k-subgroup of 8

  // f64 master accumulators, init with bias
  d4 dacc[2][2];
#pragma unroll
  for (int mt = 0; mt < 2; ++mt)
#pragma unroll
    for (int nt = 0; nt < 2; ++nt) {
      double bv = (double)bias[wq * 32 + nt * 16 + lm];
      dacc[mt][nt] = (d4){bv, bv, bv, bv};
    }

  // staging index sets
  const int cst = (t & 127) * 2;   // f64 path: channel pair
  const int prow = t >> 7;         // f64 path: pixel phase 0..3
  const int c16 = (t & 31) * 8;    // plane path: 8-channel chunk (16B)
  const int pp0 = t >> 5;          // plane path: pixel 0..15

  for (int ky = 0; ky < 3; ++ky) {
    const int gy = y + ky - 1;
    const bool rowok = (gy >= 0 && gy < H);
    __syncthreads();
    if (PLANES) {
      const unsigned short* __restrict__ inH = A.inH[l];
      const unsigned short* __restrict__ inL = A.inL[l];
      for (int pp = pp0; pp < 34; pp += 16) {
        int gx = x0 + pp - 1;
        uint4 vh = {0u, 0u, 0u, 0u}, vl = {0u, 0u, 0u, 0u};
        if (rowok && gx >= 0 && gx < W) {
          size_t base = (((size_t)b * H + gy) * W + gx) * 256 + c16;
          vh = *(const uint4*)&inH[base];
          vl = *(const uint4*)&inL[base];
        }
        int bo = pp * 512 + ((c16 * 2) ^ ((pp & 7) << 4));
        *(uint4*)(sh + bo) = vh;
        *(uint4*)(sh + 17408 + bo) = vl;
      }
    } else {
      const double* __restrict__ inD = A.inD[l];
      for (int pp = prow; pp < 34; pp += 4) {
        int gx = x0 + pp - 1;
        double xv0 = 0.0, xv1 = 0.0;
        if (rowok && gx >= 0 && gx < W) {
          const double* ptr = inD + (((size_t)b * H + gy) * W + gx) * 256 + cst;
          xv0 = ptr[0];
          xv1 = ptr[1];
        }
        _Float16 h0 = (_Float16)((float)xv0);
        _Float16 h1 = (_Float16)((float)xv1);
        float r0 = (float)(xv0 - (double)(float)h0) * 4096.0f;
        float r1 = (float)(xv1 - (double)(float)h1) * 4096.0f;
        _Float16 l0 = (_Float16)r0, l1 = (_Float16)r1;
        unsigned hp = (unsigned)__builtin_bit_cast(unsigned short, h0) |
                      ((unsigned)__builtin_bit_cast(unsigned short, h1) << 16);
        unsigned lp = (unsigned)__builtin_bit_cast(unsigned short, l0) |
                      ((unsigned)__builtin_bit_cast(unsigned short, l1) << 16);
        int bo = pp * 512 + ((cst * 2) ^ ((pp & 7) << 4));
        *(unsigned*)(sh + bo) = hp;
        *(unsigned*)(sh + 17408 + bo) = lp;
      }
    }
    __syncthreads();

    f4_t accA[2][2], accB[2][2];
#pragma unroll
    for (int mt = 0; mt < 2; ++mt)
#pragma unroll
      for (int nt = 0; nt < 2; ++nt) {
        accA[mt][nt] = (f4_t){0.f, 0.f, 0.f, 0.f};
        accB[mt][nt] = (f4_t){0.f, 0.f, 0.f, 0.f};
      }

    for (int kx = 0; kx < 3; ++kx) {
      const int P0 = (ky * 3 + kx) * 8;
      for (int kt = 0; kt < 8; ++kt) {
        h8_t aH[2], aL[2];
#pragma unroll
        for (int mt = 0; mt < 2; ++mt) {
          int pix = mt * 16 + lm + kx;
          int bo = pix * 512 + ((kt * 64 + lq * 16) ^ ((pix & 7) << 4));
          aH[mt] = *(const h8_t*)(sh + bo);
          aL[mt] = *(const h8_t*)(sh + 17408 + bo);
        }
#pragma unroll
        for (int nt = 0; nt < 2; ++nt) {
          size_t eo = (size_t)((P0 + kt) * 16 + wq * 2 + nt) * 512 + lm * 32 + lq * 8;
          h8_t bH = *(const h8_t*)(wHp + eo);
          h8_t bL = *(const h8_t*)(wLp + eo);
#pragma unroll
          for (int mt = 0; mt < 2; ++mt) {
            accB[mt][nt] = __builtin_amdgcn_mfma_f32_16x16x32_f16(aH[mt], bL, accB[mt][nt], 0, 0, 0);
            accB[mt][nt] = __builtin_amdgcn_mfma_f32_16x16x32_f16(aL[mt], bH, accB[mt][nt], 0, 0, 0);
            accA[mt][nt] = __builtin_amdgcn_mfma_f32_16x16x32_f16(aH[mt], bH, accA[mt][nt], 0, 0, 0);
          }
        }
      }
    }
    // per-ky fold into f64 (cross terms carry scale 2^12) — R8 sequence
#pragma unroll
    for (int mt = 0; mt < 2; ++mt)
#pragma unroll
      for (int nt = 0; nt < 2; ++nt)
#pragma unroll
        for (int r = 0; r < 4; ++r)
          dacc[mt][nt][r] += (double)accA[mt][nt][r] +
                             (double)accB[mt][nt][r] * (1.0 / 4096.0);
  }

  // epilogue: D layout col=lane&15 (cout), row=(lane>>4)*4+r (pixel)
#pragma unroll
  for (int mt = 0; mt < 2; ++mt)
#pragma unroll
    for (int nt = 0; nt < 2; ++nt) {
      int cout = wq * 32 + nt * 16 + lm;
#pragma unroll
      for (int r = 0; r < 4; ++r) {
        int gx = x0 + mt * 16 + lq * 4 + r;
        if (gx < W) {
          double v = dacc[mt][nt][r];
          if (RELU) v = fmax(v, 0.0);
          size_t idx = (((size_t)b * H + y) * W + gx) * 256 + cout;
          if (OSPLIT) {
            // same convert sequence as R8's conv2 staging (bit-exact)
            _Float16 hh = (_Float16)((float)v);
            float rr = (float)(v - (double)(float)hh) * 4096.0f;
            _Float16 ll = (_Float16)rr;
            A.outF[l][idx] = (float)v;
            A.outH[l][idx] = __builtin_bit_cast(unsigned short, hh);
            A.outL[l][idx] = __builtin_bit_cast(unsigned short, ll);
          } else {
            A.outD[l][idx] = v;
          }
        }
      }
    }
}

// ---------------- RPN head (obj + delta 1x1) + anchor decode, f64 -----------
struct AnchorHW { double hh[9]; double ww[9]; };

__global__ __launch_bounds__(64) void rpn_head_d(
    const double* __restrict__ tmap,
    const float* __restrict__ w_obj, const float* __restrict__ b_obj,
    const float* __restrict__ w_dlt, const float* __restrict__ b_dlt,
    double* __restrict__ scores, double* __restrict__ boxes,
    int H, int W, int a_off, double stride, AnchorHW anc) {
  __shared__ double tv[256];
  __shared__ double dlt[36];
  const int t = threadIdx.x;
  const int x = blockIdx.x, y = blockIdx.y, b = blockIdx.z;
  const double* px = tmap + (((size_t)b * H + y) * W + x) * 256;
  tv[t] = px[t]; tv[t + 64] = px[t + 64]; tv[t + 128] = px[t + 128]; tv[t + 192] = px[t + 192];
  __syncthreads();
  double sacc = 0.0;
  if (t < 9) {
    sacc = (double)b_obj[t];
    for (int ci = 0; ci < 256; ++ci) sacc += tv[ci] * (double)w_obj[ci * 9 + t];
  } else if (t < 45) {
    int j = t - 9;
    double a = (double)b_dlt[j];
    for (int ci = 0; ci < 256; ++ci) a += tv[ci] * (double)w_dlt[ci * 36 + j];
    dlt[j] = a;
  }
  __syncthreads();
  if (t < 9) {
    int ai = a_off + (y * W + x) * 9 + t;
    scores[(size_t)b * NUM_ANCH + ai] = sacc;
    double cy = (y + 0.5) * stride, cx = (x + 0.5) * stride;
    double hh = anc.hh[t], ww = anc.ww[t];
    float ay1 = (float)fmin(fmax(cy - hh * 0.5, 0.0), 512.0);
    float ax1 = (float)fmin(fmax(cx - ww * 0.5, 0.0), 512.0);
    float ay2 = (float)fmin(fmax(cy + hh * 0.5, 0.0), 512.0);
    float ax2 = (float)fmin(fmax(cx + ww * 0.5, 0.0), 512.0);
    float ahf = ay2 - ay1, awf = ax2 - ax1;
    float actyf = ay1 + ahf * 0.5f, actxf = ax1 + awf * 0.5f;
    double dy = dlt[t * 4 + 0], dx = dlt[t * 4 + 1];
    double dh = dlt[t * 4 + 2], dw = dlt[t * 4 + 3];
    double ncy = dy * (double)ahf + (double)actyf;
    double ncx = dx * (double)awf + (double)actxf;
    double nh = exp(dh) * (double)ahf;
    double nw = exp(dw) * (double)awf;
    double* bo = boxes + ((size_t)b * NUM_ANCH + ai) * 4;
    bo[0] = ncy - nh * 0.5;
    bo[1] = ncx - nw * 0.5;
    bo[2] = ncy + nh * 0.5;
    bo[3] = ncx + nw * 0.5;
  }
}

// ---------------- exact top-1000 per batch (f64 radix-select + bitonic) -----
__device__ inline unsigned long long dkey(double f) {
  unsigned long long u = (unsigned long long)__double_as_longlong(f);
  return u ^ ((unsigned long long)((long long)u >> 63) | 0x8000000000000000ull);
}

__global__ __launch_bounds__(1024) void topk_d(
    const double* __restrict__ scores, const double* __restrict__ boxes,
    double* __restrict__ ss, double* __restrict__ sb) {
  const int A = NUM_ANCH;
  __shared__ unsigned hist[256];
  __shared__ unsigned long long kk[2048];
  __shared__ unsigned id[2048];
  __shared__ unsigned long long s_prefix;
  __shared__ unsigned s_need, s_cnt;
  const int b = blockIdx.x, t = threadIdx.x;
  const double* sc = scores + (size_t)b * A;
  if (t == 0) { s_prefix = 0ull; s_need = 1000; s_cnt = 0; }
  __syncthreads();
  for (int r = 0; r < 8; ++r) {
    if (t < 256) hist[t] = 0;
    __syncthreads();
    const int shift = 56 - 8 * r;
    const unsigned long long prefix = s_prefix;
    unsigned long long maskHigh = 0ull;
    if (r != 0) maskHigh = (~0ull) << (shift + 8);
    for (int i = t; i < A; i += 1024) {
      unsigned long long k = dkey(sc[i]);
      if ((k & maskHigh) == prefix) atomicAdd(&hist[(unsigned)(k >> shift) & 255u], 1u);
    }
    __syncthreads();
    if (t == 0) {
      unsigned need = s_need, cum = 0;
      for (int bin = 255; bin >= 0; --bin) {
        cum += hist[bin];
        if (cum >= need) {
          s_prefix = prefix | ((unsigned long long)bin << shift);
          s_need = need - (cum - hist[bin]);
          break;
        }
      }
    }
    __syncthreads();
  }
  const unsigned long long K = s_prefix;
  for (int i = t; i < A; i += 1024) {
    unsigned long long k = dkey(sc[i]);
    if (k >= K) {
      unsigned pos = atomicAdd(&s_cnt, 1u);
      if (pos < 2048) { kk[pos] = k; id[pos] = (unsigned)i; }
    }
  }
  __syncthreads();
  unsigned cnt = s_cnt;
  for (int i = t; i < 2048; i += 1024)
    if (i >= cnt) { kk[i] = 0ull; id[i] = 0xFFFFFFFFu; }
  __syncthreads();
  for (int k = 2; k <= 2048; k <<= 1) {
    for (int j = k >> 1; j > 0; j >>= 1) {
#pragma unroll
      for (int u = 0; u < 2; ++u) {
        int i = t + u * 1024;
        int ixj = i ^ j;
        if (ixj > i) {
          unsigned long long ka = kk[i], kc = kk[ixj];
          unsigned ia = id[i], ic = id[ixj];
          bool cPrec = (kc > ka) || (kc == ka && ic < ia);
          bool up = (i & k) != 0;
          if (cPrec != up) { kk[i] = kc; kk[ixj] = ka; id[i] = ic; id[ixj] = ia; }
        }
      }
      __syncthreads();
    }
  }
  if (t < 1000) {
    unsigned idx = id[t];
    ss[b * 1000 + t] = sc[idx];
    const double* bp = boxes + ((size_t)b * A + idx) * 4;
    double* op = sb + (b * 1000 + t) * 4;
    op[0] = bp[0]; op[1] = bp[1]; op[2] = bp[2]; op[3] = bp[3];
  }
}

// ---------------- suppression bit-matrix (iou>0.7 & j>i), f64 ---------------
__global__ void suppmat_d(const double* __restrict__ sb,
                          unsigned long long* __restrict__ supp) {
  int g = blockIdx.x * 256 + threadIdx.x;   // 32000 = 2*1000*16
  int w = g & 15;
  int i = (g >> 4) % 1000;
  int b = g / 16000;
  const double* bx = sb + b * 4000;
  double y1 = bx[i * 4 + 0], x1 = bx[i * 4 + 1], y2 = bx[i * 4 + 2], x2 = bx[i * 4 + 3];
  double ai = (y2 - y1) * (x2 - x1);
  unsigned long long m = 0;
  for (int q = 0; q < 64; ++q) {
    int j = w * 64 + q;
    if (j > i && j < 1000) {
      double by1 = bx[j * 4 + 0], bx1 = bx[j * 4 + 1], by2 = bx[j * 4 + 2], bx2 = bx[j * 4 + 3];
      double aj = (by2 - by1) * (bx2 - bx1);
      double iy1 = fmax(y1, by1), ix1 = fmax(x1, bx1);
      double iy2 = fmin(y2, by2), ix2 = fmin(x2, bx2);
      double inter = fmax(iy2 - iy1, 0.0) * fmax(ix2 - ix1, 0.0);
      double iou = inter / (ai + aj - inter + 1e-8);
      if (iou > 0.7) m |= (1ull << q);
    }
  }
  supp[g] = m;
}

// ---------------- greedy NMS reduce + slot scatter --------------------------
__global__ __launch_bounds__(64) void nms_reduce_d(
    const double* __restrict__ ss, const double* __restrict__ sb,
    const unsigned long long* __restrict__ supp,
    float* __restrict__ rois, double* __restrict__ rois64) {
  __shared__ unsigned long long aliveS[16];
  __shared__ int pref[16];
  const int b = blockIdx.x, lane = threadIdx.x;
  unsigned long long myword = 0;
  if (lane < 16) {
    for (int q = 0; q < 64; ++q) {
      int j = lane * 64 + q;
      if (j < 1000 && ss[b * 1000 + j] > 0.0) myword |= (1ull << q);
    }
  }
  const unsigned long long* sp = supp + (size_t)b * 16000;
  unsigned long long cur = (lane < 16) ? sp[lane] : 0ull;
  for (int i = 0; i < 1000; ++i) {
    unsigned long long nxt = (lane < 16 && i < 999) ? sp[(i + 1) * 16 + lane] : 0ull;
    unsigned long long wv = __shfl(myword, i >> 6);
    if ((wv >> (i & 63)) & 1ull) {
      if (lane < 16) myword &= ~cur;
    }
    cur = nxt;
  }
  if (lane < 16) aliveS[lane] = myword;
  __syncthreads();
  if (lane == 0) {
    int s = 0;
    for (int w = 0; w < 16; ++w) { pref[w] = s; s += __popcll(aliveS[w]); }
  }
  float* ro = rois + b * 4000;
  double* rd = rois64 + b * 4000;
  for (int k = lane; k < 4000; k += 64) { ro[k] = 0.0f; rd[k] = 0.0; }
  __syncthreads();
  for (int j = lane; j < 1000; j += 64) {
    int w = j >> 6;
    unsigned long long word = aliveS[w];
    if ((word >> (j & 63)) & 1ull) {
      unsigned long long below = (j & 63) ? (word & ((1ull << (j & 63)) - 1ull)) : 0ull;
      int slot = pref[w] + __popcll(below);
      const double* bp = sb + (b * 1000 + j) * 4;
      ro[slot * 4 + 0] = (float)bp[0]; ro[slot * 4 + 1] = (float)bp[1];
      ro[slot * 4 + 2] = (float)bp[2]; ro[slot * 4 + 3] = (float)bp[3];
      rd[slot * 4 + 0] = bp[0]; rd[slot * 4 + 1] = bp[1];
      rd[slot * 4 + 2] = bp[2]; rd[slot * 4 + 3] = bp[3];
    }
  }
}

// ---------------- ROI align: f32 maps, f64 math -> hi/lo bf16 feats ---------
__global__ __launch_bounds__(256) void roi_align_d(
    const float* __restrict__ o2, const float* __restrict__ o3,
    const float* __restrict__ o4, const float* __restrict__ o5,
    const float* __restrict__ o6, const double* __restrict__ rois64,
    unsigned short* __restrict__ featsH, unsigned short* __restrict__ featsL) {
  __shared__ double s_wy[14], s_wx[14];
  __shared__ int s_y0[14], s_y1[14], s_x0[14], s_x1[14];
  const int t = threadIdx.x;
  const int b = blockIdx.x / 1000, r = blockIdx.x % 1000;
  const double* box = rois64 + (b * 1000 + r) * 4;
  double b0 = box[0], b1 = box[1], b2 = box[2], b3 = box[3];
  double h = b2 - b0, w = b3 - b1;
  double size = sqrt(fmax(h * w, 1e-8));
  double lf = floor(log2(size / 224.0) + 4.0);
  lf = fmin(fmax(lf, 2.0), 6.0);
  int lvl = (int)lf;
  int stride_i = 1 << lvl;
  double stride = (double)stride_i;
  int fs_i = 512 >> lvl;
  double fs = (double)fs_i;
  if (t < 14) {
    double v = b0 / stride + ((t + 0.5) * (h / stride)) / 14.0 - 0.5;
    v = fmin(fmax(v, 0.0), fs - 1.0);
    int i0 = (int)floor(v);
    s_y0[t] = i0; s_y1[t] = min(i0 + 1, fs_i - 1); s_wy[t] = v - (double)i0;
  } else if (t >= 64 && t < 78) {
    int u = t - 64;
    double v = b1 / stride + ((u + 0.5) * (w / stride)) / 14.0 - 0.5;
    v = fmin(fmax(v, 0.0), fs - 1.0);
    int i0 = (int)floor(v);
    s_x0[u] = i0; s_x1[u] = min(i0 + 1, fs_i - 1); s_wx[u] = v - (double)i0;
  }
  __syncthreads();
  const float* omaps[5] = {o2, o3, o4, o5, o6};
  const float* fm = omaps[lvl - 2] + (size_t)b * fs_i * fs_i * 256 + t;
  size_t obase = ((size_t)(b * 1000 + r) * 49) * 256 + t;
  for (int oy = 0; oy < 7; ++oy) {
    double acc[7] = {0, 0, 0, 0, 0, 0, 0};
#pragma unroll
    for (int sy = 0; sy < 2; ++sy) {
      int yy = oy * 2 + sy;
      int y0 = s_y0[yy], y1 = s_y1[yy];
      double wy = s_wy[yy];
      const float* r0 = fm + (size_t)y0 * fs_i * 256;
      const float* r1 = fm + (size_t)y1 * fs_i * 256;
      for (int ox = 0; ox < 7; ++ox) {
#pragma unroll
        for (int sx = 0; sx < 2; ++sx) {
          int xx = ox * 2 + sx;
          int x0 = s_x0[xx], x1 = s_x1[xx];
          double wx = s_wx[xx];
          double v00 = (double)r0[x0 * 256], v01 = (double)r0[x1 * 256];
          double v10 = (double)r1[x0 * 256], v11 = (double)r1[x1 * 256];
          double val = (1.0 - wy) * ((1.0 - wx) * v00 + wx * v01) +
                       wy * ((1.0 - wx) * v10 + wx * v11);
          acc[ox] += val;
        }
      }
    }
    for (int ox = 0; ox < 7; ++ox) {
      float v = (float)(acc[ox] * 0.25);
      unsigned short hh = f2bf(v);
      size_t idx = obase + (size_t)(oy * 7 + ox) * 256;
      featsH[idx] = hh;
      featsL[idx] = f2bf(v - bf2f(hh));
    }
  }
}

// ---------------- split f32 [K][N] -> bf16 hi/lo transposed [N][K] ----------
__global__ __launch_bounds__(256) void split_transpose(
    const float* __restrict__ W, unsigned short* __restrict__ TH,
    unsigned short* __restrict__ TL, int K, int N) {
  __shared__ unsigned short shh[32 * 33], shl[32 * 33];
  const int kt = blockIdx.y * 32, nt = blockIdx.x * 32;
  const int tx = threadIdx.x & 31, ty = threadIdx.x >> 5;   // 32x8
  for (int yy = ty; yy < 32; yy += 8) {
    float v = W[(size_t)(kt + yy) * N + nt + tx];
    unsigned short h = f2bf(v);
    shh[yy * 33 + tx] = h;
    shl[yy * 33 + tx] = f2bf(v - bf2f(h));
  }
  __syncthreads();
  for (int yy = ty; yy < 32; yy += 8) {
    TH[(size_t)(nt + yy) * K + kt + tx] = shh[tx * 33 + yy];
    TL[(size_t)(nt + yy) * K + kt + tx] = shl[tx * 33 + yy];
  }
}

// ---------------- split-K partial bf16 MFMA GEMM 128x128 --------------------
struct GemmPArgs {
  const unsigned short* AH;
  const unsigned short* AL;
  const unsigned short* BTH;
  const unsigned short* BTL;
  float* P[4];
  int M, N, K, KC;
};

__global__ __launch_bounds__(256) void gemm_mfma_partial(GemmPArgs G) {
  __shared__ __align__(16) unsigned short AsH[128 * 40], AsL[128 * 40];
  __shared__ __align__(16) unsigned short BsH[128 * 40], BsL[128 * 40];
  const int t = threadIdx.x;
  const int lane = t & 63;
  const int wave = t >> 6;
  const int lm = lane & 15, lq = lane >> 4;
  const int wn = wave & 1, wm = wave >> 1;
  const int m0 = blockIdx.y * 128, n0 = blockIdx.x * 128;
  const int kc = blockIdx.z;
  const int kbeg = kc * G.KC, kend = kbeg + G.KC;
  const int M = G.M, N = G.N, K = G.K;
  float* __restrict__ C = G.P[kc];
  const unsigned short* __restrict__ AH = G.AH;
  const unsigned short* __restrict__ AL = G.AL;
  const unsigned short* __restrict__ BTH = G.BTH;
  const unsigned short* __restrict__ BTL = G.BTL;
  const int sr = t >> 1;            // 0..127
  const int sk = (t & 1) * 16;      // 0,16

  f4_t acc[4][4];
#pragma unroll
  for (int mt = 0; mt < 4; ++mt)
#pragma unroll
    for (int nt = 0; nt < 4; ++nt) acc[mt][nt] = (f4_t){0.f, 0.f, 0.f, 0.f};

  const uint4 zz = {0u, 0u, 0u, 0u};
  for (int k0 = kbeg; k0 < kend; k0 += 32) {
    __syncthreads();
    {
      uint4 vh0 = zz, vh1 = zz, vl0 = zz, vl1 = zz;
      if (m0 + sr < M) {
        size_t off = (size_t)(m0 + sr) * K + k0 + sk;
        vh0 = *(const uint4*)&AH[off];
        vh1 = *(const uint4*)&AH[off + 8];
        vl0 = *(const uint4*)&AL[off];
        vl1 = *(const uint4*)&AL[off + 8];
      }
      *(uint4*)&AsH[sr * 40 + sk] = vh0;
      *(uint4*)&AsH[sr * 40 + sk + 8] = vh1;
      *(uint4*)&AsL[sr * 40 + sk] = vl0;
      *(uint4*)&AsL[sr * 40 + sk + 8] = vl1;
    }
    {
      size_t off = (size_t)(n0 + sr) * K + k0 + sk;
      *(uint4*)&BsH[sr * 40 + sk] = *(const uint4*)&BTH[off];
      *(uint4*)&BsH[sr * 40 + sk + 8] = *(const uint4*)&BTH[off + 8];
      *(uint4*)&BsL[sr * 40 + sk] = *(const uint4*)&BTL[off];
      *(uint4*)&BsL[sr * 40 + sk + 8] = *(const uint4*)&BTL[off + 8];
    }
    __syncthreads();

    bf8_t aH[4], aL[4], bH[4], bL[4];
#pragma unroll
    for (int mt = 0; mt < 4; ++mt) {
      int idx = (wm * 64 + mt * 16 + lm) * 40 + lq * 8;
      aH[mt] = *(const bf8_t*)&AsH[idx];
      aL[mt] = *(const bf8_t*)&AsL[idx];
    }
#pragma unroll
    for (int nt = 0; nt < 4; ++nt) {
      int idx = (wn * 64 + nt * 16 + lm) * 40 + lq * 8;
      bH[nt] = *(const bf8_t*)&BsH[idx];
      bL[nt] = *(const bf8_t*)&BsL[idx];
    }
#pragma unroll
    for (int mt = 0; mt < 4; ++mt)
#pragma unroll
      for (int nt = 0; nt < 4; ++nt) {
        f4_t a0 = acc[mt][nt];
        a0 = __builtin_amdgcn_mfma_f32_16x16x32_bf16(aL[mt], bH[nt], a0, 0, 0, 0);
        a0 = __builtin_amdgcn_mfma_f32_16x16x32_bf16(aH[mt], bL[nt], a0, 0, 0, 0);
        a0 = __builtin_amdgcn_mfma_f32_16x16x32_bf16(aH[mt], bH[nt], a0, 0, 0, 0);
        acc[mt][nt] = a0;
      }
  }
#pragma unroll
  for (int mt = 0; mt < 4; ++mt) {
#pragma unroll
    for (int nt = 0; nt < 4; ++nt) {
      int ncol = n0 + wn * 64 + nt * 16 + lm;
#pragma unroll
      for (int r = 0; r < 4; ++r) {
        int m = m0 + wm * 64 + mt * 16 + lq * 4 + r;
        if (m < M) C[(size_t)m * N + ncol] = acc[mt][nt][r];
      }
    }
  }
}

// ---------------- reduce 4 partials + bias + relu -> bf16 hi/lo -------------
__global__ void reduce4_split(const float* __restrict__ p0, const float* __restrict__ p1,
                              const float* __restrict__ p2, const float* __restrict__ p3,
                              const float* __restrict__ bias,
                              unsigned short* __restrict__ H, unsigned short* __restrict__ L,
                              int n) {
  int i = blockIdx.x * 256 + threadIdx.x;
  if (i < n) {
    float v = ((p0[i] + p1[i]) + p2[i]) + p3[i] + bias[i & 1023];
    v = fmaxf(v, 0.0f);
    unsigned short h = f2bf(v);
    H[i] = h;
    L[i] = f2bf(v - bf2f(h));
  }
}

// ---------------- reduce 4 partials + bias + relu -> f32 --------------------
__global__ void reduce4_f32(const float* __restrict__ p0, const float* __restrict__ p1,
                            const float* __restrict__ p2, const float* __restrict__ p3,
                            const float* __restrict__ bias, float* __restrict__ C, int n) {
  int i = blockIdx.x * 256 + threadIdx.x;
  if (i < n) {
    float v = ((p0[i] + p1[i]) + p2[i]) + p3[i] + bias[i & 1023];
    C[i] = fmaxf(v, 0.0f);
  }
}

// ---------------- final box(4) + cls(81) heads, f32 -------------------------
__global__ __launch_bounds__(128) void boxcls_kernel(
    const float* __restrict__ x, const float* __restrict__ w_box,
    const float* __restrict__ b_box, const float* __restrict__ w_cls,
    const float* __restrict__ b_cls, float* __restrict__ out) {
  __shared__ float xv[1024];
  const int t = threadIdx.x;
  const int row = blockIdx.x;
  const float* xp = x + (size_t)row * 1024;
#pragma unroll
  for (int k = 0; k < 8; ++k) xv[k * 128 + t] = xp[k * 128 + t];
  __syncthreads();
  if (t < 4) {
    float acc = b_box[t];
    for (int k = 0; k < 1024; ++k) acc += xv[k] * w_box[k * 4 + t];
    out[8000 + row * 4 + t] = acc;
  } else if (t < 85) {
    int j = t - 4;
    float acc = b_cls[j];
    for (int k = 0; k < 1024; ++k) acc += xv[k] * w_cls[k * 81 + j];
    out[16000 + row * 81 + j] = acc;
  }
}

// ---------------------------------------------------------------------------
extern "C" void kernel_launch(void* const* d_in, const int* in_sizes, int n_in,
                              void* d_out, int out_size, void* d_ws, size_t ws_size,
                              hipStream_t stream) {
  (void)in_sizes; (void)n_in; (void)out_size; (void)ws_size;

  const float* c_in[4] = {(const float*)d_in[0], (const float*)d_in[1],
                          (const float*)d_in[2], (const float*)d_in[3]};
  const float *w_l[5], *b_l[5], *w_o[5], *b_o[5];
  for (int l = 0; l < 5; ++l) {
    w_l[l] = (const float*)d_in[4 + l * 4 + 0];
    b_l[l] = (const float*)d_in[4 + l * 4 + 1];
    w_o[l] = (const float*)d_in[4 + l * 4 + 2];
    b_o[l] = (const float*)d_in[4 + l * 4 + 3];
  }
  const float* w_rpn = (const float*)d_in[24];
  const float* b_rpn = (const float*)d_in[25];
  const float* w_obj = (const float*)d_in[26];
  const float* b_obj = (const float*)d_in[27];
  const float* w_dlt = (const float*)d_in[28];
  const float* b_dlt = (const float*)d_in[29];
  const float* w_fc1 = (const float*)d_in[30];
  const float* b_fc1 = (const float*)d_in[31];
  const float* w_fc2 = (const float*)d_in[32];
  const float* b_fc2 = (const float*)d_in[33];
  const float* w_box = (const float*)d_in[34];
  const float* b_box = (const float*)d_in[35];
  const float* w_cls = (const float*)d_in[36];
  const float* b_cls = (const float*)d_in[37];

  char* W8 = (char*)d_ws;
  // o region: f32 maps + f16 hi/lo planes
  float* oF32 = (float*)(W8 + 0);
  unsigned short* oH = (unsigned short*)(W8 + 44695552);
  unsigned short* oL = (unsigned short*)(W8 + 67043328);
  // p region: f64 (decision path)
  double* p64 = (double*)(W8 + 89391104);
  float* c6buf = (float*)(W8 + 178782208);
  double* scores = (double*)(W8 + 179830784);
  double* boxes = (double*)(W8 + 182973440);
  double* ssb = (double*)(W8 + 195544064);
  double* sbb = (double*)(W8 + 195560064);
  double* rois64 = (double*)(W8 + 195624064);
  unsigned long long* suppb = (unsigned long long*)(W8 + 195688064);
  unsigned short* featsH = (unsigned short*)(W8 + 89391104);
  unsigned short* featsL = (unsigned short*)(W8 + 139567104);
  float* fc1b = (float*)(W8 + 0);
  float* fc2b = (float*)(W8 + 8192000);
  unsigned short* wT1H = (unsigned short*)(W8 + 16384000);
  unsigned short* wT1L = (unsigned short*)(W8 + 42074112);
  unsigned short* wT2H = (unsigned short*)(W8 + 67764224);
  unsigned short* wT2L = (unsigned short*)(W8 + 69861376);
  unsigned short* fc1H = (unsigned short*)(W8 + 89391104);
  unsigned short* fc1L = (unsigned short*)(W8 + 93487104);
  float* fc1p1 = (float*)(W8 + 8192000);
  float* fc1p2 = (float*)(W8 + 71958528);
  float* fc1p3 = (float*)(W8 + 80150528);
  float* fc2p1 = (float*)(W8 + 0);
  float* fc2p2 = (float*)(W8 + 16384000);
  float* fc2p3 = (float*)(W8 + 24576000);
  float* outf = (float*)d_out;

  // conv f16 weight planes (scores/boxes regions, dead until rpn_head)
  unsigned short* woH[5];
  unsigned short* woL[5];
  for (int l = 0; l < 5; ++l) {
    woH[l] = (unsigned short*)(W8 + 182973440 + (size_t)l * 2359296);
    woL[l] = (unsigned short*)(W8 + 182973440 + (size_t)l * 2359296 + 1179648);
  }
  unsigned short* wrH = (unsigned short*)(W8 + 179830784);
  unsigned short* wrL = (unsigned short*)(W8 + 179830784 + 1179648);

  const size_t OFF[5] = {0, 8388608, 10485760, 11010048, 11141120};
  const int HS[5] = {128, 64, 32, 16, 8};
  const int a_off[5] = {0, 147456, 184320, 193536, 195840};
  const double strides[5] = {4.0, 8.0, 16.0, 32.0, 64.0};
  const double SZ[5] = {16.0, 32.0, 64.0, 128.0, 256.0};
  AnchorHW anc[5];
  for (int l = 0; l < 5; ++l) {
    const double ars[3] = {0.5, 1.0, 2.0};
    for (int s = 0; s < 3; ++s) {
      double sc = pow(2.0, s / 3.0);
      for (int a = 0; a < 3; ++a) {
        double sq = sqrt(ars[a]);
        anc[l].hh[s * 3 + a] = SZ[l] * sc / sq;
        anc[l].ww[s * 3 + a] = SZ[l] * sc * sq;
      }
    }
  }

  // ---- weight split for conv passes ----
  for (int l = 0; l < 5; ++l)
    wsplit_f16<<<2304, 256, 0, stream>>>(w_o[l], woH[l], woL[l]);
  wsplit_f16<<<2304, 256, 0, stream>>>(w_rpn, wrH, wrL);

  // ---- FPN (f64, decision path — unchanged from R8) ----
  maxpool_kernel<<<1024, 256, 0, stream>>>(c_in[3], c6buf);
  lateral_d<2048><<<32, 256, 0, stream>>>(c6buf, w_l[4], b_l[4], p64 + OFF[4]);   // p6
  lateral_d<2048><<<128, 256, 0, stream>>>(c_in[3], w_l[3], b_l[3], p64 + OFF[3]); // p5
  upadd_d<<<512, 256, 0, stream>>>(p64 + OFF[3], p64 + OFF[4], 16, 16);
  lateral_d<1024><<<512, 256, 0, stream>>>(c_in[2], w_l[2], b_l[2], p64 + OFF[2]); // p4
  upadd_d<<<2048, 256, 0, stream>>>(p64 + OFF[2], p64 + OFF[3], 32, 32);
  lateral_d<512><<<2048, 256, 0, stream>>>(c_in[1], w_l[1], b_l[1], p64 + OFF[1]); // p3
  upadd_d<<<8192, 256, 0, stream>>>(p64 + OFF[1], p64 + OFF[2], 64, 64);
  lateral_d<256><<<8192, 256, 0, stream>>>(c_in[0], w_l[0], b_l[0], p64 + OFF[0]); // p2
  upadd_d<<<32768, 256, 0, stream>>>(p64 + OFF[0], p64 + OFF[1], 128, 128);

  // ---- fused 5-level conv passes (double-f16 MFMA, 8-wave) ----
  ConvArgsU co, ct;
  int total = 0;
  for (int l = 0; l < 5; ++l) {
    int nbx = (HS[l] + 31) / 32;
    // conv1: p64 (f64 stage) -> oF32 + oH/oL planes
    co.inD[l] = p64 + OFF[l]; co.inH[l] = nullptr; co.inL[l] = nullptr;
    co.outF[l] = oF32 + OFF[l]; co.outH[l] = oH + OFF[l]; co.outL[l] = oL + OFF[l];
    co.outD[l] = nullptr;
    co.wH[l] = woH[l]; co.wL[l] = woL[l]; co.bias[l] = b_o[l];
    // conv2: oH/oL planes (copy stage) -> p64 tower (f64)
    ct.inD[l] = nullptr; ct.inH[l] = oH + OFF[l]; ct.inL[l] = oL + OFF[l];
    ct.outF[l] = nullptr; ct.outH[l] = nullptr; ct.outL[l] = nullptr;
    ct.outD[l] = p64 + OFF[l];
    ct.wH[l] = wrH;  ct.wL[l] = wrL;  ct.bias[l] = b_rpn;
    co.H[l] = ct.H[l] = HS[l];
    co.nbx[l] = ct.nbx[l] = nbx;
    co.off[l] = ct.off[l] = total;
    total += nbx * HS[l] * 2;
  }
  co.off[5] = ct.off[5] = total;   // 1392
  conv3x3_u<false, false, true><<<total, 512, 0, stream>>>(co);
  conv3x3_u<true, true, false><<<total, 512, 0, stream>>>(ct);

  for (int l = 0; l < 5; ++l) {
    dim3 g(HS[l], HS[l], 2);
    rpn_head_d<<<g, 64, 0, stream>>>(p64 + OFF[l], w_obj, b_obj, w_dlt, b_dlt,
                                     scores, boxes, HS[l], HS[l], a_off[l],
                                     strides[l], anc[l]);
  }
  // ---- top-1000 + NMS (f64) ----
  topk_d<<<2, 1024, 0, stream>>>(scores, boxes, ssb, sbb);
  suppmat_d<<<125, 256, 0, stream>>>(sbb, suppb);
  nms_reduce_d<<<2, 64, 0, stream>>>(ssb, sbb, suppb, outf, rois64);
  // ---- ROI align (f32 maps -> hi/lo bf16 feats) ----
  roi_align_d<<<2000, 256, 0, stream>>>(oF32 + OFF[0], oF32 + OFF[1], oF32 + OFF[2],
                                        oF32 + OFF[3], oF32 + OFF[4], rois64,
                                        featsH, featsL);
  // ---- FC head: split weights (o region now dead), split-K MFMA GEMMs ----
  split_transpose<<<dim3(32, 392), 256, 0, stream>>>(w_fc1, wT1H, wT1L, 12544, 1024);
  split_transpose<<<dim3(32, 32), 256, 0, stream>>>(w_fc2, wT2H, wT2L, 1024, 1024);

  GemmPArgs g1;
  g1.AH = featsH; g1.AL = featsL; g1.BTH = wT1H; g1.BTL = wT1L;
  g1.P[0] = fc1b; g1.P[1] = fc1p1; g1.P[2] = fc1p2; g1.P[3] = fc1p3;
  g1.M = 2000; g1.N = 1024; g1.K = 12544; g1.KC = 3136;
  gemm_mfma_partial<<<dim3(8, 16, 4), 256, 0, stream>>>(g1);
  reduce4_split<<<8000, 256, 0, stream>>>(fc1b, fc1p1, fc1p2, fc1p3, b_fc1,
                                          fc1H, fc1L, 2048000);

  GemmPArgs g2;
  g2.AH = fc1H; g2.AL = fc1L; g2.BTH = wT2H; g2.BTL = wT2L;
  g2.P[0] = fc2b; g2.P[1] = fc2p1; g2.P[2] = fc2p2; g2.P[3] = fc2p3;
  g2.M = 2000; g2.N = 1024; g2.K = 1024; g2.KC = 256;
  gemm_mfma_partial<<<dim3(8, 16, 4), 256, 0, stream>>>(g2);
  reduce4_f32<<<8000, 256, 0, stream>>>(fc2b, fc2p1, fc2p2, fc2p3, b_fc2,
                                        fc2b, 2048000);

  boxcls_kernel<<<2000, 128, 0, stream>>>(fc2b, w_box, b_box, w_cls, b_cls, outf);
}

// Round 6
// 2763.164 us; speedup vs baseline: 1.7089x; 1.1204x over previous
//
#include <hip/hip_runtime.h>
#include <math.h>

// ---------------------------------------------------------------------------
// Faster-RCNN head. Round 11:
//  - topk_d (415us, 2 blocks on 256 CUs, Occupancy 0.37% — pure parallelism
//    starvation) replaced by a multi-kernel parallel radix-select with the
//    SAME selection semantics:
//      init -> 3x(hist[2048 bins, 11 bits @ shifts 53/42/31] grid(64,2) ->
//      pick suffix-scan) -> collect(all keys >= 33-bit prefix floor, atomic
//      append) -> final(identical 2048 bitonic + tie-break + top-1000).
//    Candidate set is a superset of the old kernel's (>= the 1000th key's
//    33-bit class floor); same 2048 cap; same (key desc, id asc) sort ->
//    identical deterministic output. Scratch lives in the oH region (dead
//    between conv2 and the fc overlay).
//  - Everything else identical to R10 (bit-exact f64 decision path).
//
// Workspace (BYTES):
//   o region [0 .. 89,391,104):
//     oF32 [0 .. 44,695,552)  oH [44,695,552 .. 67,043,328)
//     oL  [67,043,328 .. 89,391,104)
//     topk scratch overlays oH start (dead after conv2): hist 49,152 +
//     prefix/need/cnt + cand keys 32,768 + ids 16,384  (< 100 KB)
//   p64  (double, 11,173,888 el)  [89,391,104 .. 178,782,208)
//   c6   (float)                  [178,782,208 .. 179,830,784)
//   scores (double)               [179,830,784 .. 182,973,440)
//   boxes  (double)               [182,973,440 .. 195,544,064)
//   ss/sb/rois64/supp tail        [195,544,064 .. 195,944,064)
//   featsH/L overlap p64 after rpn; fc region overlays o region after
//   roi_align (same live-range audit as R8/R10).
// ---------------------------------------------------------------------------

#define NUM_ANCH 196416

typedef double d4 __attribute__((ext_vector_type(4)));
typedef __attribute__((ext_vector_type(8))) short bf8_t;
typedef __attribute__((ext_vector_type(4))) float f4_t;
typedef _Float16 h8_t __attribute__((ext_vector_type(8)));

__device__ inline unsigned short f2bf(float x) {
  unsigned u = __float_as_uint(x);
  unsigned r = (u + 0x7fffu + ((u >> 16) & 1u)) >> 16;   // RNE
  return (unsigned short)r;
}
__device__ inline float bf2f(unsigned short h) {
  return __uint_as_float(((unsigned)h) << 16);
}

// ---------------- maxpool2 c5 (2,16,16,2048) -> c6 (2,8,8,2048), f32 --------
__global__ void maxpool_kernel(const float* __restrict__ in, float* __restrict__ out) {
  int idx = blockIdx.x * 256 + threadIdx.x;     // 262144 total
  int c = idx & 2047;
  int x = (idx >> 11) & 7;
  int y = (idx >> 14) & 7;
  int b = idx >> 17;
  const float* p = in + (((size_t)b * 16 + 2 * y) * 16 + 2 * x) * 2048 + c;
  float m = fmaxf(fmaxf(p[0], p[2048]), fmaxf(p[16 * 2048], p[16 * 2048 + 2048]));
  out[idx] = m;
}

// ---------------- 1x1 lateral conv + bias, f32 in -> f64 out ----------------
template <int CIN>
__global__ __launch_bounds__(256) void lateral_d(
    const float* __restrict__ in, const float* __restrict__ w,
    const float* __restrict__ bias, double* __restrict__ out) {
  const int t = threadIdx.x;
  const size_t pix0 = (size_t)blockIdx.x * 4;
  double b = (double)bias[t];
  double a0 = b, a1 = b, a2 = b, a3 = b;
  const float* i0 = in + pix0 * CIN;
  for (int ci = 0; ci < CIN; ++ci) {
    double wv = (double)w[ci * 256 + t];
    a0 += (double)i0[ci] * wv;
    a1 += (double)i0[CIN + ci] * wv;
    a2 += (double)i0[2 * CIN + ci] * wv;
    a3 += (double)i0[3 * CIN + ci] * wv;
  }
  out[(pix0 + 0) * 256 + t] = a0;
  out[(pix0 + 1) * 256 + t] = a1;
  out[(pix0 + 2) * 256 + t] = a2;
  out[(pix0 + 3) * 256 + t] = a3;
}

// ---------------- fine += upsample2(coarse), C=256, f64 ---------------------
__global__ void upadd_d(double* __restrict__ fine, const double* __restrict__ coarse,
                        int Hf, int Wf) {
  int idx = blockIdx.x * 256 + threadIdx.x;
  int c = idx & 255;
  int rem = idx >> 8;
  int x = rem % Wf; rem /= Wf;
  int y = rem % Hf;
  int b = rem / Hf;
  fine[idx] += coarse[(((size_t)b * (Hf >> 1) + (y >> 1)) * (Wf >> 1) + (x >> 1)) * 256 + c];
}

// ---------------- weight split: f32 HWIO -> f16 hi/lo, B-frag layout --------
__global__ __launch_bounds__(256) void wsplit_f16(
    const float* __restrict__ W, unsigned short* __restrict__ PH,
    unsigned short* __restrict__ PL) {
  int id = blockIdx.x * 256 + threadIdx.x;      // 589824 total
  int co = id & 255, ci = (id >> 8) & 255, p9 = id >> 16;
  float w = W[id];
  _Float16 wh = (_Float16)w;
  float rw = (w - (float)wh) * 4096.0f;         // exact (Sterbenz) then *2^12
  _Float16 wl = (_Float16)rw;
  int q = (p9 * 8 + (ci >> 5)) * 16 + (co >> 4);
  int idx = q * 512 + (co & 15) * 32 + (ci & 31);
  PH[idx] = __builtin_bit_cast(unsigned short, wh);
  PL[idx] = __builtin_bit_cast(unsigned short, wl);
}

// ---------------- fused 5-level 3x3 conv, double-f16 MFMA, 8-wave -----------
struct ConvArgsU {
  const double* inD[5];
  const unsigned short* inH[5];
  const unsigned short* inL[5];
  float* outF[5];
  unsigned short* outH[5];
  unsigned short* outL[5];
  double* outD[5];
  const unsigned short* wH[5];
  const unsigned short* wL[5];
  const float* bias[5];
  int H[5];
  int nbx[5];
  int off[6];
};

template <bool PLANES, bool RELU, bool OSPLIT>
__global__ __launch_bounds__(512, 4) void conv3x3_u(ConvArgsU A) {
  __shared__ uint4 smemq[34816 / 16];
  char* sh = (char*)smemq;
  const int bx = blockIdx.x;
  int l = 0;
#pragma unroll
  for (int i = 1; i < 5; ++i)
    if (bx >= A.off[i]) l = i;
  const int rel = bx - A.off[l];
  const int H = A.H[l];
  const int W = H;
  const int nbx = A.nbx[l];
  const int x0 = (rel % nbx) * 32;
  const int y = (rel / nbx) % H;
  const int b = rel / (nbx * H);
  const unsigned short* __restrict__ wHp = A.wH[l];
  const unsigned short* __restrict__ wLp = A.wL[l];
  const float* __restrict__ bias = A.bias[l];

  const int t = threadIdx.x;
  const int lane = t & 63;
  const int wq = t >> 6;        // cout eighth (32 couts)
  const int lm = lane & 15;     // A row (pixel) / B col (cout)
  const int lq = lane >> 4;     // k-subgroup of 8

  d4 dacc[2][2];
#pragma unroll
  for (int mt = 0; mt < 2; ++mt)
#pragma unroll
    for (int nt = 0; nt < 2; ++nt) {
      double bv = (double)bias[wq * 32 + nt * 16 + lm];
      dacc[mt][nt] = (d4){bv, bv, bv, bv};
    }

  const int cst = (t & 127) * 2;   // f64 path: channel pair
  const int prow = t >> 7;         // f64 path: pixel phase 0..3
  const int c16 = (t & 31) * 8;    // plane path: 8-channel chunk (16B)
  const int pp0 = t >> 5;          // plane path: pixel 0..15

  for (int ky = 0; ky < 3; ++ky) {
    const int gy = y + ky - 1;
    const bool rowok = (gy >= 0 && gy < H);
    __syncthreads();
    if (PLANES) {
      const unsigned short* __restrict__ inH = A.inH[l];
      const unsigned short* __restrict__ inL = A.inL[l];
      for (int pp = pp0; pp < 34; pp += 16) {
        int gx = x0 + pp - 1;
        uint4 vh = {0u, 0u, 0u, 0u}, vl = {0u, 0u, 0u, 0u};
        if (rowok && gx >= 0 && gx < W) {
          size_t base = (((size_t)b * H + gy) * W + gx) * 256 + c16;
          vh = *(const uint4*)&inH[base];
          vl = *(const uint4*)&inL[base];
        }
        int bo = pp * 512 + ((c16 * 2) ^ ((pp & 7) << 4));
        *(uint4*)(sh + bo) = vh;
        *(uint4*)(sh + 17408 + bo) = vl;
      }
    } else {
      const double* __restrict__ inD = A.inD[l];
      for (int pp = prow; pp < 34; pp += 4) {
        int gx = x0 + pp - 1;
        double xv0 = 0.0, xv1 = 0.0;
        if (rowok && gx >= 0 && gx < W) {
          const double* ptr = inD + (((size_t)b * H + gy) * W + gx) * 256 + cst;
          xv0 = ptr[0];
          xv1 = ptr[1];
        }
        _Float16 h0 = (_Float16)((float)xv0);
        _Float16 h1 = (_Float16)((float)xv1);
        float r0 = (float)(xv0 - (double)(float)h0) * 4096.0f;
        float r1 = (float)(xv1 - (double)(float)h1) * 4096.0f;
        _Float16 l0 = (_Float16)r0, l1 = (_Float16)r1;
        unsigned hp = (unsigned)__builtin_bit_cast(unsigned short, h0) |
                      ((unsigned)__builtin_bit_cast(unsigned short, h1) << 16);
        unsigned lp = (unsigned)__builtin_bit_cast(unsigned short, l0) |
                      ((unsigned)__builtin_bit_cast(unsigned short, l1) << 16);
        int bo = pp * 512 + ((cst * 2) ^ ((pp & 7) << 4));
        *(unsigned*)(sh + bo) = hp;
        *(unsigned*)(sh + 17408 + bo) = lp;
      }
    }
    __syncthreads();

    f4_t accA[2][2], accB[2][2];
#pragma unroll
    for (int mt = 0; mt < 2; ++mt)
#pragma unroll
      for (int nt = 0; nt < 2; ++nt) {
        accA[mt][nt] = (f4_t){0.f, 0.f, 0.f, 0.f};
        accB[mt][nt] = (f4_t){0.f, 0.f, 0.f, 0.f};
      }

    for (int kx = 0; kx < 3; ++kx) {
      const int P0 = (ky * 3 + kx) * 8;
      for (int kt = 0; kt < 8; ++kt) {
        h8_t aH[2], aL[2];
#pragma unroll
        for (int mt = 0; mt < 2; ++mt) {
          int pix = mt * 16 + lm + kx;
          int bo = pix * 512 + ((kt * 64 + lq * 16) ^ ((pix & 7) << 4));
          aH[mt] = *(const h8_t*)(sh + bo);
          aL[mt] = *(const h8_t*)(sh + 17408 + bo);
        }
#pragma unroll
        for (int nt = 0; nt < 2; ++nt) {
          size_t eo = (size_t)((P0 + kt) * 16 + wq * 2 + nt) * 512 + lm * 32 + lq * 8;
          h8_t bH = *(const h8_t*)(wHp + eo);
          h8_t bL = *(const h8_t*)(wLp + eo);
#pragma unroll
          for (int mt = 0; mt < 2; ++mt) {
            accB[mt][nt] = __builtin_amdgcn_mfma_f32_16x16x32_f16(aH[mt], bL, accB[mt][nt], 0, 0, 0);
            accB[mt][nt] = __builtin_amdgcn_mfma_f32_16x16x32_f16(aL[mt], bH, accB[mt][nt], 0, 0, 0);
            accA[mt][nt] = __builtin_amdgcn_mfma_f32_16x16x32_f16(aH[mt], bH, accA[mt][nt], 0, 0, 0);
          }
        }
      }
    }
    // per-ky fold into f64 (cross terms carry scale 2^12) — R8 sequence
#pragma unroll
    for (int mt = 0; mt < 2; ++mt)
#pragma unroll
      for (int nt = 0; nt < 2; ++nt)
#pragma unroll
        for (int r = 0; r < 4; ++r)
          dacc[mt][nt][r] += (double)accA[mt][nt][r] +
                             (double)accB[mt][nt][r] * (1.0 / 4096.0);
  }

  // epilogue: D layout col=lane&15 (cout), row=(lane>>4)*4+r (pixel)
#pragma unroll
  for (int mt = 0; mt < 2; ++mt)
#pragma unroll
    for (int nt = 0; nt < 2; ++nt) {
      int cout = wq * 32 + nt * 16 + lm;
#pragma unroll
      for (int r = 0; r < 4; ++r) {
        int gx = x0 + mt * 16 + lq * 4 + r;
        if (gx < W) {
          double v = dacc[mt][nt][r];
          if (RELU) v = fmax(v, 0.0);
          size_t idx = (((size_t)b * H + y) * W + gx) * 256 + cout;
          if (OSPLIT) {
            // same convert sequence as R8's conv2 staging (bit-exact)
            _Float16 hh = (_Float16)((float)v);
            float rr = (float)(v - (double)(float)hh) * 4096.0f;
            _Float16 ll = (_Float16)rr;
            A.outF[l][idx] = (float)v;
            A.outH[l][idx] = __builtin_bit_cast(unsigned short, hh);
            A.outL[l][idx] = __builtin_bit_cast(unsigned short, ll);
          } else {
            A.outD[l][idx] = v;
          }
        }
      }
    }
}

// ---------------- RPN head (obj + delta 1x1) + anchor decode, f64 -----------
struct AnchorHW { double hh[9]; double ww[9]; };

__global__ __launch_bounds__(64) void rpn_head_d(
    const double* __restrict__ tmap,
    const float* __restrict__ w_obj, const float* __restrict__ b_obj,
    const float* __restrict__ w_dlt, const float* __restrict__ b_dlt,
    double* __restrict__ scores, double* __restrict__ boxes,
    int H, int W, int a_off, double stride, AnchorHW anc) {
  __shared__ double tv[256];
  __shared__ double dlt[36];
  const int t = threadIdx.x;
  const int x = blockIdx.x, y = blockIdx.y, b = blockIdx.z;
  const double* px = tmap + (((size_t)b * H + y) * W + x) * 256;
  tv[t] = px[t]; tv[t + 64] = px[t + 64]; tv[t + 128] = px[t + 128]; tv[t + 192] = px[t + 192];
  __syncthreads();
  double sacc = 0.0;
  if (t < 9) {
    sacc = (double)b_obj[t];
    for (int ci = 0; ci < 256; ++ci) sacc += tv[ci] * (double)w_obj[ci * 9 + t];
  } else if (t < 45) {
    int j = t - 9;
    double a = (double)b_dlt[j];
    for (int ci = 0; ci < 256; ++ci) a += tv[ci] * (double)w_dlt[ci * 36 + j];
    dlt[j] = a;
  }
  __syncthreads();
  if (t < 9) {
    int ai = a_off + (y * W + x) * 9 + t;
    scores[(size_t)b * NUM_ANCH + ai] = sacc;
    double cy = (y + 0.5) * stride, cx = (x + 0.5) * stride;
    double hh = anc.hh[t], ww = anc.ww[t];
    float ay1 = (float)fmin(fmax(cy - hh * 0.5, 0.0), 512.0);
    float ax1 = (float)fmin(fmax(cx - ww * 0.5, 0.0), 512.0);
    float ay2 = (float)fmin(fmax(cy + hh * 0.5, 0.0), 512.0);
    float ax2 = (float)fmin(fmax(cx + ww * 0.5, 0.0), 512.0);
    float ahf = ay2 - ay1, awf = ax2 - ax1;
    float actyf = ay1 + ahf * 0.5f, actxf = ax1 + awf * 0.5f;
    double dy = dlt[t * 4 + 0], dx = dlt[t * 4 + 1];
    double dh = dlt[t * 4 + 2], dw = dlt[t * 4 + 3];
    double ncy = dy * (double)ahf + (double)actyf;
    double ncx = dx * (double)awf + (double)actxf;
    double nh = exp(dh) * (double)ahf;
    double nw = exp(dw) * (double)awf;
    double* bo = boxes + ((size_t)b * NUM_ANCH + ai) * 4;
    bo[0] = ncy - nh * 0.5;
    bo[1] = ncx - nw * 0.5;
    bo[2] = ncy + nh * 0.5;
    bo[3] = ncx + nw * 0.5;
  }
}

// ---------------- parallel exact top-1000 (radix-select, multi-kernel) ------
__device__ inline unsigned long long dkey(double f) {
  unsigned long long u = (unsigned long long)__double_as_longlong(f);
  return u ^ ((unsigned long long)((long long)u >> 63) | 0x8000000000000000ull);
}

__global__ void topk_init(unsigned* __restrict__ hist,
                          unsigned long long* __restrict__ prefix,
                          unsigned* __restrict__ need, unsigned* __restrict__ cnt) {
  int t = blockIdx.x * 256 + threadIdx.x;
  if (t < 2 * 3 * 2048) hist[t] = 0;
  if (t < 2) { prefix[t] = 0ull; need[t] = 1000; cnt[t] = 0; }
}

__global__ __launch_bounds__(256) void topk_hist(
    const double* __restrict__ scores, const unsigned long long* __restrict__ prefix,
    unsigned* __restrict__ hist, int shift, unsigned long long maskHigh) {
  const int b = blockIdx.y;
  __shared__ unsigned lh[2048];
  for (int i = threadIdx.x; i < 2048; i += 256) lh[i] = 0;
  __syncthreads();
  const double* sc = scores + (size_t)b * NUM_ANCH;
  const unsigned long long pfx = prefix[b];
  const int stride = gridDim.x * 256;
  for (int i = blockIdx.x * 256 + threadIdx.x; i < NUM_ANCH; i += stride) {
    unsigned long long k = dkey(sc[i]);
    if ((k & maskHigh) == pfx)
      atomicAdd(&lh[(unsigned)(k >> shift) & 2047u], 1u);
  }
  __syncthreads();
  unsigned* gh = hist + b * 2048;
  for (int i = threadIdx.x; i < 2048; i += 256) {
    unsigned v = lh[i];
    if (v) atomicAdd(&gh[i], v);
  }
}

__global__ __launch_bounds__(1024) void topk_pick(
    const unsigned* __restrict__ hist, unsigned long long* __restrict__ prefix,
    unsigned* __restrict__ need, int shift) {
  const int b = blockIdx.x;
  __shared__ unsigned s[2048];
  const unsigned* gh = hist + b * 2048;
  const int t = threadIdx.x;
  s[t] = gh[t];
  s[t + 1024] = gh[t + 1024];
  __syncthreads();
  // inclusive suffix scan: s[i] = sum_{j>=i} hist[j]
  for (int off = 1; off < 2048; off <<= 1) {
    unsigned v0 = s[t] + ((t + off < 2048) ? s[t + off] : 0u);
    unsigned v1 = s[t + 1024] + ((t + 1024 + off < 2048) ? s[t + 1024 + off] : 0u);
    __syncthreads();
    s[t] = v0;
    s[t + 1024] = v1;
    __syncthreads();
  }
  const unsigned nd = need[b];
#pragma unroll
  for (int u = 0; u < 2; ++u) {
    int bin = t + u * 1024;
    unsigned Sb = s[bin];
    unsigned Sa = (bin < 2047) ? s[bin + 1] : 0u;
    if (Sb >= nd && Sa < nd) {   // unique: highest bin with suffix-count >= need
      prefix[b] |= ((unsigned long long)bin) << shift;
      need[b] = nd - Sa;
    }
  }
}

__global__ __launch_bounds__(256) void topk_collect(
    const double* __restrict__ scores, const unsigned long long* __restrict__ prefix,
    unsigned* __restrict__ cnt, unsigned long long* __restrict__ ckey,
    unsigned* __restrict__ cid) {
  const int b = blockIdx.y;
  const double* sc = scores + (size_t)b * NUM_ANCH;
  const unsigned long long K = prefix[b];
  const int stride = gridDim.x * 256;
  for (int i = blockIdx.x * 256 + threadIdx.x; i < NUM_ANCH; i += stride) {
    unsigned long long k = dkey(sc[i]);
    if (k >= K) {
      unsigned pos = atomicAdd(&cnt[b], 1u);
      if (pos < 2048) { ckey[b * 2048 + pos] = k; cid[b * 2048 + pos] = (unsigned)i; }
    }
  }
}

__global__ __launch_bounds__(1024) void topk_final(
    const double* __restrict__ scores, const double* __restrict__ boxes,
    const unsigned* __restrict__ cnt, const unsigned long long* __restrict__ ckey,
    const unsigned* __restrict__ cid, double* __restrict__ ss,
    double* __restrict__ sb) {
  const int b = blockIdx.x;
  __shared__ unsigned long long kk[2048];
  __shared__ unsigned id[2048];
  const int t = threadIdx.x;
  unsigned c = cnt[b];
  if (c > 2048u) c = 2048u;
  for (int i = t; i < 2048; i += 1024) {
    if (i < (int)c) { kk[i] = ckey[b * 2048 + i]; id[i] = cid[b * 2048 + i]; }
    else { kk[i] = 0ull; id[i] = 0xFFFFFFFFu; }
  }
  __syncthreads();
  for (int k = 2; k <= 2048; k <<= 1) {
    for (int j = k >> 1; j > 0; j >>= 1) {
#pragma unroll
      for (int u = 0; u < 2; ++u) {
        int i = t + u * 1024;
        int ixj = i ^ j;
        if (ixj > i) {
          unsigned long long ka = kk[i], kc = kk[ixj];
          unsigned ia = id[i], ic = id[ixj];
          bool cPrec = (kc > ka) || (kc == ka && ic < ia);
          bool up = (i & k) != 0;
          if (cPrec != up) { kk[i] = kc; kk[ixj] = ka; id[i] = ic; id[ixj] = ia; }
        }
      }
      __syncthreads();
    }
  }
  if (t < 1000) {
    unsigned idx = id[t];
    ss[b * 1000 + t] = scores[(size_t)b * NUM_ANCH + idx];
    const double* bp = boxes + ((size_t)b * NUM_ANCH + idx) * 4;
    double* op = sb + (b * 1000 + t) * 4;
    op[0] = bp[0]; op[1] = bp[1]; op[2] = bp[2]; op[3] = bp[3];
  }
}

// ---------------- suppression bit-matrix (iou>0.7 & j>i), f64 ---------------
__global__ void suppmat_d(const double* __restrict__ sb,
                          unsigned long long* __restrict__ supp) {
  int g = blockIdx.x * 256 + threadIdx.x;   // 32000 = 2*1000*16
  int w = g & 15;
  int i = (g >> 4) % 1000;
  int b = g / 16000;
  const double* bx = sb + b * 4000;
  double y1 = bx[i * 4 + 0], x1 = bx[i * 4 + 1], y2 = bx[i * 4 + 2], x2 = bx[i * 4 + 3];
  double ai = (y2 - y1) * (x2 - x1);
  unsigned long long m = 0;
  for (int q = 0; q < 64; ++q) {
    int j = w * 64 + q;
    if (j > i && j < 1000) {
      double by1 = bx[j * 4 + 0], bx1 = bx[j * 4 + 1], by2 = bx[j * 4 + 2], bx2 = bx[j * 4 + 3];
      double aj = (by2 - by1) * (bx2 - bx1);
      double iy1 = fmax(y1, by1), ix1 = fmax(x1, bx1);
      double iy2 = fmin(y2, by2), ix2 = fmin(x2, bx2);
      double inter = fmax(iy2 - iy1, 0.0) * fmax(ix2 - ix1, 0.0);
      double iou = inter / (ai + aj - inter + 1e-8);
      if (iou > 0.7) m |= (1ull << q);
    }
  }
  supp[g] = m;
}

// ---------------- greedy NMS reduce + slot scatter --------------------------
__global__ __launch_bounds__(64) void nms_reduce_d(
    const double* __restrict__ ss, const double* __restrict__ sb,
    const unsigned long long* __restrict__ supp,
    float* __restrict__ rois, double* __restrict__ rois64) {
  __shared__ unsigned long long aliveS[16];
  __shared__ int pref[16];
  const int b = blockIdx.x, lane = threadIdx.x;
  unsigned long long myword = 0;
  if (lane < 16) {
    for (int q = 0; q < 64; ++q) {
      int j = lane * 64 + q;
      if (j < 1000 && ss[b * 1000 + j] > 0.0) myword |= (1ull << q);
    }
  }
  const unsigned long long* sp = supp + (size_t)b * 16000;
  unsigned long long cur = (lane < 16) ? sp[lane] : 0ull;
  for (int i = 0; i < 1000; ++i) {
    unsigned long long nxt = (lane < 16 && i < 999) ? sp[(i + 1) * 16 + lane] : 0ull;
    unsigned long long wv = __shfl(myword, i >> 6);
    if ((wv >> (i & 63)) & 1ull) {
      if (lane < 16) myword &= ~cur;
    }
    cur = nxt;
  }
  if (lane < 16) aliveS[lane] = myword;
  __syncthreads();
  if (lane == 0) {
    int s = 0;
    for (int w = 0; w < 16; ++w) { pref[w] = s; s += __popcll(aliveS[w]); }
  }
  float* ro = rois + b * 4000;
  double* rd = rois64 + b * 4000;
  for (int k = lane; k < 4000; k += 64) { ro[k] = 0.0f; rd[k] = 0.0; }
  __syncthreads();
  for (int j = lane; j < 1000; j += 64) {
    int w = j >> 6;
    unsigned long long word = aliveS[w];
    if ((word >> (j & 63)) & 1ull) {
      unsigned long long below = (j & 63) ? (word & ((1ull << (j & 63)) - 1ull)) : 0ull;
      int slot = pref[w] + __popcll(below);
      const double* bp = sb + (b * 1000 + j) * 4;
      ro[slot * 4 + 0] = (float)bp[0]; ro[slot * 4 + 1] = (float)bp[1];
      ro[slot * 4 + 2] = (float)bp[2]; ro[slot * 4 + 3] = (float)bp[3];
      rd[slot * 4 + 0] = bp[0]; rd[slot * 4 + 1] = bp[1];
      rd[slot * 4 + 2] = bp[2]; rd[slot * 4 + 3] = bp[3];
    }
  }
}

// ---------------- ROI align: f32 maps, f64 math -> hi/lo bf16 feats ---------
__global__ __launch_bounds__(256) void roi_align_d(
    const float* __restrict__ o2, const float* __restrict__ o3,
    const float* __restrict__ o4, const float* __restrict__ o5,
    const float* __restrict__ o6, const double* __restrict__ rois64,
    unsigned short* __restrict__ featsH, unsigned short* __restrict__ featsL) {
  __shared__ double s_wy[14], s_wx[14];
  __shared__ int s_y0[14], s_y1[14], s_x0[14], s_x1[14];
  const int t = threadIdx.x;
  const int b = blockIdx.x / 1000, r = blockIdx.x % 1000;
  const double* box = rois64 + (b * 1000 + r) * 4;
  double b0 = box[0], b1 = box[1], b2 = box[2], b3 = box[3];
  double h = b2 - b0, w = b3 - b1;
  double size = sqrt(fmax(h * w, 1e-8));
  double lf = floor(log2(size / 224.0) + 4.0);
  lf = fmin(fmax(lf, 2.0), 6.0);
  int lvl = (int)lf;
  int stride_i = 1 << lvl;
  double stride = (double)stride_i;
  int fs_i = 512 >> lvl;
  double fs = (double)fs_i;
  if (t < 14) {
    double v = b0 / stride + ((t + 0.5) * (h / stride)) / 14.0 - 0.5;
    v = fmin(fmax(v, 0.0), fs - 1.0);
    int i0 = (int)floor(v);
    s_y0[t] = i0; s_y1[t] = min(i0 + 1, fs_i - 1); s_wy[t] = v - (double)i0;
  } else if (t >= 64 && t < 78) {
    int u = t - 64;
    double v = b1 / stride + ((u + 0.5) * (w / stride)) / 14.0 - 0.5;
    v = fmin(fmax(v, 0.0), fs - 1.0);
    int i0 = (int)floor(v);
    s_x0[u] = i0; s_x1[u] = min(i0 + 1, fs_i - 1); s_wx[u] = v - (double)i0;
  }
  __syncthreads();
  const float* omaps[5] = {o2, o3, o4, o5, o6};
  const float* fm = omaps[lvl - 2] + (size_t)b * fs_i * fs_i * 256 + t;
  size_t obase = ((size_t)(b * 1000 + r) * 49) * 256 + t;
  for (int oy = 0; oy < 7; ++oy) {
    double acc[7] = {0, 0, 0, 0, 0, 0, 0};
#pragma unroll
    for (int sy = 0; sy < 2; ++sy) {
      int yy = oy * 2 + sy;
      int y0 = s_y0[yy], y1 = s_y1[yy];
      double wy = s_wy[yy];
      const float* r0 = fm + (size_t)y0 * fs_i * 256;
      const float* r1 = fm + (size_t)y1 * fs_i * 256;
      for (int ox = 0; ox < 7; ++ox) {
#pragma unroll
        for (int sx = 0; sx < 2; ++sx) {
          int xx = ox * 2 + sx;
          int x0 = s_x0[xx], x1 = s_x1[xx];
          double wx = s_wx[xx];
          double v00 = (double)r0[x0 * 256], v01 = (double)r0[x1 * 256];
          double v10 = (double)r1[x0 * 256], v11 = (double)r1[x1 * 256];
          double val = (1.0 - wy) * ((1.0 - wx) * v00 + wx * v01) +
                       wy * ((1.0 - wx) * v10 + wx * v11);
          acc[ox] += val;
        }
      }
    }
    for (int ox = 0; ox < 7; ++ox) {
      float v = (float)(acc[ox] * 0.25);
      unsigned short hh = f2bf(v);
      size_t idx = obase + (size_t)(oy * 7 + ox) * 256;
      featsH[idx] = hh;
      featsL[idx] = f2bf(v - bf2f(hh));
    }
  }
}

// ---------------- split f32 [K][N] -> bf16 hi/lo transposed [N][K] ----------
__global__ __launch_bounds__(256) void split_transpose(
    const float* __restrict__ W, unsigned short* __restrict__ TH,
    unsigned short* __restrict__ TL, int K, int N) {
  __shared__ unsigned short shh[32 * 33], shl[32 * 33];
  const int kt = blockIdx.y * 32, nt = blockIdx.x * 32;
  const int tx = threadIdx.x & 31, ty = threadIdx.x >> 5;   // 32x8
  for (int yy = ty; yy < 32; yy += 8) {
    float v = W[(size_t)(kt + yy) * N + nt + tx];
    unsigned short h = f2bf(v);
    shh[yy * 33 + tx] = h;
    shl[yy * 33 + tx] = f2bf(v - bf2f(h));
  }
  __syncthreads();
  for (int yy = ty; yy < 32; yy += 8) {
    TH[(size_t)(nt + yy) * K + kt + tx] = shh[tx * 33 + yy];
    TL[(size_t)(nt + yy) * K + kt + tx] = shl[tx * 33 + yy];
  }
}

// ---------------- split-K partial bf16 MFMA GEMM 128x128 --------------------
struct GemmPArgs {
  const unsigned short* AH;
  const unsigned short* AL;
  const unsigned short* BTH;
  const unsigned short* BTL;
  float* P[4];
  int M, N, K, KC;
};

__global__ __launch_bounds__(256) void gemm_mfma_partial(GemmPArgs G) {
  __shared__ __align__(16) unsigned short AsH[128 * 40], AsL[128 * 40];
  __shared__ __align__(16) unsigned short BsH[128 * 40], BsL[128 * 40];
  const int t = threadIdx.x;
  const int lane = t & 63;
  const int wave = t >> 6;
  const int lm = lane & 15, lq = lane >> 4;
  const int wn = wave & 1, wm = wave >> 1;
  const int m0 = blockIdx.y * 128, n0 = blockIdx.x * 128;
  const int kc = blockIdx.z;
  const int kbeg = kc * G.KC, kend = kbeg + G.KC;
  const int M = G.M, N = G.N, K = G.K;
  float* __restrict__ C = G.P[kc];
  const unsigned short* __restrict__ AH = G.AH;
  const unsigned short* __restrict__ AL = G.AL;
  const unsigned short* __restrict__ BTH = G.BTH;
  const unsigned short* __restrict__ BTL = G.BTL;
  const int sr = t >> 1;            // 0..127
  const int sk = (t & 1) * 16;      // 0,16

  f4_t acc[4][4];
#pragma unroll
  for (int mt = 0; mt < 4; ++mt)
#pragma unroll
    for (int nt = 0; nt < 4; ++nt) acc[mt][nt] = (f4_t){0.f, 0.f, 0.f, 0.f};

  const uint4 zz = {0u, 0u, 0u, 0u};
  for (int k0 = kbeg; k0 < kend; k0 += 32) {
    __syncthreads();
    {
      uint4 vh0 = zz, vh1 = zz, vl0 = zz, vl1 = zz;
      if (m0 + sr < M) {
        size_t off = (size_t)(m0 + sr) * K + k0 + sk;
        vh0 = *(const uint4*)&AH[off];
        vh1 = *(const uint4*)&AH[off + 8];
        vl0 = *(const uint4*)&AL[off];
        vl1 = *(const uint4*)&AL[off + 8];
      }
      *(uint4*)&AsH[sr * 40 + sk] = vh0;
      *(uint4*)&AsH[sr * 40 + sk + 8] = vh1;
      *(uint4*)&AsL[sr * 40 + sk] = vl0;
      *(uint4*)&AsL[sr * 40 + sk + 8] = vl1;
    }
    {
      size_t off = (size_t)(n0 + sr) * K + k0 + sk;
      *(uint4*)&BsH[sr * 40 + sk] = *(const uint4*)&BTH[off];
      *(uint4*)&BsH[sr * 40 + sk + 8] = *(const uint4*)&BTH[off + 8];
      *(uint4*)&BsL[sr * 40 + sk] = *(const uint4*)&BTL[off];
      *(uint4*)&BsL[sr * 40 + sk + 8] = *(const uint4*)&BTL[off + 8];
    }
    __syncthreads();

    bf8_t aH[4], aL[4], bH[4], bL[4];
#pragma unroll
    for (int mt = 0; mt < 4; ++mt) {
      int idx = (wm * 64 + mt * 16 + lm) * 40 + lq * 8;
      aH[mt] = *(const bf8_t*)&AsH[idx];
      aL[mt] = *(const bf8_t*)&AsL[idx];
    }
#pragma unroll
    for (int nt = 0; nt < 4; ++nt) {
      int idx = (wn * 64 + nt * 16 + lm) * 40 + lq * 8;
      bH[nt] = *(const bf8_t*)&BsH[idx];
      bL[nt] = *(const bf8_t*)&BsL[idx];
    }
#pragma unroll
    for (int mt = 0; mt < 4; ++mt)
#pragma unroll
      for (int nt = 0; nt < 4; ++nt) {
        f4_t a0 = acc[mt][nt];
        a0 = __builtin_amdgcn_mfma_f32_16x16x32_bf16(aL[mt], bH[nt], a0, 0, 0, 0);
        a0 = __builtin_amdgcn_mfma_f32_16x16x32_bf16(aH[mt], bL[nt], a0, 0, 0, 0);
        a0 = __builtin_amdgcn_mfma_f32_16x16x32_bf16(aH[mt], bH[nt], a0, 0, 0, 0);
        acc[mt][nt] = a0;
      }
  }
#pragma unroll
  for (int mt = 0; mt < 4; ++mt) {
#pragma unroll
    for (int nt = 0; nt < 4; ++nt) {
      int ncol = n0 + wn * 64 + nt * 16 + lm;
#pragma unroll
      for (int r = 0; r < 4; ++r) {
        int m = m0 + wm * 64 + mt * 16 + lq * 4 + r;
        if (m < M) C[(size_t)m * N + ncol] = acc[mt][nt][r];
      }
    }
  }
}

// ---------------- reduce 4 partials + bias + relu -> bf16 hi/lo -------------
__global__ void reduce4_split(const float* __restrict__ p0, const float* __restrict__ p1,
                              const float* __restrict__ p2, const float* __restrict__ p3,
                              const float* __restrict__ bias,
                              unsigned short* __restrict__ H, unsigned short* __restrict__ L,
                              int n) {
  int i = blockIdx.x * 256 + threadIdx.x;
  if (i < n) {
    float v = ((p0[i] + p1[i]) + p2[i]) + p3[i] + bias[i & 1023];
    v = fmaxf(v, 0.0f);
    unsigned short h = f2bf(v);
    H[i] = h;
    L[i] = f2bf(v - bf2f(h));
  }
}

// ---------------- reduce 4 partials + bias + relu -> f32 --------------------
__global__ void reduce4_f32(const float* __restrict__ p0, const float* __restrict__ p1,
                            const float* __restrict__ p2, const float* __restrict__ p3,
                            const float* __restrict__ bias, float* __restrict__ C, int n) {
  int i = blockIdx.x * 256 + threadIdx.x;
  if (i < n) {
    float v = ((p0[i] + p1[i]) + p2[i]) + p3[i] + bias[i & 1023];
    C[i] = fmaxf(v, 0.0f);
  }
}

// ---------------- final box(4) + cls(81) heads, f32 -------------------------
__global__ __launch_bounds__(128) void boxcls_kernel(
    const float* __restrict__ x, const float* __restrict__ w_box,
    const float* __restrict__ b_box, const float* __restrict__ w_cls,
    const float* __restrict__ b_cls, float* __restrict__ out) {
  __shared__ float xv[1024];
  const int t = threadIdx.x;
  const int row = blockIdx.x;
  const float* xp = x + (size_t)row * 1024;
#pragma unroll
  for (int k = 0; k < 8; ++k) xv[k * 128 + t] = xp[k * 128 + t];
  __syncthreads();
  if (t < 4) {
    float acc = b_box[t];
    for (int k = 0; k < 1024; ++k) acc += xv[k] * w_box[k * 4 + t];
    out[8000 + row * 4 + t] = acc;
  } else if (t < 85) {
    int j = t - 4;
    float acc = b_cls[j];
    for (int k = 0; k < 1024; ++k) acc += xv[k] * w_cls[k * 81 + j];
    out[16000 + row * 81 + j] = acc;
  }
}

// ---------------------------------------------------------------------------
extern "C" void kernel_launch(void* const* d_in, const int* in_sizes, int n_in,
                              void* d_out, int out_size, void* d_ws, size_t ws_size,
                              hipStream_t stream) {
  (void)in_sizes; (void)n_in; (void)out_size; (void)ws_size;

  const float* c_in[4] = {(const float*)d_in[0], (const float*)d_in[1],
                          (const float*)d_in[2], (const float*)d_in[3]};
  const float *w_l[5], *b_l[5], *w_o[5], *b_o[5];
  for (int l = 0; l < 5; ++l) {
    w_l[l] = (const float*)d_in[4 + l * 4 + 0];
    b_l[l] = (const float*)d_in[4 + l * 4 + 1];
    w_o[l] = (const float*)d_in[4 + l * 4 + 2];
    b_o[l] = (const float*)d_in[4 + l * 4 + 3];
  }
  const float* w_rpn = (const float*)d_in[24];
  const float* b_rpn = (const float*)d_in[25];
  const float* w_obj = (const float*)d_in[26];
  const float* b_obj = (const float*)d_in[27];
  const float* w_dlt = (const float*)d_in[28];
  const float* b_dlt = (const float*)d_in[29];
  const float* w_fc1 = (const float*)d_in[30];
  const float* b_fc1 = (const float*)d_in[31];
  const float* w_fc2 = (const float*)d_in[32];
  const float* b_fc2 = (const float*)d_in[33];
  const float* w_box = (const float*)d_in[34];
  const float* b_box = (const float*)d_in[35];
  const float* w_cls = (const float*)d_in[36];
  const float* b_cls = (const float*)d_in[37];

  char* W8 = (char*)d_ws;
  // o region: f32 maps + f16 hi/lo planes
  float* oF32 = (float*)(W8 + 0);
  unsigned short* oH = (unsigned short*)(W8 + 44695552);
  unsigned short* oL = (unsigned short*)(W8 + 67043328);
  // p region: f64 (decision path)
  double* p64 = (double*)(W8 + 89391104);
  float* c6buf = (float*)(W8 + 178782208);
  double* scores = (double*)(W8 + 179830784);
  double* boxes = (double*)(W8 + 182973440);
  double* ssb = (double*)(W8 + 195544064);
  double* sbb = (double*)(W8 + 195560064);
  double* rois64 = (double*)(W8 + 195624064);
  unsigned long long* suppb = (unsigned long long*)(W8 + 195688064);
  unsigned short* featsH = (unsigned short*)(W8 + 89391104);
  unsigned short* featsL = (unsigned short*)(W8 + 139567104);
  float* fc1b = (float*)(W8 + 0);
  float* fc2b = (float*)(W8 + 8192000);
  unsigned short* wT1H = (unsigned short*)(W8 + 16384000);
  unsigned short* wT1L = (unsigned short*)(W8 + 42074112);
  unsigned short* wT2H = (unsigned short*)(W8 + 67764224);
  unsigned short* wT2L = (unsigned short*)(W8 + 69861376);
  unsigned short* fc1H = (unsigned short*)(W8 + 89391104);
  unsigned short* fc1L = (unsigned short*)(W8 + 93487104);
  float* fc1p1 = (float*)(W8 + 8192000);
  float* fc1p2 = (float*)(W8 + 71958528);
  float* fc1p3 = (float*)(W8 + 80150528);
  float* fc2p1 = (float*)(W8 + 0);
  float* fc2p2 = (float*)(W8 + 16384000);
  float* fc2p3 = (float*)(W8 + 24576000);
  float* outf = (float*)d_out;

  // topk scratch overlays oH start (dead after conv2, before fc overlay)
  unsigned* tk_hist = (unsigned*)(W8 + 44695552);                    // 2*3*2048*4
  unsigned long long* tk_prefix = (unsigned long long*)(W8 + 44744704);
  unsigned* tk_need = (unsigned*)(W8 + 44744720);
  unsigned* tk_cnt = (unsigned*)(W8 + 44744728);
  unsigned long long* tk_ckey = (unsigned long long*)(W8 + 44744768); // 2*2048*8
  unsigned* tk_cid = (unsigned*)(W8 + 44777536);                      // 2*2048*4

  // conv f16 weight planes (scores/boxes regions, dead until rpn_head)
  unsigned short* woH[5];
  unsigned short* woL[5];
  for (int l = 0; l < 5; ++l) {
    woH[l] = (unsigned short*)(W8 + 182973440 + (size_t)l * 2359296);
    woL[l] = (unsigned short*)(W8 + 182973440 + (size_t)l * 2359296 + 1179648);
  }
  unsigned short* wrH = (unsigned short*)(W8 + 179830784);
  unsigned short* wrL = (unsigned short*)(W8 + 179830784 + 1179648);

  const size_t OFF[5] = {0, 8388608, 10485760, 11010048, 11141120};
  const int HS[5] = {128, 64, 32, 16, 8};
  const int a_off[5] = {0, 147456, 184320, 193536, 195840};
  const double strides[5] = {4.0, 8.0, 16.0, 32.0, 64.0};
  const double SZ[5] = {16.0, 32.0, 64.0, 128.0, 256.0};
  AnchorHW anc[5];
  for (int l = 0; l < 5; ++l) {
    const double ars[3] = {0.5, 1.0, 2.0};
    for (int s = 0; s < 3; ++s) {
      double sc = pow(2.0, s / 3.0);
      for (int a = 0; a < 3; ++a) {
        double sq = sqrt(ars[a]);
        anc[l].hh[s * 3 + a] = SZ[l] * sc / sq;
        anc[l].ww[s * 3 + a] = SZ[l] * sc * sq;
      }
    }
  }

  // ---- weight split for conv passes ----
  for (int l = 0; l < 5; ++l)
    wsplit_f16<<<2304, 256, 0, stream>>>(w_o[l], woH[l], woL[l]);
  wsplit_f16<<<2304, 256, 0, stream>>>(w_rpn, wrH, wrL);

  // ---- FPN (f64, decision path) ----
  maxpool_kernel<<<1024, 256, 0, stream>>>(c_in[3], c6buf);
  lateral_d<2048><<<32, 256, 0, stream>>>(c6buf, w_l[4], b_l[4], p64 + OFF[4]);   // p6
  lateral_d<2048><<<128, 256, 0, stream>>>(c_in[3], w_l[3], b_l[3], p64 + OFF[3]); // p5
  upadd_d<<<512, 256, 0, stream>>>(p64 + OFF[3], p64 + OFF[4], 16, 16);
  lateral_d<1024><<<512, 256, 0, stream>>>(c_in[2], w_l[2], b_l[2], p64 + OFF[2]); // p4
  upadd_d<<<2048, 256, 0, stream>>>(p64 + OFF[2], p64 + OFF[3], 32, 32);
  lateral_d<512><<<2048, 256, 0, stream>>>(c_in[1], w_l[1], b_l[1], p64 + OFF[1]); // p3
  upadd_d<<<8192, 256, 0, stream>>>(p64 + OFF[1], p64 + OFF[2], 64, 64);
  lateral_d<256><<<8192, 256, 0, stream>>>(c_in[0], w_l[0], b_l[0], p64 + OFF[0]); // p2
  upadd_d<<<32768, 256, 0, stream>>>(p64 + OFF[0], p64 + OFF[1], 128, 128);

  // ---- fused 5-level conv passes (double-f16 MFMA, 8-wave) ----
  ConvArgsU co, ct;
  int total = 0;
  for (int l = 0; l < 5; ++l) {
    int nbx = (HS[l] + 31) / 32;
    co.inD[l] = p64 + OFF[l]; co.inH[l] = nullptr; co.inL[l] = nullptr;
    co.outF[l] = oF32 + OFF[l]; co.outH[l] = oH + OFF[l]; co.outL[l] = oL + OFF[l];
    co.outD[l] = nullptr;
    co.wH[l] = woH[l]; co.wL[l] = woL[l]; co.bias[l] = b_o[l];
    ct.inD[l] = nullptr; ct.inH[l] = oH + OFF[l]; ct.inL[l] = oL + OFF[l];
    ct.outF[l] = nullptr; ct.outH[l] = nullptr; ct.outL[l] = nullptr;
    ct.outD[l] = p64 + OFF[l];
    ct.wH[l] = wrH;  ct.wL[l] = wrL;  ct.bias[l] = b_rpn;
    co.H[l] = ct.H[l] = HS[l];
    co.nbx[l] = ct.nbx[l] = nbx;
    co.off[l] = ct.off[l] = total;
    total += nbx * HS[l] * 2;
  }
  co.off[5] = ct.off[5] = total;   // 1392
  conv3x3_u<false, false, true><<<total, 512, 0, stream>>>(co);
  conv3x3_u<true, true, false><<<total, 512, 0, stream>>>(ct);

  for (int l = 0; l < 5; ++l) {
    dim3 g(HS[l], HS[l], 2);
    rpn_head_d<<<g, 64, 0, stream>>>(p64 + OFF[l], w_obj, b_obj, w_dlt, b_dlt,
                                     scores, boxes, HS[l], HS[l], a_off[l],
                                     strides[l], anc[l]);
  }

  // ---- parallel top-1000 (radix select; scratch in dead oH region) ----
  topk_init<<<48, 256, 0, stream>>>(tk_hist, tk_prefix, tk_need, tk_cnt);
  const int tk_shift[3] = {53, 42, 31};
  for (int lv = 0; lv < 3; ++lv) {
    unsigned long long maskHigh = lv ? ((~0ull) << (tk_shift[lv] + 11)) : 0ull;
    topk_hist<<<dim3(64, 2), 256, 0, stream>>>(scores, tk_prefix,
                                               tk_hist + lv * 4096,
                                               tk_shift[lv], maskHigh);
    topk_pick<<<2, 1024, 0, stream>>>(tk_hist + lv * 4096, tk_prefix, tk_need,
                                      tk_shift[lv]);
  }
  topk_collect<<<dim3(64, 2), 256, 0, stream>>>(scores, tk_prefix, tk_cnt,
                                                tk_ckey, tk_cid);
  topk_final<<<2, 1024, 0, stream>>>(scores, boxes, tk_cnt, tk_ckey, tk_cid,
                                     ssb, sbb);

  // ---- NMS (f64) ----
  suppmat_d<<<125, 256, 0, stream>>>(sbb, suppb);
  nms_reduce_d<<<2, 64, 0, stream>>>(ssb, sbb, suppb, outf, rois64);
  // ---- ROI align (f32 maps -> hi/lo bf16 feats) ----
  roi_align_d<<<2000, 256, 0, stream>>>(oF32 + OFF[0], oF32 + OFF[1], oF32 + OFF[2],
                                        oF32 + OFF[3], oF32 + OFF[4], rois64,
                                        featsH, featsL);
  // ---- FC head: split weights (o region now dead), split-K MFMA GEMMs ----
  split_transpose<<<dim3(32, 392), 256, 0, stream>>>(w_fc1, wT1H, wT1L, 12544, 1024);
  split_transpose<<<dim3(32, 32), 256, 0, stream>>>(w_fc2, wT2H, wT2L, 1024, 1024);

  GemmPArgs g1;
  g1.AH = featsH; g1.AL = featsL; g1.BTH = wT1H; g1.BTL = wT1L;
  g1.P[0] = fc1b; g1.P[1] = fc1p1; g1.P[2] = fc1p2; g1.P[3] = fc1p3;
  g1.M = 2000; g1.N = 1024; g1.K = 12544; g1.KC = 3136;
  gemm_mfma_partial<<<dim3(8, 16, 4), 256, 0, stream>>>(g1);
  reduce4_split<<<8000, 256, 0, stream>>>(fc1b, fc1p1, fc1p2, fc1p3, b_fc1,
                                          fc1H, fc1L, 2048000);

  GemmPArgs g2;
  g2.AH = fc1H; g2.AL = fc1L; g2.BTH = wT2H; g2.BTL = wT2L;
  g2.P[0] = fc2b; g2.P[1] = fc2p1; g2.P[2] = fc2p2; g2.P[3] = fc2p3;
  g2.M = 2000; g2.N = 1024; g2.K = 1024; g2.KC = 256;
  gemm_mfma_partial<<<dim3(8, 16, 4), 256, 0, stream>>>(g2);
  reduce4_f32<<<8000, 256, 0, stream>>>(fc2b, fc2p1, fc2p2, fc2p3, b_fc2,
                                        fc2b, 2048000);

  boxcls_kernel<<<2000, 128, 0, stream>>>(fc2b, w_box, b_box, w_cls, b_cls, outf);
}